// Round 16
// baseline (777.420 us; speedup 1.0000x reference)
//
#include <hip/hip_runtime.h>

#define LN_EPS 1e-5f

typedef unsigned short u16;
typedef u16 u16x8 __attribute__((ext_vector_type(8)));
typedef __bf16 bf16x8 __attribute__((ext_vector_type(8)));
typedef float f32x4 __attribute__((ext_vector_type(4)));
typedef float f32x2 __attribute__((ext_vector_type(2)));

__device__ __forceinline__ u16 f2bf(float f){
  return __builtin_bit_cast(u16, (__bf16)f);
}
__device__ __forceinline__ float bf2f(u16 b){
  return (float)__builtin_bit_cast(__bf16, b);
}
__device__ __forceinline__ f32x4 mfma16(u16x8 a, u16x8 b, f32x4 c){
  return __builtin_amdgcn_mfma_f32_16x16x32_bf16(
      __builtin_bit_cast(bf16x8, a), __builtin_bit_cast(bf16x8, b), c, 0, 0, 0);
}
// LDS h-tile: [64 rows][512 k] bf16, XOR swizzle on k (8-elem granules)
__device__ __forceinline__ int uidx(int row, int k){
  return row * 512 + (k ^ ((row & 7) << 3));
}
// bit-reverse of a 4-bit lane id (butterfly reduce lands row bitrev4(lrow) on lane lrow)
__device__ __forceinline__ int bitrev4(int l){
  return ((l & 1) << 3) | ((l & 2) << 1) | ((l & 4) >> 1) | ((l & 8) >> 3);
}

__device__ __forceinline__ void zero_acc(f32x4 (&acc)[4][4]){
  #pragma unroll
  for (int mt = 0; mt < 4; ++mt)
    #pragma unroll
    for (int ct = 0; ct < 4; ++ct){
      f32x4 z = {0.f, 0.f, 0.f, 0.f};
      acc[mt][ct] = z;
    }
}

// Register-halving butterfly: reduce x[16] across 16 lrow-lanes; lane lrow ends
// with the total of value p = bitrev4(lrow) in x[0]. ~60 issue-ops vs 128.
__device__ __forceinline__ float reduce16(float (&x)[16], int lrow){
  #pragma unroll
  for (int b = 1; b < 16; b <<= 1){
    const int h = 8 / b;
    #pragma unroll
    for (int k = 0; k < h; ++k){
      float mine  = (lrow & b) ? x[k + h] : x[k];
      float other = (lrow & b) ? x[k] : x[k + h];
      x[k] = mine + __shfl_xor(other, b);
    }
  }
  return x[0];
}

// Issue first kt's 4 B-fragment loads BEFORE the preceding barrier (in flight
// across s_barrier; hides cold-start L2 latency).
__device__ __forceinline__ void preload_b4(const u16* __restrict__ Bp, int wave, int lane,
                                           u16x8 (&b)[4]){
  const u16* bb = Bp + ((size_t)(wave * 4) * 64 + lane) * 8;
  #pragma unroll
  for (int ct = 0; ct < 4; ++ct) b[ct] = *(const u16x8*)&bb[ct * 512];
}

// GEMM, A from LDS (64 rows), B from global (N=512 packing, kt-stride 16384),
// 1-deep register prefetch. b_cur arrives preloaded.
__device__ __forceinline__ void gemm_pipe(const u16* hA, const u16* __restrict__ Bp,
                                          f32x4 (&acc)[4][4], int wave, int lane,
                                          u16x8 (&b_cur)[4]){
  int lrow = lane & 15, lhi = lane >> 4;
  const u16* bb = Bp + ((size_t)(wave * 4) * 64 + lane) * 8;
  u16x8 b_nxt[4], a[4];
  #pragma unroll
  for (int kt = 0; kt < 16; ++kt){
    #pragma unroll
    for (int mt = 0; mt < 4; ++mt)
      a[mt] = *(const u16x8*)&hA[uidx(mt * 16 + lrow, kt * 32 + lhi * 8)];
    if (kt < 15){
      #pragma unroll
      for (int ct = 0; ct < 4; ++ct)
        b_nxt[ct] = *(const u16x8*)&bb[(size_t)(kt + 1) * 16384 + ct * 512];
    }
    __builtin_amdgcn_s_setprio(1);
    #pragma unroll
    for (int ct = 0; ct < 4; ++ct)
      #pragma unroll
      for (int mt = 0; mt < 4; ++mt)
        acc[mt][ct] = mfma16(a[mt], b_cur[ct], acc[mt][ct]);
    __builtin_amdgcn_s_setprio(0);
    #pragma unroll
    for (int ct = 0; ct < 4; ++ct) b_cur[ct] = b_nxt[ct];
  }
}

// K=1024 GEMM, A rows from TWO global sources (nodeb | hsumb), B packed K=1024
// (kt-stride 16384, KT=32).
__device__ __forceinline__ void gemm_k1024_gA(const u16* __restrict__ A0,
                                              const u16* __restrict__ A1, size_t row0,
                                              const u16* __restrict__ Bp,
                                              f32x4 (&acc)[4][4], int wave, int lane){
  int lrow = lane & 15, lhi = lane >> 4;
  const u16* bb = Bp + ((size_t)(wave * 4) * 64 + lane) * 8;
  const u16* a0 = A0 + (row0 + lrow) * 512 + lhi * 8;
  const u16* a1 = A1 + (row0 + lrow) * 512 + lhi * 8;
  u16x8 b_cur[4], b_nxt[4], a[4];
  #pragma unroll
  for (int ct = 0; ct < 4; ++ct) b_cur[ct] = *(const u16x8*)&bb[ct * 512];
  #pragma unroll
  for (int kt = 0; kt < 32; ++kt){
    const u16* ab = (kt < 16) ? a0 : a1;
    int kk = (kt & 15) * 32;
    #pragma unroll
    for (int mt = 0; mt < 4; ++mt)
      a[mt] = *(const u16x8*)&ab[mt * 8192 + kk];
    if (kt < 31){
      #pragma unroll
      for (int ct = 0; ct < 4; ++ct)
        b_nxt[ct] = *(const u16x8*)&bb[(size_t)(kt + 1) * 16384 + ct * 512];
    }
    __builtin_amdgcn_s_setprio(1);
    #pragma unroll
    for (int ct = 0; ct < 4; ++ct)
      #pragma unroll
      for (int mt = 0; mt < 4; ++mt)
        acc[mt][ct] = mfma16(a[mt], b_cur[ct], acc[mt][ct]);
    __builtin_amdgcn_s_setprio(0);
    #pragma unroll
    for (int ct = 0; ct < 4; ++ct) b_cur[ct] = b_nxt[ct];
  }
}

// GEMM over hA with custom B base/kt-stride (for N=1024 w1p packing).
__device__ __forceinline__ void gemm_pipe_s(const u16* hA, const u16* __restrict__ bbBase,
                                            int ktStride, f32x4 (&acc)[4][4],
                                            int lane){
  int lrow = lane & 15, lhi = lane >> 4;
  u16x8 b_cur[4], b_nxt[4], a[4];
  #pragma unroll
  for (int ct = 0; ct < 4; ++ct) b_cur[ct] = *(const u16x8*)&bbBase[ct * 512];
  #pragma unroll
  for (int kt = 0; kt < 16; ++kt){
    #pragma unroll
    for (int mt = 0; mt < 4; ++mt)
      a[mt] = *(const u16x8*)&hA[uidx(mt * 16 + lrow, kt * 32 + lhi * 8)];
    if (kt < 15){
      #pragma unroll
      for (int ct = 0; ct < 4; ++ct)
        b_nxt[ct] = *(const u16x8*)&bbBase[(size_t)(kt + 1) * ktStride + ct * 512];
    }
    __builtin_amdgcn_s_setprio(1);
    #pragma unroll
    for (int ct = 0; ct < 4; ++ct)
      #pragma unroll
      for (int mt = 0; mt < 4; ++mt)
        acc[mt][ct] = mfma16(a[mt], b_cur[ct], acc[mt][ct]);
    __builtin_amdgcn_s_setprio(0);
    #pragma unroll
    for (int ct = 0; ct < 4; ++ct) b_cur[ct] = b_nxt[ct];
  }
}

__device__ __forceinline__ void add_bias8(f32x4 (&acc)[4][4], const float* __restrict__ b,
                                          int wave, int lane){
  int lrow = lane & 15;
  #pragma unroll
  for (int ct = 0; ct < 4; ++ct){
    float bb = b[wave * 64 + ct * 16 + lrow];
    #pragma unroll
    for (int mt = 0; mt < 4; ++mt)
      #pragma unroll
      for (int r = 0; r < 4; ++r) acc[mt][ct][r] += bb;
  }
}

// acc += bias; relu; write bf16 into hA (swizzled). (r1 stage of node MLP.)
__device__ __forceinline__ void relu_to_lds(f32x4 (&acc)[4][4], u16* hA,
                                            const float* __restrict__ b,
                                            int wave, int lane){
  int lrow = lane & 15, lhi = lane >> 4;
  #pragma unroll
  for (int ct = 0; ct < 4; ++ct){
    int c = wave * 64 + ct * 16 + lrow;
    float bb = b[c];
    #pragma unroll
    for (int mt = 0; mt < 4; ++mt)
      #pragma unroll
      for (int r = 0; r < 4; ++r){
        int row = mt * 16 + lhi * 4 + r;
        hA[uidx(row, c)] = f2bf(fmaxf(acc[mt][ct][r] + bb, 0.f));
      }
  }
}

// LN stats: acc += b2; s1/s2 accumulate; butterfly reduce; mu/rsqrt into mufb.
// Includes both barriers. acc left holding x (pre-normalize, bias added).
__device__ __forceinline__ void ln_stats(f32x4 (&acc)[4][4],
    f32x2 (*stats)[8], f32x2* mufb, const float* __restrict__ b2,
    int wave, int lane, int tid)
{
  int lrow = lane & 15, lhi = lane >> 4;
  float s1[16], s2[16];
  #pragma unroll
  for (int p = 0; p < 16; ++p){ s1[p] = 0.f; s2[p] = 0.f; }
  #pragma unroll
  for (int ct = 0; ct < 4; ++ct){
    int c = wave * 64 + ct * 16 + lrow;
    float bb = b2[c];
    #pragma unroll
    for (int mt = 0; mt < 4; ++mt)
      #pragma unroll
      for (int r = 0; r < 4; ++r){
        float x = acc[mt][ct][r] + bb;
        acc[mt][ct][r] = x;
        s1[mt * 4 + r] += x;
        s2[mt * 4 + r] += x * x;
      }
  }
  #pragma unroll
  for (int b = 1; b < 16; b <<= 1){
    const int h = 8 / b;
    #pragma unroll
    for (int k = 0; k < h; ++k){
      float m1 = (lrow & b) ? s1[k + h] : s1[k];
      float o1 = (lrow & b) ? s1[k] : s1[k + h];
      s1[k] = m1 + __shfl_xor(o1, b);
      float m2 = (lrow & b) ? s2[k + h] : s2[k];
      float o2 = (lrow & b) ? s2[k] : s2[k + h];
      s2[k] = m2 + __shfl_xor(o2, b);
    }
  }
  int p = bitrev4(lrow);
  int rowa = (p >> 2) * 16 + lhi * 4 + (p & 3);
  f32x2 pa = {s1[0], s2[0]};
  stats[rowa][wave] = pa;
  __syncthreads();              // also: all waves done reading hA (prev GEMM)
  if (tid < 64){
    float a = 0.f, b = 0.f;
    #pragma unroll
    for (int w = 0; w < 8; ++w){ a += stats[tid][w][0]; b += stats[tid][w][1]; }
    float mu  = a * (1.f / 512.f);
    float var = b * (1.f / 512.f) - mu * mu;
    f32x2 mr = {mu, rsqrtf(fmaxf(var, 0.f) + LN_EPS)};
    mufb[tid] = mr;
  }
  __syncthreads();
}

// normalize + relu -> bf16 into hA (swizzled). Caller barriers before reads.
__device__ __forceinline__ void ln_norm_to_lds(f32x4 (&acc)[4][4], u16* hA,
    f32x2* mufb, const float* __restrict__ g, const float* __restrict__ bt,
    int wave, int lane)
{
  int lrow = lane & 15, lhi = lane >> 4;
  float gv[4], btv[4];
  #pragma unroll
  for (int ct = 0; ct < 4; ++ct){
    int c = wave * 64 + ct * 16 + lrow;
    gv[ct] = g[c]; btv[ct] = bt[c];
  }
  #pragma unroll
  for (int mt = 0; mt < 4; ++mt)
    #pragma unroll
    for (int r = 0; r < 4; ++r){
      int row = mt * 16 + lhi * 4 + r;
      f32x2 mr = mufb[row];
      #pragma unroll
      for (int ct = 0; ct < 4; ++ct){
        int c = wave * 64 + ct * 16 + lrow;
        float x = (acc[mt][ct][r] - mr[0]) * mr[1] * gv[ct] + btv[ct];
        hA[uidx(row, c)] = f2bf(fmaxf(x, 0.f));
      }
    }
}

// Staging: h1 = relu(P'[i]+Q[j]) into hA rows 0..48 (+ zero pad rows 49..63).
// b1 pre-folded into P' at PQ-GEMM output.
__device__ __forceinline__ void stage_h1(const u16* __restrict__ PQ, int gg, u16* hA,
                                         int wave, int lane){
  const u16* Pg = PQ + (size_t)gg * 7 * 1024;
  u16x8 pA, qA, pB, qB;
  {
    int e = wave;
    int i = e / 7, j = e % 7;
    pA = *(const u16x8*)&Pg[(size_t)i * 1024 + lane * 8];
    qA = *(const u16x8*)&Pg[(size_t)j * 1024 + 512 + lane * 8];
  }
  #pragma unroll
  for (int it = 0; it < 8; ++it){
    int e = it * 8 + wave;
    if (it < 7){
      int e2 = e + 8;
      if (e2 < 49){
        int i = e2 / 7, j = e2 % 7;
        pB = *(const u16x8*)&Pg[(size_t)i * 1024 + lane * 8];
        qB = *(const u16x8*)&Pg[(size_t)j * 1024 + 512 + lane * 8];
      }
    }
    u16x8 o;
    if (e < 49){
      #pragma unroll
      for (int u = 0; u < 8; ++u)
        o[u] = f2bf(fmaxf(bf2f(pA[u]) + bf2f(qA[u]), 0.f));
    } else {
      #pragma unroll
      for (int u = 0; u < 8; ++u) o[u] = 0;
    }
    *(u16x8*)&hA[uidx(e, lane * 8)] = o;
    pA = pB; qA = qB;
  }
}

// ======== edge pass 0: stage -> GEMM1(w2) -> LN -> colsum -> hsum (global) ======
__global__ __launch_bounds__(512, 2) void edge0_kernel(
    const u16* __restrict__ PQ, const u16* __restrict__ w2p,
    const float* __restrict__ b2,
    const float* __restrict__ g, const float* __restrict__ bt,
    u16* __restrict__ hsum)
{
  __shared__ alignas(16) u16 hA[64 * 512];
  __shared__ f32x2 stats[64][8];
  __shared__ f32x2 mufb[64];
  int gidx = blockIdx.x;
  int tid = threadIdx.x;
  int wave = tid >> 6, lane = tid & 63;

  stage_h1(PQ, gidx, hA, wave, lane);
  u16x8 bpre[4];
  preload_b4(w2p, wave, lane, bpre);
  __syncthreads();

  f32x4 acc[4][4];
  zero_acc(acc);
  gemm_pipe(hA, w2p, acc, wave, lane, bpre);
  ln_stats(acc, stats, mufb, b2, wave, lane, tid);
  ln_norm_to_lds(acc, hA, mufb, g, bt, wave, lane);
  __syncthreads();                    // h2n rows 0..48 visible
  // column sums: hsum[i][c] = sum_j h2n[7i+j][c] -> global (bf16, coalesced)
  {
    int c = tid;   // 0..511
    #pragma unroll
    for (int i = 0; i < 7; ++i){
      float s = 0.f;
      #pragma unroll
      for (int j = 0; j < 7; ++j)
        s += bf2f(hA[uidx(7 * i + j, c)]);
      hsum[((size_t)(gidx * 7 + i)) * 512 + c] = f2bf(s);
    }
  }
}

// ==== edge pass 1: fused normalize + w3f-dot (w3 folded: w3f = ew3@few) ====
__global__ __launch_bounds__(512, 2) void edge1_kernel(
    const u16* __restrict__ PQ, const u16* __restrict__ w2p,
    const float* __restrict__ b2,
    const float* __restrict__ g, const float* __restrict__ bt,
    const float* __restrict__ w3f, float* __restrict__ out)
{
  __shared__ alignas(16) u16 hA[64 * 512];
  __shared__ f32x2 stats[64][8];
  __shared__ f32x2 mufb[64];
  int gidx = blockIdx.x;
  int tid = threadIdx.x;
  int wave = tid >> 6, lane = tid & 63;
  int lrow = lane & 15, lhi = lane >> 4;

  stage_h1(PQ, gidx, hA, wave, lane);
  u16x8 bpre[4];
  preload_b4(w2p, wave, lane, bpre);
  __syncthreads();

  f32x4 acc[4][4];
  zero_acc(acc);
  gemm_pipe(hA, w2p, acc, wave, lane, bpre);
  ln_stats(acc, stats, mufb, b2, wave, lane, tid);
  // fused normalize + relu + dot with w3f: hs[p] = sum_c w3f[c]*relu(norm(x))
  float gv[4], btv[4], wv[4];
  #pragma unroll
  for (int ct = 0; ct < 4; ++ct){
    int c = wave * 64 + ct * 16 + lrow;
    gv[ct] = g[c]; btv[ct] = bt[c]; wv[ct] = w3f[c];
  }
  float hs[16];
  #pragma unroll
  for (int p = 0; p < 16; ++p) hs[p] = 0.f;
  #pragma unroll
  for (int mt = 0; mt < 4; ++mt)
    #pragma unroll
    for (int r = 0; r < 4; ++r){
      int row = mt * 16 + lhi * 4 + r;
      f32x2 mr = mufb[row];
      #pragma unroll
      for (int ct = 0; ct < 4; ++ct){
        float x = (acc[mt][ct][r] - mr[0]) * mr[1] * gv[ct] + btv[ct];
        hs[mt * 4 + r] = fmaf(fmaxf(x, 0.f), wv[ct], hs[mt * 4 + r]);
      }
    }
  float sa = reduce16(hs, lrow);
  int p = bitrev4(lrow);
  int rowa = (p >> 2) * 16 + lhi * 4 + (p & 3);
  f32x2 pa = {sa, 0.f};
  stats[rowa][wave] = pa;
  __syncthreads();
  if (tid < 49){
    float s = w3f[512];   // eb3.few + feb
    #pragma unroll
    for (int w = 0; w < 8; ++w) s += stats[tid][w][0];
    out[(size_t)gidx * 56 + 7 + tid] = s;
  }
}

// ==== node mega-kernel: r1 -> h2 -> LN -> node2 (+head) -> PQ (pass 2) ====
__global__ __launch_bounds__(512, 2) void node_mega(
    const u16* __restrict__ nodeb, const u16* __restrict__ hsumb,
    const u16* __restrict__ nw1cat, const u16* __restrict__ nw2p,
    const u16* __restrict__ nw3p, const u16* __restrict__ w1p,
    const float* __restrict__ bvec, const float* __restrict__ nb2,
    const float* __restrict__ ng, const float* __restrict__ nbt,
    const float* __restrict__ nb3, const float* __restrict__ hw,
    const float* __restrict__ hb, const float* __restrict__ b1,
    u16* __restrict__ PQ, float* __restrict__ out)
{
  __shared__ alignas(16) u16 hA[64 * 512];
  __shared__ f32x2 stats[64][8];
  __shared__ f32x2 mufb[64];
  int tid = threadIdx.x;
  int wave = tid >> 6, lane = tid & 63;
  int lrow = lane & 15, lhi = lane >> 4;
  size_t row0 = (size_t)blockIdx.x * 64;

  // r1 = relu([nodeb|hsumb] @ [nw1a|w3n] + bvec)  (K=1024, A from global)
  f32x4 acc[4][4];
  zero_acc(acc);
  gemm_k1024_gA(nodeb, hsumb, row0, nw1cat, acc, wave, lane);
  relu_to_lds(acc, hA, bvec, wave, lane);
  u16x8 bpre[4];
  preload_b4(nw2p, wave, lane, bpre);
  __syncthreads();
  // h2 = r1 @ nw2 (+nb2 in LN) -> LN -> relu -> hA
  zero_acc(acc);
  gemm_pipe(hA, nw2p, acc, wave, lane, bpre);
  ln_stats(acc, stats, mufb, nb2, wave, lane, tid);
  ln_norm_to_lds(acc, hA, mufb, ng, nbt, wave, lane);
  preload_b4(nw3p, wave, lane, bpre);
  __syncthreads();
  // node2 = h2n @ nw3 + nb3
  zero_acc(acc);
  gemm_pipe(hA, nw3p, acc, wave, lane, bpre);
  add_bias8(acc, nb3, wave, lane);
  __syncthreads();   // all GEMM reads of hA (h2n) done before overwrite
  // node2 -> hA (for PQ GEMMs); head partial (fused dot + butterfly)
  float hs[16];
  #pragma unroll
  for (int p = 0; p < 16; ++p) hs[p] = 0.f;
  float wv[4];
  #pragma unroll
  for (int ct = 0; ct < 4; ++ct) wv[ct] = hw[wave * 64 + ct * 16 + lrow];
  #pragma unroll
  for (int ct = 0; ct < 4; ++ct){
    int c = wave * 64 + ct * 16 + lrow;
    #pragma unroll
    for (int mt = 0; mt < 4; ++mt)
      #pragma unroll
      for (int r = 0; r < 4; ++r){
        float v = acc[mt][ct][r];
        hA[uidx(mt * 16 + lhi * 4 + r, c)] = f2bf(v);
        hs[mt * 4 + r] = fmaf(v, wv[ct], hs[mt * 4 + r]);
      }
  }
  float sa = reduce16(hs, lrow);
  int p4 = bitrev4(lrow);
  int rowa = (p4 >> 2) * 16 + lhi * 4 + (p4 & 3);
  f32x2 pa = {sa, 0.f};
  stats[rowa][wave] = pa;
  __syncthreads();   // node2 + stats visible
  if (tid < 64){
    size_t v = row0 + tid;
    float s = hb[0];
    #pragma unroll
    for (int w = 0; w < 8; ++w) s += stats[tid][w][0];
    out[(v / 7) * 56 + (v % 7)] = s;
  }
  // PQ = node2 @ w1p  (N=1024, two 512-col passes; P half gets +b1)
  #pragma unroll
  for (int pp = 0; pp < 2; ++pp){
    zero_acc(acc);
    const u16* bbBase = w1p + (((size_t)(pp * 32) + wave * 4) * 64 + lane) * 8;
    gemm_pipe_s(hA, bbBase, 32768, acc, lane);
    #pragma unroll
    for (int ct = 0; ct < 4; ++ct){
      int cc = wave * 64 + ct * 16 + lrow;
      int c = pp * 512 + cc;
      float bb = (pp == 0) ? b1[cc] : 0.f;
      #pragma unroll
      for (int mt = 0; mt < 4; ++mt)
        #pragma unroll
        for (int r = 0; r < 4; ++r){
          size_t grow = row0 + mt * 16 + lhi * 4 + r;
          PQ[grow * 1024 + c] = f2bf(acc[mt][ct][r] + bb);
        }
    }
  }
}

// gemm64 MODE0: PQ = nodeb @ w1p (pass 1); P half (coff==0) gets +b1.
__global__ __launch_bounds__(256, 2) void gemm64_0(
    const u16* __restrict__ A0, const u16* __restrict__ Bp,
    const float* __restrict__ b1, u16* __restrict__ Cout)
{
  int tid = threadIdx.x;
  int wave = tid >> 6, lane = tid & 63;
  int lrow = lane & 15, lhi = lane >> 4;
  size_t row0 = (size_t)blockIdx.x * 64;
  int coff = blockIdx.y * 512;
  const u16* bb = Bp + (((size_t)(coff >> 4) + wave * 8) * 64 + lane) * 8;
  f32x4 acc[4][8];
  #pragma unroll
  for (int mt = 0; mt < 4; ++mt)
    #pragma unroll
    for (int ct = 0; ct < 8; ++ct){
      f32x4 z = {0.f, 0.f, 0.f, 0.f};
      acc[mt][ct] = z;
    }
  u16x8 b_cur[8], b_nxt[8];
  #pragma unroll
  for (int ct = 0; ct < 8; ++ct) b_cur[ct] = *(const u16x8*)&bb[ct * 512];
  #pragma unroll
  for (int kt = 0; kt < 16; ++kt){
    u16x8 af[4];
    #pragma unroll
    for (int mt = 0; mt < 4; ++mt)
      af[mt] = *(const u16x8*)&A0[(row0 + mt * 16 + lrow) * 512 + kt * 32 + lhi * 8];
    if (kt < 15){
      #pragma unroll
      for (int ct = 0; ct < 8; ++ct)
        b_nxt[ct] = *(const u16x8*)&bb[((size_t)(kt + 1) * 64 * 64 + ct * 64) * 8];
    }
    __builtin_amdgcn_s_setprio(1);
    #pragma unroll
    for (int ct = 0; ct < 8; ++ct)
      #pragma unroll
      for (int mt = 0; mt < 4; ++mt) acc[mt][ct] = mfma16(af[mt], b_cur[ct], acc[mt][ct]);
    __builtin_amdgcn_s_setprio(0);
    #pragma unroll
    for (int ct = 0; ct < 8; ++ct) b_cur[ct] = b_nxt[ct];
  }
  #pragma unroll
  for (int ct = 0; ct < 8; ++ct){
    int cc = wave * 128 + ct * 16 + lrow;
    int c = coff + cc;
    float bb2 = (coff == 0) ? b1[cc] : 0.f;
    #pragma unroll
    for (int mt = 0; mt < 4; ++mt)
      #pragma unroll
      for (int r = 0; r < 4; ++r){
        size_t grow = row0 + mt * 16 + lhi * 4 + r;
        Cout[grow * 1024 + c] = f2bf(acc[mt][ct][r] + bb2);
      }
  }
}

// w3n = ew3(f32) @ nw1b(packed bf16): 512x512, K=512. Grid (8,4): 64 rows x 128 cols.
__global__ __launch_bounds__(256) void gemm_w3n(
    const float* __restrict__ A, const u16* __restrict__ Bp, float* __restrict__ C)
{
  int tid = threadIdx.x;
  int wave = tid >> 6, lane = tid & 63;
  int lrow = lane & 15, lhi = lane >> 4;
  size_t row0 = (size_t)blockIdx.x * 64;
  int coff = blockIdx.y * 128;
  const u16* bb = Bp + (((size_t)(coff >> 4) + wave * 2) * 64 + lane) * 8;
  f32x4 acc[4][2];
  #pragma unroll
  for (int mt = 0; mt < 4; ++mt)
    #pragma unroll
    for (int ct = 0; ct < 2; ++ct){
      f32x4 z = {0.f, 0.f, 0.f, 0.f};
      acc[mt][ct] = z;
    }
  for (int kt = 0; kt < 16; ++kt){
    u16x8 af[4], bv[2];
    #pragma unroll
    for (int mt = 0; mt < 4; ++mt){
      const float* ar = A + (row0 + mt * 16 + lrow) * 512 + kt * 32 + lhi * 8;
      float4 v0 = *(const float4*)ar, v1 = *(const float4*)(ar + 4);
      af[mt][0] = f2bf(v0.x); af[mt][1] = f2bf(v0.y);
      af[mt][2] = f2bf(v0.z); af[mt][3] = f2bf(v0.w);
      af[mt][4] = f2bf(v1.x); af[mt][5] = f2bf(v1.y);
      af[mt][6] = f2bf(v1.z); af[mt][7] = f2bf(v1.w);
    }
    #pragma unroll
    for (int ct = 0; ct < 2; ++ct)
      bv[ct] = *(const u16x8*)&bb[(size_t)kt * 16384 + ct * 512];
    #pragma unroll
    for (int ct = 0; ct < 2; ++ct)
      #pragma unroll
      for (int mt = 0; mt < 4; ++mt) acc[mt][ct] = mfma16(af[mt], bv[ct], acc[mt][ct]);
  }
  #pragma unroll
  for (int ct = 0; ct < 2; ++ct){
    int c = coff + wave * 32 + ct * 16 + lrow;
    #pragma unroll
    for (int mt = 0; mt < 4; ++mt)
      #pragma unroll
      for (int r = 0; r < 4; ++r){
        size_t grow = row0 + mt * 16 + lhi * 4 + r;
        C[grow * 512 + c] = acc[mt][ct][r];
      }
  }
}

// bvec[c] = nb1[c] + 7 * sum_m b3[m] * nw1[512+m][c]   (grid 8 x 64 threads)
__global__ void fold_bvec(const float* __restrict__ nb1, const float* __restrict__ b3,
                          const float* __restrict__ nw1, float* __restrict__ bvec)
{
  int c = blockIdx.x * 64 + threadIdx.x;
  float s = 0.f;
  for (int m = 0; m < 512; ++m)
    s += b3[m] * nw1[(size_t)(512 + m) * 512 + c];
  bvec[c] = nb1[c] + 7.f * s;
}

// w3f[k] = sum_c ew3[k][c]*few[c]  (f32); w3f[512] = eb3.few + feb
__global__ void fold_w3(const float* __restrict__ W3, const float* __restrict__ hw,
                        const float* __restrict__ b3, const float* __restrict__ hb,
                        float* __restrict__ w3f)
{
  int k = blockIdx.x, l = threadIdx.x;
  const float* row = (k < 512) ? (W3 + (size_t)k * 512) : b3;
  float s = 0.f;
  for (int c = l; c < 512; c += 64) s += row[c] * hw[c];
  #pragma unroll
  for (int off = 32; off; off >>= 1) s += __shfl_down(s, off);
  if (l == 0) w3f[k] = (k < 512) ? s : s + hb[0];
}

// Pack f32 weight [K][N] into MFMA B-fragment order (bf16).
__global__ void pack_w(const float* __restrict__ W, u16* __restrict__ dst,
                       int K, int N, int w1mode)
{
  int idx = blockIdx.x * 256 + threadIdx.x;
  int total = (K >> 5) * (N >> 4) * 64;
  if (idx >= total) return;
  int lane = idx & 63;
  int t = idx >> 6;
  int nt = N >> 4;
  int ct = t % nt;
  int kt = t / nt;
  int c  = ct * 16 + (lane & 15);
  int k0 = kt * 32 + (lane >> 4) * 8;
  u16x8 o;
  #pragma unroll
  for (int j = 0; j < 8; ++j){
    int k = k0 + j;
    float v;
    if (w1mode){
      v = (c < 512) ? W[(size_t)k * 512 + c] : W[(size_t)(k + 512) * 512 + (c - 512)];
    } else {
      v = W[(size_t)k * N + c];
    }
    o[j] = f2bf(v);
  }
  *(u16x8*)&dst[(size_t)idx * 8] = o;
}

__global__ void cast_node(const float* __restrict__ src, u16* __restrict__ dst, int n8){
  int idx = blockIdx.x * 256 + threadIdx.x;
  if (idx >= n8) return;
  const float4* s = (const float4*)src;
  float4 a = s[(size_t)idx * 2], b = s[(size_t)idx * 2 + 1];
  u16x8 o;
  o[0] = f2bf(a.x); o[1] = f2bf(a.y); o[2] = f2bf(a.z); o[3] = f2bf(a.w);
  o[4] = f2bf(b.x); o[5] = f2bf(b.y); o[6] = f2bf(b.z); o[7] = f2bf(b.w);
  *(u16x8*)&dst[(size_t)idx * 8] = o;
}

extern "C" void kernel_launch(void* const* d_in, const int* in_sizes, int n_in,
                              void* d_out, int out_size, void* d_ws, size_t ws_size,
                              hipStream_t stream)
{
  (void)in_sizes; (void)n_in; (void)out_size; (void)ws_size;
  const float* states = (const float*)d_in[0];
  const float* ew1 = (const float*)d_in[1];
  const float* eb1 = (const float*)d_in[2];
  const float* ew2 = (const float*)d_in[3];
  const float* eb2 = (const float*)d_in[4];
  const float* eg  = (const float*)d_in[5];
  const float* ebt = (const float*)d_in[6];
  const float* ew3 = (const float*)d_in[7];
  const float* eb3 = (const float*)d_in[8];
  const float* nw1 = (const float*)d_in[9];
  const float* nb1 = (const float*)d_in[10];
  const float* nw2 = (const float*)d_in[11];
  const float* nb2 = (const float*)d_in[12];
  const float* ng  = (const float*)d_in[13];
  const float* nbt = (const float*)d_in[14];
  const float* nw3 = (const float*)d_in[15];
  const float* nb3 = (const float*)d_in[16];
  const float* fnw = (const float*)d_in[17];
  const float* fnb = (const float*)d_in[18];
  const float* few = (const float*)d_in[19];
  const float* feb = (const float*)d_in[20];
  float* out = (float*)d_out;

  char* ws = (char*)d_ws;
  size_t off = 0;
  auto alloc = [&](size_t bytes) -> void* {
    void* p = ws + off;
    off += (bytes + 255) & ~(size_t)255;
    return p;
  };
  const size_t NV = 28672;  // B*n
  u16* PQ     = (u16*)alloc(NV * 1024 * 2);   // [NV][P'(512)|Q(512)] bf16 (P' = P+b1)
  u16* nodeb  = (u16*)alloc(NV * 512 * 2);
  u16* hsumb  = (u16*)alloc(NV * 512 * 2);
  u16* w1p    = (u16*)alloc(512 * 1024 * 2);
  u16* nw1cat = (u16*)alloc(1024 * 512 * 2);  // [nw1a packed | w3n packed]
  u16* nw1bp  = (u16*)alloc(512 * 512 * 2);
  u16* w2p    = (u16*)alloc(512 * 512 * 2);
  u16* nw2p   = (u16*)alloc(512 * 512 * 2);
  u16* nw3p   = (u16*)alloc(512 * 512 * 2);
  float* w3n  = (float*)alloc(512 * 512 * 4);
  float* w3f  = (float*)alloc(513 * 4);
  float* bvec = (float*)alloc(512 * 4);

  pack_w<<<256, 256, 0, stream>>>(ew1, w1p, 512, 1024, 1);
  pack_w<<<128, 256, 0, stream>>>(nw1, nw1cat, 512, 512, 0);             // nw1a
  pack_w<<<128, 256, 0, stream>>>(nw1 + 512 * 512, nw1bp, 512, 512, 0);  // nw1b
  pack_w<<<128, 256, 0, stream>>>(ew2, w2p, 512, 512, 0);
  pack_w<<<128, 256, 0, stream>>>(nw2, nw2p, 512, 512, 0);
  pack_w<<<128, 256, 0, stream>>>(nw3, nw3p, 512, 512, 0);
  fold_w3<<<513, 64, 0, stream>>>(ew3, few, eb3, feb, w3f);
  fold_bvec<<<8, 64, 0, stream>>>(nb1, eb3, nw1, bvec);
  gemm_w3n<<<dim3(8, 4), 256, 0, stream>>>(ew3, nw1bp, w3n);
  pack_w<<<128, 256, 0, stream>>>(w3n, nw1cat + 512 * 512, 512, 512, 0); // w3n
  cast_node<<<7168, 256, 0, stream>>>(states, nodeb, (int)(NV * 512 / 8));

  // Pass 1
  gemm64_0<<<dim3(448, 2), 256, 0, stream>>>(nodeb, w1p, eb1, PQ);
  edge0_kernel<<<4096, 512, 0, stream>>>(PQ, w2p, eb2, eg, ebt, hsumb);
  // Node update + head + PQ for pass 2 (fused)
  node_mega<<<448, 512, 0, stream>>>(nodeb, hsumb, nw1cat, nw2p, nw3p, w1p,
                                     bvec, nb2, ng, nbt, nb3, fnw, fnb, eb1, PQ, out);
  // Pass 2 edge head
  edge1_kernel<<<4096, 512, 0, stream>>>(PQ, w2p, eb2, eg, ebt, w3f, out);
}

// Round 17
// 576.027 us; speedup vs baseline: 1.3496x; 1.3496x over previous
//
#include <hip/hip_runtime.h>

#define LN_EPS 1e-5f

typedef unsigned short u16;
typedef u16 u16x8 __attribute__((ext_vector_type(8)));
typedef __bf16 bf16x8 __attribute__((ext_vector_type(8)));
typedef float f32x4 __attribute__((ext_vector_type(4)));
typedef float f32x2 __attribute__((ext_vector_type(2)));

__device__ __forceinline__ u16 f2bf(float f){
  return __builtin_bit_cast(u16, (__bf16)f);
}
__device__ __forceinline__ float bf2f(u16 b){
  return (float)__builtin_bit_cast(__bf16, b);
}
__device__ __forceinline__ f32x4 mfma16(u16x8 a, u16x8 b, f32x4 c){
  return __builtin_amdgcn_mfma_f32_16x16x32_bf16(
      __builtin_bit_cast(bf16x8, a), __builtin_bit_cast(bf16x8, b), c, 0, 0, 0);
}
// LDS h-tile: [64 rows][512 k] bf16, XOR swizzle on k (8-elem granules)
__device__ __forceinline__ int uidx(int row, int k){
  return row * 512 + (k ^ ((row & 7) << 3));
}

__device__ __forceinline__ void zero_acc(f32x4 (&acc)[4][4]){
  #pragma unroll
  for (int mt = 0; mt < 4; ++mt)
    #pragma unroll
    for (int ct = 0; ct < 4; ++ct){
      f32x4 z = {0.f, 0.f, 0.f, 0.f};
      acc[mt][ct] = z;
    }
}

// Issue first kt's 4 B-fragment loads BEFORE the preceding barrier (in flight
// across s_barrier; hides cold-start L2 latency).
__device__ __forceinline__ void preload_b4(const u16* __restrict__ Bp, int wave, int lane,
                                           u16x8 (&b)[4]){
  const u16* bb = Bp + ((size_t)(wave * 4) * 64 + lane) * 8;
  #pragma unroll
  for (int ct = 0; ct < 4; ++ct) b[ct] = *(const u16x8*)&bb[ct * 512];
}

// GEMM, A from LDS (64 rows), B from global (N=512 packing, kt-stride 16384),
// 1-deep register prefetch (~64 VGPR clean). b_cur arrives preloaded.
__device__ __forceinline__ void gemm_pipe(const u16* hA, const u16* __restrict__ Bp,
                                          f32x4 (&acc)[4][4], int wave, int lane,
                                          u16x8 (&b_cur)[4]){
  int lrow = lane & 15, lhi = lane >> 4;
  const u16* bb = Bp + ((size_t)(wave * 4) * 64 + lane) * 8;
  u16x8 b_nxt[4], a[4];
  #pragma unroll
  for (int kt = 0; kt < 16; ++kt){
    #pragma unroll
    for (int mt = 0; mt < 4; ++mt)
      a[mt] = *(const u16x8*)&hA[uidx(mt * 16 + lrow, kt * 32 + lhi * 8)];
    if (kt < 15){
      #pragma unroll
      for (int ct = 0; ct < 4; ++ct)
        b_nxt[ct] = *(const u16x8*)&bb[(size_t)(kt + 1) * 16384 + ct * 512];
    }
    __builtin_amdgcn_s_setprio(1);
    #pragma unroll
    for (int ct = 0; ct < 4; ++ct)
      #pragma unroll
      for (int mt = 0; mt < 4; ++mt)
        acc[mt][ct] = mfma16(a[mt], b_cur[ct], acc[mt][ct]);
    __builtin_amdgcn_s_setprio(0);
    #pragma unroll
    for (int ct = 0; ct < 4; ++ct) b_cur[ct] = b_nxt[ct];
  }
}

// K=1024 GEMM, A rows from TWO global sources (nodeb | hsumb), B packed K=1024
// (kt-stride 16384, KT=32).
__device__ __forceinline__ void gemm_k1024_gA(const u16* __restrict__ A0,
                                              const u16* __restrict__ A1, size_t row0,
                                              const u16* __restrict__ Bp,
                                              f32x4 (&acc)[4][4], int wave, int lane){
  int lrow = lane & 15, lhi = lane >> 4;
  const u16* bb = Bp + ((size_t)(wave * 4) * 64 + lane) * 8;
  const u16* a0 = A0 + (row0 + lrow) * 512 + lhi * 8;
  const u16* a1 = A1 + (row0 + lrow) * 512 + lhi * 8;
  u16x8 b_cur[4], b_nxt[4], a[4];
  #pragma unroll
  for (int ct = 0; ct < 4; ++ct) b_cur[ct] = *(const u16x8*)&bb[ct * 512];
  #pragma unroll
  for (int kt = 0; kt < 32; ++kt){
    const u16* ab = (kt < 16) ? a0 : a1;
    int kk = (kt & 15) * 32;
    #pragma unroll
    for (int mt = 0; mt < 4; ++mt)
      a[mt] = *(const u16x8*)&ab[mt * 8192 + kk];
    if (kt < 31){
      #pragma unroll
      for (int ct = 0; ct < 4; ++ct)
        b_nxt[ct] = *(const u16x8*)&bb[(size_t)(kt + 1) * 16384 + ct * 512];
    }
    __builtin_amdgcn_s_setprio(1);
    #pragma unroll
    for (int ct = 0; ct < 4; ++ct)
      #pragma unroll
      for (int mt = 0; mt < 4; ++mt)
        acc[mt][ct] = mfma16(a[mt], b_cur[ct], acc[mt][ct]);
    __builtin_amdgcn_s_setprio(0);
    #pragma unroll
    for (int ct = 0; ct < 4; ++ct) b_cur[ct] = b_nxt[ct];
  }
}

// GEMM over hA with custom B base/kt-stride (for N=1024 w1p packing).
__device__ __forceinline__ void gemm_pipe_s(const u16* hA, const u16* __restrict__ bbBase,
                                            int ktStride, f32x4 (&acc)[4][4],
                                            int lane){
  int lrow = lane & 15, lhi = lane >> 4;
  u16x8 b_cur[4], b_nxt[4], a[4];
  #pragma unroll
  for (int ct = 0; ct < 4; ++ct) b_cur[ct] = *(const u16x8*)&bbBase[ct * 512];
  #pragma unroll
  for (int kt = 0; kt < 16; ++kt){
    #pragma unroll
    for (int mt = 0; mt < 4; ++mt)
      a[mt] = *(const u16x8*)&hA[uidx(mt * 16 + lrow, kt * 32 + lhi * 8)];
    if (kt < 15){
      #pragma unroll
      for (int ct = 0; ct < 4; ++ct)
        b_nxt[ct] = *(const u16x8*)&bbBase[(size_t)(kt + 1) * ktStride + ct * 512];
    }
    __builtin_amdgcn_s_setprio(1);
    #pragma unroll
    for (int ct = 0; ct < 4; ++ct)
      #pragma unroll
      for (int mt = 0; mt < 4; ++mt)
        acc[mt][ct] = mfma16(a[mt], b_cur[ct], acc[mt][ct]);
    __builtin_amdgcn_s_setprio(0);
    #pragma unroll
    for (int ct = 0; ct < 4; ++ct) b_cur[ct] = b_nxt[ct];
  }
}

__device__ __forceinline__ void add_bias8(f32x4 (&acc)[4][4], const float* __restrict__ b,
                                          int wave, int lane){
  int lrow = lane & 15;
  #pragma unroll
  for (int ct = 0; ct < 4; ++ct){
    float bb = b[wave * 64 + ct * 16 + lrow];
    #pragma unroll
    for (int mt = 0; mt < 4; ++mt)
      #pragma unroll
      for (int r = 0; r < 4; ++r) acc[mt][ct][r] += bb;
  }
}

// acc += bias; relu; write bf16 into hA (swizzled). (r1 stage of node MLP.)
__device__ __forceinline__ void relu_to_lds(f32x4 (&acc)[4][4], u16* hA,
                                            const float* __restrict__ b,
                                            int wave, int lane){
  int lrow = lane & 15, lhi = lane >> 4;
  #pragma unroll
  for (int ct = 0; ct < 4; ++ct){
    int c = wave * 64 + ct * 16 + lrow;
    float bb = b[c];
    #pragma unroll
    for (int mt = 0; mt < 4; ++mt)
      #pragma unroll
      for (int r = 0; r < 4; ++r){
        int row = mt * 16 + lhi * 4 + r;
        hA[uidx(row, c)] = f2bf(fmaxf(acc[mt][ct][r] + bb, 0.f));
      }
  }
}

// acc += b2; LayerNorm over 512 cols per row; relu.  (r15-measured: 64 VGPR)
// TO_ACC=0: write bf16 into hA (swizzled); TO_ACC=1: result into acc.
template<int TO_ACC>
__device__ __forceinline__ void ln_relu8_t(f32x4 (&acc)[4][4], u16* hA,
    f32x2 (*stats)[8], f32x2* mufb,
    const float* __restrict__ b2, const float* __restrict__ g, const float* __restrict__ bt,
    int wave, int lane, int tid)
{
  int lrow = lane & 15, lhi = lane >> 4;
  float s1[4][4], s2[4][4];
  #pragma unroll
  for (int mt = 0; mt < 4; ++mt)
    #pragma unroll
    for (int r = 0; r < 4; ++r){ s1[mt][r] = 0.f; s2[mt][r] = 0.f; }
  #pragma unroll
  for (int ct = 0; ct < 4; ++ct){
    int c = wave * 64 + ct * 16 + lrow;
    float bb = b2[c];
    #pragma unroll
    for (int mt = 0; mt < 4; ++mt)
      #pragma unroll
      for (int r = 0; r < 4; ++r){
        float x = acc[mt][ct][r] + bb;
        acc[mt][ct][r] = x;
        s1[mt][r] += x; s2[mt][r] += x * x;
      }
  }
  #pragma unroll
  for (int off = 1; off < 16; off <<= 1){
    #pragma unroll
    for (int mt = 0; mt < 4; ++mt)
      #pragma unroll
      for (int r = 0; r < 4; ++r){
        s1[mt][r] += __shfl_xor(s1[mt][r], off);
        s2[mt][r] += __shfl_xor(s2[mt][r], off);
      }
  }
  float sa1 = 0.f, sa2 = 0.f;
  #pragma unroll
  for (int mt = 0; mt < 4; ++mt)
    #pragma unroll
    for (int r = 0; r < 4; ++r)
      if (lrow == mt * 4 + r){ sa1 = s1[mt][r]; sa2 = s2[mt][r]; }
  int rowa = (lrow >> 2) * 16 + lhi * 4 + (lrow & 3);
  f32x2 pa = {sa1, sa2};
  stats[rowa][wave] = pa;
  __syncthreads();              // also: all waves done reading hA (prev GEMM)
  if (tid < 64){
    float a = 0.f, b = 0.f;
    #pragma unroll
    for (int w = 0; w < 8; ++w){ a += stats[tid][w][0]; b += stats[tid][w][1]; }
    float mu  = a * (1.f / 512.f);
    float var = b * (1.f / 512.f) - mu * mu;
    f32x2 mr = {mu, rsqrtf(fmaxf(var, 0.f) + LN_EPS)};
    mufb[tid] = mr;
  }
  __syncthreads();
  float gv[4], btv[4];
  #pragma unroll
  for (int ct = 0; ct < 4; ++ct){
    int c = wave * 64 + ct * 16 + lrow;
    gv[ct] = g[c]; btv[ct] = bt[c];
  }
  #pragma unroll
  for (int mt = 0; mt < 4; ++mt)
    #pragma unroll
    for (int r = 0; r < 4; ++r){
      int row = mt * 16 + lhi * 4 + r;
      f32x2 mr = mufb[row];
      #pragma unroll
      for (int ct = 0; ct < 4; ++ct){
        int c = wave * 64 + ct * 16 + lrow;
        float x = (acc[mt][ct][r] - mr[0]) * mr[1] * gv[ct] + btv[ct];
        if (TO_ACC) acc[mt][ct][r] = fmaxf(x, 0.f);
        else        hA[uidx(row, c)] = f2bf(fmaxf(x, 0.f));
      }
    }
  // TO_ACC=0 caller: barrier before any cross-thread hA read.
}

// dot each row with weight vector w; per-wave partial -> stats[row][wave].x
__device__ __forceinline__ void head_partial8(f32x4 (&acc)[4][4], const float* __restrict__ w,
                                              f32x2 (*stats)[8], int wave, int lane)
{
  int lrow = lane & 15, lhi = lane >> 4;
  float hs[4][4];
  #pragma unroll
  for (int mt = 0; mt < 4; ++mt)
    #pragma unroll
    for (int r = 0; r < 4; ++r) hs[mt][r] = 0.f;
  #pragma unroll
  for (int ct = 0; ct < 4; ++ct){
    int c = wave * 64 + ct * 16 + lrow;
    float f = w[c];
    #pragma unroll
    for (int mt = 0; mt < 4; ++mt)
      #pragma unroll
      for (int r = 0; r < 4; ++r) hs[mt][r] += acc[mt][ct][r] * f;
  }
  #pragma unroll
  for (int off = 1; off < 16; off <<= 1)
    #pragma unroll
    for (int mt = 0; mt < 4; ++mt)
      #pragma unroll
      for (int r = 0; r < 4; ++r) hs[mt][r] += __shfl_xor(hs[mt][r], off);
  float sa = 0.f;
  #pragma unroll
  for (int mt = 0; mt < 4; ++mt)
    #pragma unroll
    for (int r = 0; r < 4; ++r)
      if (lrow == mt * 4 + r) sa = hs[mt][r];
  int rowa = (lrow >> 2) * 16 + lhi * 4 + (lrow & 3);
  f32x2 pa = {sa, 0.f};
  stats[rowa][wave] = pa;
}

// Staging: h1 = relu(P'[i]+Q[j]) into hA rows 0..48 (+ zero pad rows 49..63).
// b1 pre-folded into P' at PQ-GEMM output (saves bias regs + VALU here).
__device__ __forceinline__ void stage_h1(const u16* __restrict__ PQ, int gg, u16* hA,
                                         int wave, int lane){
  const u16* Pg = PQ + (size_t)gg * 7 * 1024;
  u16x8 pA, qA, pB, qB;
  {
    int e = wave;
    int i = e / 7, j = e % 7;
    pA = *(const u16x8*)&Pg[(size_t)i * 1024 + lane * 8];
    qA = *(const u16x8*)&Pg[(size_t)j * 1024 + 512 + lane * 8];
  }
  #pragma unroll
  for (int it = 0; it < 8; ++it){
    int e = it * 8 + wave;
    if (it < 7){
      int e2 = e + 8;
      if (e2 < 49){
        int i = e2 / 7, j = e2 % 7;
        pB = *(const u16x8*)&Pg[(size_t)i * 1024 + lane * 8];
        qB = *(const u16x8*)&Pg[(size_t)j * 1024 + 512 + lane * 8];
      }
    }
    u16x8 o;
    if (e < 49){
      #pragma unroll
      for (int u = 0; u < 8; ++u)
        o[u] = f2bf(fmaxf(bf2f(pA[u]) + bf2f(qA[u]), 0.f));
    } else {
      #pragma unroll
      for (int u = 0; u < 8; ++u) o[u] = 0;
    }
    *(u16x8*)&hA[uidx(e, lane * 8)] = o;
    pA = pB; qA = qB;
  }
}

// ======== edge pass 0: stage -> GEMM1(w2) -> LN -> colsum -> hsum (global) ======
__global__ __launch_bounds__(512, 2) void edge0_kernel(
    const u16* __restrict__ PQ, const u16* __restrict__ w2p,
    const float* __restrict__ b2,
    const float* __restrict__ g, const float* __restrict__ bt,
    u16* __restrict__ hsum)
{
  __shared__ alignas(16) u16 hA[64 * 512];
  __shared__ f32x2 stats[64][8];
  __shared__ f32x2 mufb[64];
  int gidx = blockIdx.x;
  int tid = threadIdx.x;
  int wave = tid >> 6, lane = tid & 63;

  stage_h1(PQ, gidx, hA, wave, lane);
  u16x8 bpre[4];
  preload_b4(w2p, wave, lane, bpre);
  __syncthreads();

  f32x4 acc[4][4];
  zero_acc(acc);
  gemm_pipe(hA, w2p, acc, wave, lane, bpre);
  ln_relu8_t<0>(acc, hA, stats, mufb, b2, g, bt, wave, lane, tid);
  __syncthreads();                    // h2n rows 0..48 visible
  // column sums: hsum[i][c] = sum_j h2n[7i+j][c] -> global (bf16, coalesced)
  {
    int c = tid;   // 0..511
    #pragma unroll
    for (int i = 0; i < 7; ++i){
      float s = 0.f;
      #pragma unroll
      for (int j = 0; j < 7; ++j)
        s += bf2f(hA[uidx(7 * i + j, c)]);
      hsum[((size_t)(gidx * 7 + i)) * 512 + c] = f2bf(s);
    }
  }
}

// ============ edge pass 1: w3 folded to a vector (w3f = ew3@few) ============
__global__ __launch_bounds__(512, 2) void edge1_kernel(
    const u16* __restrict__ PQ, const u16* __restrict__ w2p,
    const float* __restrict__ b2,
    const float* __restrict__ g, const float* __restrict__ bt,
    const float* __restrict__ w3f, float* __restrict__ out)
{
  __shared__ alignas(16) u16 hA[64 * 512];
  __shared__ f32x2 stats[64][8];
  __shared__ f32x2 mufb[64];
  int gidx = blockIdx.x;
  int tid = threadIdx.x;
  int wave = tid >> 6, lane = tid & 63;

  stage_h1(PQ, gidx, hA, wave, lane);
  u16x8 bpre[4];
  preload_b4(w2p, wave, lane, bpre);
  __syncthreads();

  f32x4 acc[4][4];
  zero_acc(acc);
  gemm_pipe(hA, w2p, acc, wave, lane, bpre);
  ln_relu8_t<1>(acc, hA, stats, mufb, b2, g, bt, wave, lane, tid);  // acc := relu(LN)
  head_partial8(acc, w3f, stats, wave, lane);
  __syncthreads();
  if (tid < 49){
    float s = w3f[512];   // eb3.few + feb
    #pragma unroll
    for (int w = 0; w < 8; ++w) s += stats[tid][w][0];
    out[(size_t)gidx * 56 + 7 + tid] = s;
  }
}

// ==== node mega-kernel: r1 -> h2 -> LN -> node2 (+head) -> PQ (pass 2) ====
__global__ __launch_bounds__(512, 2) void node_mega(
    const u16* __restrict__ nodeb, const u16* __restrict__ hsumb,
    const u16* __restrict__ nw1cat, const u16* __restrict__ nw2p,
    const u16* __restrict__ nw3p, const u16* __restrict__ w1p,
    const float* __restrict__ bvec, const float* __restrict__ nb2,
    const float* __restrict__ ng, const float* __restrict__ nbt,
    const float* __restrict__ nb3, const float* __restrict__ hw,
    const float* __restrict__ hb, const float* __restrict__ b1,
    u16* __restrict__ PQ, float* __restrict__ out)
{
  __shared__ alignas(16) u16 hA[64 * 512];
  __shared__ f32x2 stats[64][8];
  __shared__ f32x2 mufb[64];
  int tid = threadIdx.x;
  int wave = tid >> 6, lane = tid & 63;
  int lrow = lane & 15, lhi = lane >> 4;
  size_t row0 = (size_t)blockIdx.x * 64;

  // r1 = relu([nodeb|hsumb] @ [nw1a|w3n] + bvec)  (K=1024, A from global)
  f32x4 acc[4][4];
  zero_acc(acc);
  gemm_k1024_gA(nodeb, hsumb, row0, nw1cat, acc, wave, lane);
  relu_to_lds(acc, hA, bvec, wave, lane);
  u16x8 bpre[4];
  preload_b4(nw2p, wave, lane, bpre);
  __syncthreads();
  // h2 = r1 @ nw2 (+nb2 in LN) -> LN -> relu -> hA
  zero_acc(acc);
  gemm_pipe(hA, nw2p, acc, wave, lane, bpre);
  ln_relu8_t<0>(acc, hA, stats, mufb, nb2, ng, nbt, wave, lane, tid);
  preload_b4(nw3p, wave, lane, bpre);
  __syncthreads();
  // node2 = h2n @ nw3 + nb3
  zero_acc(acc);
  gemm_pipe(hA, nw3p, acc, wave, lane, bpre);
  add_bias8(acc, nb3, wave, lane);
  __syncthreads();   // all GEMM reads of hA (h2n) done before overwrite
  // node2 -> hA (for PQ GEMMs); head partial
  #pragma unroll
  for (int ct = 0; ct < 4; ++ct){
    int c = wave * 64 + ct * 16 + lrow;
    #pragma unroll
    for (int mt = 0; mt < 4; ++mt)
      #pragma unroll
      for (int r = 0; r < 4; ++r)
        hA[uidx(mt * 16 + lhi * 4 + r, c)] = f2bf(acc[mt][ct][r]);
  }
  head_partial8(acc, hw, stats, wave, lane);
  __syncthreads();   // node2 + stats visible
  if (tid < 64){
    size_t v = row0 + tid;
    float s = hb[0];
    #pragma unroll
    for (int w = 0; w < 8; ++w) s += stats[tid][w][0];
    out[(v / 7) * 56 + (v % 7)] = s;
  }
  // PQ = node2 @ w1p  (N=1024, two 512-col passes; P half gets +b1)
  #pragma unroll
  for (int pp = 0; pp < 2; ++pp){
    zero_acc(acc);
    const u16* bbBase = w1p + (((size_t)(pp * 32) + wave * 4) * 64 + lane) * 8;
    gemm_pipe_s(hA, bbBase, 32768, acc, lane);
    #pragma unroll
    for (int ct = 0; ct < 4; ++ct){
      int cc = wave * 64 + ct * 16 + lrow;
      int c = pp * 512 + cc;
      float bb = (pp == 0) ? b1[cc] : 0.f;
      #pragma unroll
      for (int mt = 0; mt < 4; ++mt)
        #pragma unroll
        for (int r = 0; r < 4; ++r){
          size_t grow = row0 + mt * 16 + lhi * 4 + r;
          PQ[grow * 1024 + c] = f2bf(acc[mt][ct][r] + bb);
        }
    }
  }
}

// gemm64 MODE0: PQ = nodeb @ w1p (pass 1); P half (coff==0) gets +b1.
__global__ __launch_bounds__(256, 2) void gemm64_0(
    const u16* __restrict__ A0, const u16* __restrict__ Bp,
    const float* __restrict__ b1, u16* __restrict__ Cout)
{
  int tid = threadIdx.x;
  int wave = tid >> 6, lane = tid & 63;
  int lrow = lane & 15, lhi = lane >> 4;
  size_t row0 = (size_t)blockIdx.x * 64;
  int coff = blockIdx.y * 512;
  const u16* bb = Bp + (((size_t)(coff >> 4) + wave * 8) * 64 + lane) * 8;
  f32x4 acc[4][8];
  #pragma unroll
  for (int mt = 0; mt < 4; ++mt)
    #pragma unroll
    for (int ct = 0; ct < 8; ++ct){
      f32x4 z = {0.f, 0.f, 0.f, 0.f};
      acc[mt][ct] = z;
    }
  u16x8 b_cur[8], b_nxt[8];
  #pragma unroll
  for (int ct = 0; ct < 8; ++ct) b_cur[ct] = *(const u16x8*)&bb[ct * 512];
  #pragma unroll
  for (int kt = 0; kt < 16; ++kt){
    u16x8 af[4];
    #pragma unroll
    for (int mt = 0; mt < 4; ++mt)
      af[mt] = *(const u16x8*)&A0[(row0 + mt * 16 + lrow) * 512 + kt * 32 + lhi * 8];
    if (kt < 15){
      #pragma unroll
      for (int ct = 0; ct < 8; ++ct)
        b_nxt[ct] = *(const u16x8*)&bb[((size_t)(kt + 1) * 64 * 64 + ct * 64) * 8];
    }
    __builtin_amdgcn_s_setprio(1);
    #pragma unroll
    for (int ct = 0; ct < 8; ++ct)
      #pragma unroll
      for (int mt = 0; mt < 4; ++mt) acc[mt][ct] = mfma16(af[mt], b_cur[ct], acc[mt][ct]);
    __builtin_amdgcn_s_setprio(0);
    #pragma unroll
    for (int ct = 0; ct < 8; ++ct) b_cur[ct] = b_nxt[ct];
  }
  #pragma unroll
  for (int ct = 0; ct < 8; ++ct){
    int cc = wave * 128 + ct * 16 + lrow;
    int c = coff + cc;
    float bb2 = (coff == 0) ? b1[cc] : 0.f;
    #pragma unroll
    for (int mt = 0; mt < 4; ++mt)
      #pragma unroll
      for (int r = 0; r < 4; ++r){
        size_t grow = row0 + mt * 16 + lhi * 4 + r;
        Cout[grow * 1024 + c] = f2bf(acc[mt][ct][r] + bb2);
      }
  }
}

// w3n = ew3(f32) @ nw1b(packed bf16): 512x512, K=512. Grid (8,4): 64 rows x 128 cols.
__global__ __launch_bounds__(256) void gemm_w3n(
    const float* __restrict__ A, const u16* __restrict__ Bp, float* __restrict__ C)
{
  int tid = threadIdx.x;
  int wave = tid >> 6, lane = tid & 63;
  int lrow = lane & 15, lhi = lane >> 4;
  size_t row0 = (size_t)blockIdx.x * 64;
  int coff = blockIdx.y * 128;
  const u16* bb = Bp + (((size_t)(coff >> 4) + wave * 2) * 64 + lane) * 8;
  f32x4 acc[4][2];
  #pragma unroll
  for (int mt = 0; mt < 4; ++mt)
    #pragma unroll
    for (int ct = 0; ct < 2; ++ct){
      f32x4 z = {0.f, 0.f, 0.f, 0.f};
      acc[mt][ct] = z;
    }
  for (int kt = 0; kt < 16; ++kt){
    u16x8 af[4], bv[2];
    #pragma unroll
    for (int mt = 0; mt < 4; ++mt){
      const float* ar = A + (row0 + mt * 16 + lrow) * 512 + kt * 32 + lhi * 8;
      float4 v0 = *(const float4*)ar, v1 = *(const float4*)(ar + 4);
      af[mt][0] = f2bf(v0.x); af[mt][1] = f2bf(v0.y);
      af[mt][2] = f2bf(v0.z); af[mt][3] = f2bf(v0.w);
      af[mt][4] = f2bf(v1.x); af[mt][5] = f2bf(v1.y);
      af[mt][6] = f2bf(v1.z); af[mt][7] = f2bf(v1.w);
    }
    #pragma unroll
    for (int ct = 0; ct < 2; ++ct)
      bv[ct] = *(const u16x8*)&bb[(size_t)kt * 16384 + ct * 512];
    #pragma unroll
    for (int ct = 0; ct < 2; ++ct)
      #pragma unroll
      for (int mt = 0; mt < 4; ++mt) acc[mt][ct] = mfma16(af[mt], bv[ct], acc[mt][ct]);
  }
  #pragma unroll
  for (int ct = 0; ct < 2; ++ct){
    int c = coff + wave * 32 + ct * 16 + lrow;
    #pragma unroll
    for (int mt = 0; mt < 4; ++mt)
      #pragma unroll
      for (int r = 0; r < 4; ++r){
        size_t grow = row0 + mt * 16 + lhi * 4 + r;
        C[grow * 512 + c] = acc[mt][ct][r];
      }
  }
}

// bvec[c] = nb1[c] + 7 * sum_m b3[m] * nw1[512+m][c]   (grid 8 x 64 threads)
__global__ void fold_bvec(const float* __restrict__ nb1, const float* __restrict__ b3,
                          const float* __restrict__ nw1, float* __restrict__ bvec)
{
  int c = blockIdx.x * 64 + threadIdx.x;
  float s = 0.f;
  for (int m = 0; m < 512; ++m)
    s += b3[m] * nw1[(size_t)(512 + m) * 512 + c];
  bvec[c] = nb1[c] + 7.f * s;
}

// w3f[k] = sum_c ew3[k][c]*few[c]  (f32); w3f[512] = eb3.few + feb
__global__ void fold_w3(const float* __restrict__ W3, const float* __restrict__ hw,
                        const float* __restrict__ b3, const float* __restrict__ hb,
                        float* __restrict__ w3f)
{
  int k = blockIdx.x, l = threadIdx.x;
  const float* row = (k < 512) ? (W3 + (size_t)k * 512) : b3;
  float s = 0.f;
  for (int c = l; c < 512; c += 64) s += row[c] * hw[c];
  #pragma unroll
  for (int off = 32; off; off >>= 1) s += __shfl_down(s, off);
  if (l == 0) w3f[k] = (k < 512) ? s : s + hb[0];
}

// Pack f32 weight [K][N] into MFMA B-fragment order (bf16).
__global__ void pack_w(const float* __restrict__ W, u16* __restrict__ dst,
                       int K, int N, int w1mode)
{
  int idx = blockIdx.x * 256 + threadIdx.x;
  int total = (K >> 5) * (N >> 4) * 64;
  if (idx >= total) return;
  int lane = idx & 63;
  int t = idx >> 6;
  int nt = N >> 4;
  int ct = t % nt;
  int kt = t / nt;
  int c  = ct * 16 + (lane & 15);
  int k0 = kt * 32 + (lane >> 4) * 8;
  u16x8 o;
  #pragma unroll
  for (int j = 0; j < 8; ++j){
    int k = k0 + j;
    float v;
    if (w1mode){
      v = (c < 512) ? W[(size_t)k * 512 + c] : W[(size_t)(k + 512) * 512 + (c - 512)];
    } else {
      v = W[(size_t)k * N + c];
    }
    o[j] = f2bf(v);
  }
  *(u16x8*)&dst[(size_t)idx * 8] = o;
}

__global__ void cast_node(const float* __restrict__ src, u16* __restrict__ dst, int n8){
  int idx = blockIdx.x * 256 + threadIdx.x;
  if (idx >= n8) return;
  const float4* s = (const float4*)src;
  float4 a = s[(size_t)idx * 2], b = s[(size_t)idx * 2 + 1];
  u16x8 o;
  o[0] = f2bf(a.x); o[1] = f2bf(a.y); o[2] = f2bf(a.z); o[3] = f2bf(a.w);
  o[4] = f2bf(b.x); o[5] = f2bf(b.y); o[6] = f2bf(b.z); o[7] = f2bf(b.w);
  *(u16x8*)&dst[(size_t)idx * 8] = o;
}

extern "C" void kernel_launch(void* const* d_in, const int* in_sizes, int n_in,
                              void* d_out, int out_size, void* d_ws, size_t ws_size,
                              hipStream_t stream)
{
  (void)in_sizes; (void)n_in; (void)out_size; (void)ws_size;
  const float* states = (const float*)d_in[0];
  const float* ew1 = (const float*)d_in[1];
  const float* eb1 = (const float*)d_in[2];
  const float* ew2 = (const float*)d_in[3];
  const float* eb2 = (const float*)d_in[4];
  const float* eg  = (const float*)d_in[5];
  const float* ebt = (const float*)d_in[6];
  const float* ew3 = (const float*)d_in[7];
  const float* eb3 = (const float*)d_in[8];
  const float* nw1 = (const float*)d_in[9];
  const float* nb1 = (const float*)d_in[10];
  const float* nw2 = (const float*)d_in[11];
  const float* nb2 = (const float*)d_in[12];
  const float* ng  = (const float*)d_in[13];
  const float* nbt = (const float*)d_in[14];
  const float* nw3 = (const float*)d_in[15];
  const float* nb3 = (const float*)d_in[16];
  const float* fnw = (const float*)d_in[17];
  const float* fnb = (const float*)d_in[18];
  const float* few = (const float*)d_in[19];
  const float* feb = (const float*)d_in[20];
  float* out = (float*)d_out;

  char* ws = (char*)d_ws;
  size_t off = 0;
  auto alloc = [&](size_t bytes) -> void* {
    void* p = ws + off;
    off += (bytes + 255) & ~(size_t)255;
    return p;
  };
  const size_t NV = 28672;  // B*n
  u16* PQ     = (u16*)alloc(NV * 1024 * 2);   // [NV][P'(512)|Q(512)] bf16 (P' = P+b1)
  u16* nodeb  = (u16*)alloc(NV * 512 * 2);
  u16* hsumb  = (u16*)alloc(NV * 512 * 2);
  u16* w1p    = (u16*)alloc(512 * 1024 * 2);
  u16* nw1cat = (u16*)alloc(1024 * 512 * 2);  // [nw1a packed | w3n packed]
  u16* nw1bp  = (u16*)alloc(512 * 512 * 2);
  u16* w2p    = (u16*)alloc(512 * 512 * 2);
  u16* nw2p   = (u16*)alloc(512 * 512 * 2);
  u16* nw3p   = (u16*)alloc(512 * 512 * 2);
  float* w3n  = (float*)alloc(512 * 512 * 4);
  float* w3f  = (float*)alloc(513 * 4);
  float* bvec = (float*)alloc(512 * 4);

  pack_w<<<256, 256, 0, stream>>>(ew1, w1p, 512, 1024, 1);
  pack_w<<<128, 256, 0, stream>>>(nw1, nw1cat, 512, 512, 0);             // nw1a
  pack_w<<<128, 256, 0, stream>>>(nw1 + 512 * 512, nw1bp, 512, 512, 0);  // nw1b
  pack_w<<<128, 256, 0, stream>>>(ew2, w2p, 512, 512, 0);
  pack_w<<<128, 256, 0, stream>>>(nw2, nw2p, 512, 512, 0);
  pack_w<<<128, 256, 0, stream>>>(nw3, nw3p, 512, 512, 0);
  fold_w3<<<513, 64, 0, stream>>>(ew3, few, eb3, feb, w3f);
  fold_bvec<<<8, 64, 0, stream>>>(nb1, eb3, nw1, bvec);
  gemm_w3n<<<dim3(8, 4), 256, 0, stream>>>(ew3, nw1bp, w3n);
  pack_w<<<128, 256, 0, stream>>>(w3n, nw1cat + 512 * 512, 512, 512, 0); // w3n
  cast_node<<<7168, 256, 0, stream>>>(states, nodeb, (int)(NV * 512 / 8));

  // Pass 1
  gemm64_0<<<dim3(448, 2), 256, 0, stream>>>(nodeb, w1p, eb1, PQ);
  edge0_kernel<<<4096, 512, 0, stream>>>(PQ, w2p, eb2, eg, ebt, hsumb);
  // Node update + head + PQ for pass 2 (fused)
  node_mega<<<448, 512, 0, stream>>>(nodeb, hsumb, nw1cat, nw2p, nw3p, w1p,
                                     bvec, nb2, ng, nbt, nb3, fnw, fnb, eb1, PQ, out);
  // Pass 2 edge head
  edge1_kernel<<<4096, 512, 0, stream>>>(PQ, w2p, eb2, eg, ebt, w3f, out);
}

// Round 18
// 556.414 us; speedup vs baseline: 1.3972x; 1.0353x over previous
//
#include <hip/hip_runtime.h>

#define LN_EPS 1e-5f

typedef unsigned short u16;
typedef u16 u16x8 __attribute__((ext_vector_type(8)));
typedef __bf16 bf16x8 __attribute__((ext_vector_type(8)));
typedef float f32x4 __attribute__((ext_vector_type(4)));
typedef float f32x2 __attribute__((ext_vector_type(2)));

__device__ __forceinline__ u16 f2bf(float f){
  return __builtin_bit_cast(u16, (__bf16)f);
}
__device__ __forceinline__ float bf2f(u16 b){
  return (float)__builtin_bit_cast(__bf16, b);
}
__device__ __forceinline__ f32x4 mfma16(u16x8 a, u16x8 b, f32x4 c){
  return __builtin_amdgcn_mfma_f32_16x16x32_bf16(
      __builtin_bit_cast(bf16x8, a), __builtin_bit_cast(bf16x8, b), c, 0, 0, 0);
}
// LDS h-tile: [64 rows][512 k] bf16, XOR swizzle on k (8-elem granules)
__device__ __forceinline__ int uidx(int row, int k){
  return row * 512 + (k ^ ((row & 7) << 3));
}

__device__ __forceinline__ void zero_acc(f32x4 (&acc)[4][4]){
  #pragma unroll
  for (int mt = 0; mt < 4; ++mt)
    #pragma unroll
    for (int ct = 0; ct < 4; ++ct){
      f32x4 z = {0.f, 0.f, 0.f, 0.f};
      acc[mt][ct] = z;
    }
}

// Issue first kt's 4 B-fragment loads BEFORE the preceding barrier (in flight
// across s_barrier; hides cold-start L2 latency).
__device__ __forceinline__ void preload_b4(const u16* __restrict__ Bp, int wave, int lane,
                                           u16x8 (&b)[4]){
  const u16* bb = Bp + ((size_t)(wave * 4) * 64 + lane) * 8;
  #pragma unroll
  for (int ct = 0; ct < 4; ++ct) b[ct] = *(const u16x8*)&bb[ct * 512];
}

// GEMM, A from LDS (64 rows), B from global (N=512 packing, kt-stride 16384),
// 1-deep register prefetch (~64 VGPR clean). b_cur arrives preloaded.
__device__ __forceinline__ void gemm_pipe(const u16* hA, const u16* __restrict__ Bp,
                                          f32x4 (&acc)[4][4], int wave, int lane,
                                          u16x8 (&b_cur)[4]){
  int lrow = lane & 15, lhi = lane >> 4;
  const u16* bb = Bp + ((size_t)(wave * 4) * 64 + lane) * 8;
  u16x8 b_nxt[4], a[4];
  #pragma unroll
  for (int kt = 0; kt < 16; ++kt){
    #pragma unroll
    for (int mt = 0; mt < 4; ++mt)
      a[mt] = *(const u16x8*)&hA[uidx(mt * 16 + lrow, kt * 32 + lhi * 8)];
    if (kt < 15){
      #pragma unroll
      for (int ct = 0; ct < 4; ++ct)
        b_nxt[ct] = *(const u16x8*)&bb[(size_t)(kt + 1) * 16384 + ct * 512];
    }
    __builtin_amdgcn_s_setprio(1);
    #pragma unroll
    for (int ct = 0; ct < 4; ++ct)
      #pragma unroll
      for (int mt = 0; mt < 4; ++mt)
        acc[mt][ct] = mfma16(a[mt], b_cur[ct], acc[mt][ct]);
    __builtin_amdgcn_s_setprio(0);
    #pragma unroll
    for (int ct = 0; ct < 4; ++ct) b_cur[ct] = b_nxt[ct];
  }
}

// K=1024 GEMM, A rows from TWO global sources (nodeb | hsumb), B packed K=1024
// (kt-stride 16384, KT=32).
__device__ __forceinline__ void gemm_k1024_gA(const u16* __restrict__ A0,
                                              const u16* __restrict__ A1, size_t row0,
                                              const u16* __restrict__ Bp,
                                              f32x4 (&acc)[4][4], int wave, int lane){
  int lrow = lane & 15, lhi = lane >> 4;
  const u16* bb = Bp + ((size_t)(wave * 4) * 64 + lane) * 8;
  const u16* a0 = A0 + (row0 + lrow) * 512 + lhi * 8;
  const u16* a1 = A1 + (row0 + lrow) * 512 + lhi * 8;
  u16x8 b_cur[4], b_nxt[4], a[4];
  #pragma unroll
  for (int ct = 0; ct < 4; ++ct) b_cur[ct] = *(const u16x8*)&bb[ct * 512];
  #pragma unroll
  for (int kt = 0; kt < 32; ++kt){
    const u16* ab = (kt < 16) ? a0 : a1;
    int kk = (kt & 15) * 32;
    #pragma unroll
    for (int mt = 0; mt < 4; ++mt)
      a[mt] = *(const u16x8*)&ab[mt * 8192 + kk];
    if (kt < 31){
      #pragma unroll
      for (int ct = 0; ct < 4; ++ct)
        b_nxt[ct] = *(const u16x8*)&bb[(size_t)(kt + 1) * 16384 + ct * 512];
    }
    __builtin_amdgcn_s_setprio(1);
    #pragma unroll
    for (int ct = 0; ct < 4; ++ct)
      #pragma unroll
      for (int mt = 0; mt < 4; ++mt)
        acc[mt][ct] = mfma16(a[mt], b_cur[ct], acc[mt][ct]);
    __builtin_amdgcn_s_setprio(0);
    #pragma unroll
    for (int ct = 0; ct < 4; ++ct) b_cur[ct] = b_nxt[ct];
  }
}

// GEMM over hA with custom B base/kt-stride (for N=1024 w1p packing).
__device__ __forceinline__ void gemm_pipe_s(const u16* hA, const u16* __restrict__ bbBase,
                                            int ktStride, f32x4 (&acc)[4][4],
                                            int lane){
  int lrow = lane & 15, lhi = lane >> 4;
  u16x8 b_cur[4], b_nxt[4], a[4];
  #pragma unroll
  for (int ct = 0; ct < 4; ++ct) b_cur[ct] = *(const u16x8*)&bbBase[ct * 512];
  #pragma unroll
  for (int kt = 0; kt < 16; ++kt){
    #pragma unroll
    for (int mt = 0; mt < 4; ++mt)
      a[mt] = *(const u16x8*)&hA[uidx(mt * 16 + lrow, kt * 32 + lhi * 8)];
    if (kt < 15){
      #pragma unroll
      for (int ct = 0; ct < 4; ++ct)
        b_nxt[ct] = *(const u16x8*)&bbBase[(size_t)(kt + 1) * ktStride + ct * 512];
    }
    __builtin_amdgcn_s_setprio(1);
    #pragma unroll
    for (int ct = 0; ct < 4; ++ct)
      #pragma unroll
      for (int mt = 0; mt < 4; ++mt)
        acc[mt][ct] = mfma16(a[mt], b_cur[ct], acc[mt][ct]);
    __builtin_amdgcn_s_setprio(0);
    #pragma unroll
    for (int ct = 0; ct < 4; ++ct) b_cur[ct] = b_nxt[ct];
  }
}

__device__ __forceinline__ void add_bias8(f32x4 (&acc)[4][4], const float* __restrict__ b,
                                          int wave, int lane){
  int lrow = lane & 15;
  #pragma unroll
  for (int ct = 0; ct < 4; ++ct){
    float bb = b[wave * 64 + ct * 16 + lrow];
    #pragma unroll
    for (int mt = 0; mt < 4; ++mt)
      #pragma unroll
      for (int r = 0; r < 4; ++r) acc[mt][ct][r] += bb;
  }
}

// acc += bias; relu; write bf16 into hA (swizzled). (r1 stage of node MLP.)
__device__ __forceinline__ void relu_to_lds(f32x4 (&acc)[4][4], u16* hA,
                                            const float* __restrict__ b,
                                            int wave, int lane){
  int lrow = lane & 15, lhi = lane >> 4;
  #pragma unroll
  for (int ct = 0; ct < 4; ++ct){
    int c = wave * 64 + ct * 16 + lrow;
    float bb = b[c];
    #pragma unroll
    for (int mt = 0; mt < 4; ++mt)
      #pragma unroll
      for (int r = 0; r < 4; ++r){
        int row = mt * 16 + lhi * 4 + r;
        hA[uidx(row, c)] = f2bf(fmaxf(acc[mt][ct][r] + bb, 0.f));
      }
  }
}

// acc += b2; LayerNorm over 512 cols per row; relu.  (r15-measured: 64 VGPR)
// TO_ACC=0: write bf16 into hA (swizzled); TO_ACC=1: result into acc.
template<int TO_ACC>
__device__ __forceinline__ void ln_relu8_t(f32x4 (&acc)[4][4], u16* hA,
    f32x2 (*stats)[8], f32x2* mufb,
    const float* __restrict__ b2, const float* __restrict__ g, const float* __restrict__ bt,
    int wave, int lane, int tid)
{
  int lrow = lane & 15, lhi = lane >> 4;
  float s1[4][4], s2[4][4];
  #pragma unroll
  for (int mt = 0; mt < 4; ++mt)
    #pragma unroll
    for (int r = 0; r < 4; ++r){ s1[mt][r] = 0.f; s2[mt][r] = 0.f; }
  #pragma unroll
  for (int ct = 0; ct < 4; ++ct){
    int c = wave * 64 + ct * 16 + lrow;
    float bb = b2[c];
    #pragma unroll
    for (int mt = 0; mt < 4; ++mt)
      #pragma unroll
      for (int r = 0; r < 4; ++r){
        float x = acc[mt][ct][r] + bb;
        acc[mt][ct][r] = x;
        s1[mt][r] += x; s2[mt][r] += x * x;
      }
  }
  #pragma unroll
  for (int off = 1; off < 16; off <<= 1){
    #pragma unroll
    for (int mt = 0; mt < 4; ++mt)
      #pragma unroll
      for (int r = 0; r < 4; ++r){
        s1[mt][r] += __shfl_xor(s1[mt][r], off);
        s2[mt][r] += __shfl_xor(s2[mt][r], off);
      }
  }
  float sa1 = 0.f, sa2 = 0.f;
  #pragma unroll
  for (int mt = 0; mt < 4; ++mt)
    #pragma unroll
    for (int r = 0; r < 4; ++r)
      if (lrow == mt * 4 + r){ sa1 = s1[mt][r]; sa2 = s2[mt][r]; }
  int rowa = (lrow >> 2) * 16 + lhi * 4 + (lrow & 3);
  f32x2 pa = {sa1, sa2};
  stats[rowa][wave] = pa;
  __syncthreads();              // also: all waves done reading hA (prev GEMM)
  if (tid < 64){
    float a = 0.f, b = 0.f;
    #pragma unroll
    for (int w = 0; w < 8; ++w){ a += stats[tid][w][0]; b += stats[tid][w][1]; }
    float mu  = a * (1.f / 512.f);
    float var = b * (1.f / 512.f) - mu * mu;
    f32x2 mr = {mu, rsqrtf(fmaxf(var, 0.f) + LN_EPS)};
    mufb[tid] = mr;
  }
  __syncthreads();
  float gv[4], btv[4];
  #pragma unroll
  for (int ct = 0; ct < 4; ++ct){
    int c = wave * 64 + ct * 16 + lrow;
    gv[ct] = g[c]; btv[ct] = bt[c];
  }
  #pragma unroll
  for (int mt = 0; mt < 4; ++mt)
    #pragma unroll
    for (int r = 0; r < 4; ++r){
      int row = mt * 16 + lhi * 4 + r;
      f32x2 mr = mufb[row];
      #pragma unroll
      for (int ct = 0; ct < 4; ++ct){
        int c = wave * 64 + ct * 16 + lrow;
        float x = (acc[mt][ct][r] - mr[0]) * mr[1] * gv[ct] + btv[ct];
        if (TO_ACC) acc[mt][ct][r] = fmaxf(x, 0.f);
        else        hA[uidx(row, c)] = f2bf(fmaxf(x, 0.f));
      }
    }
  // TO_ACC=0 caller: barrier before any cross-thread hA read.
}

// dot each row with weight vector w; per-wave partial -> stats[row][wave].x
__device__ __forceinline__ void head_partial8(f32x4 (&acc)[4][4], const float* __restrict__ w,
                                              f32x2 (*stats)[8], int wave, int lane)
{
  int lrow = lane & 15, lhi = lane >> 4;
  float hs[4][4];
  #pragma unroll
  for (int mt = 0; mt < 4; ++mt)
    #pragma unroll
    for (int r = 0; r < 4; ++r) hs[mt][r] = 0.f;
  #pragma unroll
  for (int ct = 0; ct < 4; ++ct){
    int c = wave * 64 + ct * 16 + lrow;
    float f = w[c];
    #pragma unroll
    for (int mt = 0; mt < 4; ++mt)
      #pragma unroll
      for (int r = 0; r < 4; ++r) hs[mt][r] += acc[mt][ct][r] * f;
  }
  #pragma unroll
  for (int off = 1; off < 16; off <<= 1)
    #pragma unroll
    for (int mt = 0; mt < 4; ++mt)
      #pragma unroll
      for (int r = 0; r < 4; ++r) hs[mt][r] += __shfl_xor(hs[mt][r], off);
  float sa = 0.f;
  #pragma unroll
  for (int mt = 0; mt < 4; ++mt)
    #pragma unroll
    for (int r = 0; r < 4; ++r)
      if (lrow == mt * 4 + r) sa = hs[mt][r];
  int rowa = (lrow >> 2) * 16 + lhi * 4 + (lrow & 3);
  f32x2 pa = {sa, 0.f};
  stats[rowa][wave] = pa;
}

// Staging: h1 = relu(P'[i]+Q[j]) into hA rows 0..48 (+ zero pad rows 49..63).
// b1 pre-folded into P' at PQ-GEMM output.
__device__ __forceinline__ void stage_h1(const u16* __restrict__ PQ, int gg, u16* hA,
                                         int wave, int lane){
  const u16* Pg = PQ + (size_t)gg * 7 * 1024;
  u16x8 pA, qA, pB, qB;
  {
    int e = wave;
    int i = e / 7, j = e % 7;
    pA = *(const u16x8*)&Pg[(size_t)i * 1024 + lane * 8];
    qA = *(const u16x8*)&Pg[(size_t)j * 1024 + 512 + lane * 8];
  }
  #pragma unroll
  for (int it = 0; it < 8; ++it){
    int e = it * 8 + wave;
    if (it < 7){
      int e2 = e + 8;
      if (e2 < 49){
        int i = e2 / 7, j = e2 % 7;
        pB = *(const u16x8*)&Pg[(size_t)i * 1024 + lane * 8];
        qB = *(const u16x8*)&Pg[(size_t)j * 1024 + 512 + lane * 8];
      }
    }
    u16x8 o;
    if (e < 49){
      #pragma unroll
      for (int u = 0; u < 8; ++u)
        o[u] = f2bf(fmaxf(bf2f(pA[u]) + bf2f(qA[u]), 0.f));
    } else {
      #pragma unroll
      for (int u = 0; u < 8; ++u) o[u] = 0;
    }
    *(u16x8*)&hA[uidx(e, lane * 8)] = o;
    pA = pB; qA = qB;
  }
}

// ======== edge pass 0: stage -> GEMM1(w2) -> LN -> colsum -> hsum (global) ======
__global__ __launch_bounds__(512, 2) void edge0_kernel(
    const u16* __restrict__ PQ, const u16* __restrict__ w2p,
    const float* __restrict__ b2,
    const float* __restrict__ g, const float* __restrict__ bt,
    u16* __restrict__ hsum)
{
  __shared__ alignas(16) u16 hA[64 * 512];
  __shared__ f32x2 stats[64][8];
  __shared__ f32x2 mufb[64];
  int gidx = blockIdx.x;
  int tid = threadIdx.x;
  int wave = tid >> 6, lane = tid & 63;

  stage_h1(PQ, gidx, hA, wave, lane);
  u16x8 bpre[4];
  preload_b4(w2p, wave, lane, bpre);
  __syncthreads();

  f32x4 acc[4][4];
  zero_acc(acc);
  gemm_pipe(hA, w2p, acc, wave, lane, bpre);
  ln_relu8_t<0>(acc, hA, stats, mufb, b2, g, bt, wave, lane, tid);
  __syncthreads();                    // h2n rows 0..48 visible
  // column sums: hsum[i][c] = sum_j h2n[7i+j][c] -> global (bf16, coalesced)
  {
    int c = tid;   // 0..511
    #pragma unroll
    for (int i = 0; i < 7; ++i){
      float s = 0.f;
      #pragma unroll
      for (int j = 0; j < 7; ++j)
        s += bf2f(hA[uidx(7 * i + j, c)]);
      hsum[((size_t)(gidx * 7 + i)) * 512 + c] = f2bf(s);
    }
  }
}

// ============ edge pass 1: w3 folded to a vector (w3f = ew3@few) ============
__global__ __launch_bounds__(512, 2) void edge1_kernel(
    const u16* __restrict__ PQ, const u16* __restrict__ w2p,
    const float* __restrict__ b2,
    const float* __restrict__ g, const float* __restrict__ bt,
    const float* __restrict__ w3f, float* __restrict__ out)
{
  __shared__ alignas(16) u16 hA[64 * 512];
  __shared__ f32x2 stats[64][8];
  __shared__ f32x2 mufb[64];
  int gidx = blockIdx.x;
  int tid = threadIdx.x;
  int wave = tid >> 6, lane = tid & 63;

  stage_h1(PQ, gidx, hA, wave, lane);
  u16x8 bpre[4];
  preload_b4(w2p, wave, lane, bpre);
  __syncthreads();

  f32x4 acc[4][4];
  zero_acc(acc);
  gemm_pipe(hA, w2p, acc, wave, lane, bpre);
  ln_relu8_t<1>(acc, hA, stats, mufb, b2, g, bt, wave, lane, tid);  // acc := relu(LN)
  head_partial8(acc, w3f, stats, wave, lane);
  __syncthreads();
  if (tid < 49){
    float s = w3f[512];   // eb3.few + feb
    #pragma unroll
    for (int w = 0; w < 8; ++w) s += stats[tid][w][0];
    out[(size_t)gidx * 56 + 7 + tid] = s;
  }
}

// ==== node mega-kernel: r1 -> h2 -> LN -> node2 (+head) -> PQ (pass 2) ====
__global__ __launch_bounds__(512, 2) void node_mega(
    const u16* __restrict__ nodeb, const u16* __restrict__ hsumb,
    const u16* __restrict__ nw1cat, const u16* __restrict__ nw2p,
    const u16* __restrict__ nw3p, const u16* __restrict__ w1p,
    const float* __restrict__ bvec, const float* __restrict__ nb2,
    const float* __restrict__ ng, const float* __restrict__ nbt,
    const float* __restrict__ nb3, const float* __restrict__ hw,
    const float* __restrict__ hb, const float* __restrict__ b1,
    u16* __restrict__ PQ, float* __restrict__ out)
{
  __shared__ alignas(16) u16 hA[64 * 512];
  __shared__ f32x2 stats[64][8];
  __shared__ f32x2 mufb[64];
  int tid = threadIdx.x;
  int wave = tid >> 6, lane = tid & 63;
  int lrow = lane & 15, lhi = lane >> 4;
  size_t row0 = (size_t)blockIdx.x * 64;

  // r1 = relu([nodeb|hsumb] @ [nw1a|w3n] + bvec)  (K=1024, A from global)
  f32x4 acc[4][4];
  zero_acc(acc);
  gemm_k1024_gA(nodeb, hsumb, row0, nw1cat, acc, wave, lane);
  relu_to_lds(acc, hA, bvec, wave, lane);
  u16x8 bpre[4];
  preload_b4(nw2p, wave, lane, bpre);
  __syncthreads();
  // h2 = r1 @ nw2 (+nb2 in LN) -> LN -> relu -> hA
  zero_acc(acc);
  gemm_pipe(hA, nw2p, acc, wave, lane, bpre);
  ln_relu8_t<0>(acc, hA, stats, mufb, nb2, ng, nbt, wave, lane, tid);
  preload_b4(nw3p, wave, lane, bpre);
  __syncthreads();
  // node2 = h2n @ nw3 + nb3
  zero_acc(acc);
  gemm_pipe(hA, nw3p, acc, wave, lane, bpre);
  add_bias8(acc, nb3, wave, lane);
  __syncthreads();   // all GEMM reads of hA (h2n) done before overwrite
  // node2 -> hA (for PQ GEMMs); head partial
  #pragma unroll
  for (int ct = 0; ct < 4; ++ct){
    int c = wave * 64 + ct * 16 + lrow;
    #pragma unroll
    for (int mt = 0; mt < 4; ++mt)
      #pragma unroll
      for (int r = 0; r < 4; ++r)
        hA[uidx(mt * 16 + lhi * 4 + r, c)] = f2bf(acc[mt][ct][r]);
  }
  head_partial8(acc, hw, stats, wave, lane);
  __syncthreads();   // node2 + stats visible
  if (tid < 64){
    size_t v = row0 + tid;
    float s = hb[0];
    #pragma unroll
    for (int w = 0; w < 8; ++w) s += stats[tid][w][0];
    out[(v / 7) * 56 + (v % 7)] = s;
  }
  // PQ = node2 @ w1p  (N=1024, two 512-col passes; P half gets +b1)
  #pragma unroll
  for (int pp = 0; pp < 2; ++pp){
    zero_acc(acc);
    const u16* bbBase = w1p + (((size_t)(pp * 32) + wave * 4) * 64 + lane) * 8;
    gemm_pipe_s(hA, bbBase, 32768, acc, lane);
    #pragma unroll
    for (int ct = 0; ct < 4; ++ct){
      int cc = wave * 64 + ct * 16 + lrow;
      int c = pp * 512 + cc;
      float bb = (pp == 0) ? b1[cc] : 0.f;
      #pragma unroll
      for (int mt = 0; mt < 4; ++mt)
        #pragma unroll
        for (int r = 0; r < 4; ++r){
          size_t grow = row0 + mt * 16 + lhi * 4 + r;
          PQ[grow * 1024 + c] = f2bf(acc[mt][ct][r] + bb);
        }
    }
  }
}

// gemm64 MODE0: PQ = nodeb @ w1p (pass 1); P half (coff==0) gets +b1.
__global__ __launch_bounds__(256, 2) void gemm64_0(
    const u16* __restrict__ A0, const u16* __restrict__ Bp,
    const float* __restrict__ b1, u16* __restrict__ Cout)
{
  int tid = threadIdx.x;
  int wave = tid >> 6, lane = tid & 63;
  int lrow = lane & 15, lhi = lane >> 4;
  size_t row0 = (size_t)blockIdx.x * 64;
  int coff = blockIdx.y * 512;
  const u16* bb = Bp + (((size_t)(coff >> 4) + wave * 8) * 64 + lane) * 8;
  f32x4 acc[4][8];
  #pragma unroll
  for (int mt = 0; mt < 4; ++mt)
    #pragma unroll
    for (int ct = 0; ct < 8; ++ct){
      f32x4 z = {0.f, 0.f, 0.f, 0.f};
      acc[mt][ct] = z;
    }
  u16x8 b_cur[8], b_nxt[8];
  #pragma unroll
  for (int ct = 0; ct < 8; ++ct) b_cur[ct] = *(const u16x8*)&bb[ct * 512];
  #pragma unroll
  for (int kt = 0; kt < 16; ++kt){
    u16x8 af[4];
    #pragma unroll
    for (int mt = 0; mt < 4; ++mt)
      af[mt] = *(const u16x8*)&A0[(row0 + mt * 16 + lrow) * 512 + kt * 32 + lhi * 8];
    if (kt < 15){
      #pragma unroll
      for (int ct = 0; ct < 8; ++ct)
        b_nxt[ct] = *(const u16x8*)&bb[((size_t)(kt + 1) * 64 * 64 + ct * 64) * 8];
    }
    __builtin_amdgcn_s_setprio(1);
    #pragma unroll
    for (int ct = 0; ct < 8; ++ct)
      #pragma unroll
      for (int mt = 0; mt < 4; ++mt) acc[mt][ct] = mfma16(af[mt], b_cur[ct], acc[mt][ct]);
    __builtin_amdgcn_s_setprio(0);
    #pragma unroll
    for (int ct = 0; ct < 8; ++ct) b_cur[ct] = b_nxt[ct];
  }
  #pragma unroll
  for (int ct = 0; ct < 8; ++ct){
    int cc = wave * 128 + ct * 16 + lrow;
    int c = coff + cc;
    float bb2 = (coff == 0) ? b1[cc] : 0.f;
    #pragma unroll
    for (int mt = 0; mt < 4; ++mt)
      #pragma unroll
      for (int r = 0; r < 4; ++r){
        size_t grow = row0 + mt * 16 + lhi * 4 + r;
        Cout[grow * 1024 + c] = f2bf(acc[mt][ct][r] + bb2);
      }
  }
}

// w3n = ew3(f32) @ nw1b(packed bf16): 512x512, K=512. Grid (8,4).
// Output written DIRECTLY in packed B-fragment order into nw1cat+512*512.
__global__ __launch_bounds__(256) void gemm_w3n(
    const float* __restrict__ A, const u16* __restrict__ Bp, u16* __restrict__ dst)
{
  int tid = threadIdx.x;
  int wave = tid >> 6, lane = tid & 63;
  int lrow = lane & 15, lhi = lane >> 4;
  size_t row0 = (size_t)blockIdx.x * 64;
  int coff = blockIdx.y * 128;
  const u16* bb = Bp + (((size_t)(coff >> 4) + wave * 2) * 64 + lane) * 8;
  f32x4 acc[4][2];
  #pragma unroll
  for (int mt = 0; mt < 4; ++mt)
    #pragma unroll
    for (int ct = 0; ct < 2; ++ct){
      f32x4 z = {0.f, 0.f, 0.f, 0.f};
      acc[mt][ct] = z;
    }
  for (int kt = 0; kt < 16; ++kt){
    u16x8 af[4], bv[2];
    #pragma unroll
    for (int mt = 0; mt < 4; ++mt){
      const float* ar = A + (row0 + mt * 16 + lrow) * 512 + kt * 32 + lhi * 8;
      float4 v0 = *(const float4*)ar, v1 = *(const float4*)(ar + 4);
      af[mt][0] = f2bf(v0.x); af[mt][1] = f2bf(v0.y);
      af[mt][2] = f2bf(v0.z); af[mt][3] = f2bf(v0.w);
      af[mt][4] = f2bf(v1.x); af[mt][5] = f2bf(v1.y);
      af[mt][6] = f2bf(v1.z); af[mt][7] = f2bf(v1.w);
    }
    #pragma unroll
    for (int ct = 0; ct < 2; ++ct)
      bv[ct] = *(const u16x8*)&bb[(size_t)kt * 16384 + ct * 512];
    #pragma unroll
    for (int ct = 0; ct < 2; ++ct)
      #pragma unroll
      for (int mt = 0; mt < 4; ++mt) acc[mt][ct] = mfma16(af[mt], bv[ct], acc[mt][ct]);
  }
  // packed write: dst[((kt*32+ctp)*64 + lanehi*16+lanelo)*8 + j]
  //   = W[kt*32 + lanehi*8 + j][ctp*16 + lanelo],  W[k][c] = acc value at
  //   k = row0+mt*16+lhi*4+r, c = coff + wave*32 + ct*16 + lrow.
  #pragma unroll
  for (int ct = 0; ct < 2; ++ct){
    int c = coff + wave * 32 + ct * 16 + lrow;
    int ctp = c >> 4, lanelo = c & 15;
    #pragma unroll
    for (int mt = 0; mt < 4; ++mt)
      #pragma unroll
      for (int r = 0; r < 4; ++r){
        int k = (int)row0 + mt * 16 + lhi * 4 + r;
        int kt = k >> 5, lanehi = (k >> 3) & 3, j = k & 7;
        dst[((size_t)(kt * 32 + ctp) * 64 + lanehi * 16 + lanelo) * 8 + j]
            = f2bf(acc[mt][ct][r]);
      }
  }
}

// ==== prep_all: all packing / folding / casting in ONE launch ====
// segments by blockIdx.x:
//  [0,256):    pack ew1 (w1mode, K=512 N=1024) -> w1p
//  [256,384):  pack nw1[0:512]   -> nw1cat (nw1a)
//  [384,512):  pack nw1[512:]    -> nw1bp
//  [512,640):  pack ew2          -> w2p
//  [640,768):  pack nw2          -> nw2p
//  [768,896):  pack nw3          -> nw3p
//  [896,1025): fold_w3 (4 k per block, one per wave)
//  [1025,1027): fold_bvec (256 c per block)
//  [1027,...): cast_node
__device__ __forceinline__ void pack_body(const float* __restrict__ W, u16* __restrict__ dst,
                                          int N, int w1mode, int idx){
  int lane = idx & 63;
  int t = idx >> 6;
  int nt = N >> 4;
  int ct = t % nt;
  int kt = t / nt;
  int c  = ct * 16 + (lane & 15);
  int k0 = kt * 32 + (lane >> 4) * 8;
  u16x8 o;
  #pragma unroll
  for (int j = 0; j < 8; ++j){
    int k = k0 + j;
    float v;
    if (w1mode){
      v = (c < 512) ? W[(size_t)k * 512 + c] : W[(size_t)(k + 512) * 512 + (c - 512)];
    } else {
      v = W[(size_t)k * N + c];
    }
    o[j] = f2bf(v);
  }
  *(u16x8*)&dst[(size_t)idx * 8] = o;
}

__global__ __launch_bounds__(256) void prep_all(
    const float* __restrict__ states,
    const float* __restrict__ ew1, const float* __restrict__ nw1,
    const float* __restrict__ ew2, const float* __restrict__ nw2,
    const float* __restrict__ nw3, const float* __restrict__ ew3,
    const float* __restrict__ few, const float* __restrict__ eb3,
    const float* __restrict__ feb, const float* __restrict__ nb1,
    u16* __restrict__ nodeb, u16* __restrict__ w1p, u16* __restrict__ nw1cat,
    u16* __restrict__ nw1bp, u16* __restrict__ w2p, u16* __restrict__ nw2p,
    u16* __restrict__ nw3p, float* __restrict__ w3f, float* __restrict__ bvec)
{
  int blk = blockIdx.x;
  int tid = threadIdx.x;
  if (blk < 256){
    pack_body(ew1, w1p, 1024, 1, blk * 256 + tid);
  } else if (blk < 384){
    pack_body(nw1, nw1cat, 512, 0, (blk - 256) * 256 + tid);
  } else if (blk < 512){
    pack_body(nw1 + 512 * 512, nw1bp, 512, 0, (blk - 384) * 256 + tid);
  } else if (blk < 640){
    pack_body(ew2, w2p, 512, 0, (blk - 512) * 256 + tid);
  } else if (blk < 768){
    pack_body(nw2, nw2p, 512, 0, (blk - 640) * 256 + tid);
  } else if (blk < 896){
    pack_body(nw3, nw3p, 512, 0, (blk - 768) * 256 + tid);
  } else if (blk < 1025){
    int k = (blk - 896) * 4 + (tid >> 6);
    int l = tid & 63;
    if (k <= 512){
      const float* row = (k < 512) ? (ew3 + (size_t)k * 512) : eb3;
      float s = 0.f;
      for (int c = l; c < 512; c += 64) s += row[c] * few[c];
      #pragma unroll
      for (int off = 32; off; off >>= 1) s += __shfl_down(s, off);
      if (l == 0) w3f[k] = (k < 512) ? s : s + feb[0];
    }
  } else if (blk < 1027){
    int c = (blk - 1025) * 256 + tid;
    float s = 0.f;
    for (int m = 0; m < 512; ++m)
      s += eb3[m] * nw1[(size_t)(512 + m) * 512 + c];
    bvec[c] = nb1[c] + 7.f * s;
  } else {
    int idx = (blk - 1027) * 256 + tid;   // cast_node, n8 = NV*512/8
    const float4* s = (const float4*)states;
    float4 a = s[(size_t)idx * 2], b = s[(size_t)idx * 2 + 1];
    u16x8 o;
    o[0] = f2bf(a.x); o[1] = f2bf(a.y); o[2] = f2bf(a.z); o[3] = f2bf(a.w);
    o[4] = f2bf(b.x); o[5] = f2bf(b.y); o[6] = f2bf(b.z); o[7] = f2bf(b.w);
    *(u16x8*)&nodeb[(size_t)idx * 8] = o;
  }
}

extern "C" void kernel_launch(void* const* d_in, const int* in_sizes, int n_in,
                              void* d_out, int out_size, void* d_ws, size_t ws_size,
                              hipStream_t stream)
{
  (void)in_sizes; (void)n_in; (void)out_size; (void)ws_size;
  const float* states = (const float*)d_in[0];
  const float* ew1 = (const float*)d_in[1];
  const float* eb1 = (const float*)d_in[2];
  const float* ew2 = (const float*)d_in[3];
  const float* eb2 = (const float*)d_in[4];
  const float* eg  = (const float*)d_in[5];
  const float* ebt = (const float*)d_in[6];
  const float* ew3 = (const float*)d_in[7];
  const float* eb3 = (const float*)d_in[8];
  const float* nw1 = (const float*)d_in[9];
  const float* nb1 = (const float*)d_in[10];
  const float* nw2 = (const float*)d_in[11];
  const float* nb2 = (const float*)d_in[12];
  const float* ng  = (const float*)d_in[13];
  const float* nbt = (const float*)d_in[14];
  const float* nw3 = (const float*)d_in[15];
  const float* nb3 = (const float*)d_in[16];
  const float* fnw = (const float*)d_in[17];
  const float* fnb = (const float*)d_in[18];
  const float* few = (const float*)d_in[19];
  const float* feb = (const float*)d_in[20];
  float* out = (float*)d_out;

  char* ws = (char*)d_ws;
  size_t off = 0;
  auto alloc = [&](size_t bytes) -> void* {
    void* p = ws + off;
    off += (bytes + 255) & ~(size_t)255;
    return p;
  };
  const size_t NV = 28672;  // B*n
  u16* PQ     = (u16*)alloc(NV * 1024 * 2);   // [NV][P'(512)|Q(512)] bf16 (P' = P+b1)
  u16* nodeb  = (u16*)alloc(NV * 512 * 2);
  u16* hsumb  = (u16*)alloc(NV * 512 * 2);
  u16* w1p    = (u16*)alloc(512 * 1024 * 2);
  u16* nw1cat = (u16*)alloc(1024 * 512 * 2);  // [nw1a packed | w3n packed]
  u16* nw1bp  = (u16*)alloc(512 * 512 * 2);
  u16* w2p    = (u16*)alloc(512 * 512 * 2);
  u16* nw2p   = (u16*)alloc(512 * 512 * 2);
  u16* nw3p   = (u16*)alloc(512 * 512 * 2);
  float* w3f  = (float*)alloc(513 * 4);
  float* bvec = (float*)alloc(512 * 4);

  // all packing/folding/casting in one launch (segments by blockIdx)
  prep_all<<<1027 + 7168, 256, 0, stream>>>(
      states, ew1, nw1, ew2, nw2, nw3, ew3, few, eb3, feb, nb1,
      nodeb, w1p, nw1cat, nw1bp, w2p, nw2p, nw3p, w3f, bvec);
  // w3n = ew3 @ nw1b, written directly packed into nw1cat second half
  gemm_w3n<<<dim3(8, 4), 256, 0, stream>>>(ew3, nw1bp, nw1cat + 512 * 512);

  // Pass 1
  gemm64_0<<<dim3(448, 2), 256, 0, stream>>>(nodeb, w1p, eb1, PQ);
  edge0_kernel<<<4096, 512, 0, stream>>>(PQ, w2p, eb2, eg, ebt, hsumb);
  // Node update + head + PQ for pass 2 (fused)
  node_mega<<<448, 512, 0, stream>>>(nodeb, hsumb, nw1cat, nw2p, nw3p, w1p,
                                     bvec, nb2, ng, nbt, nb3, fnw, fnb, eb1, PQ, out);
  // Pass 2 edge head
  edge1_kernel<<<4096, 512, 0, stream>>>(PQ, w2p, eb2, eg, ebt, w3f, out);
}

// Round 19
// 538.977 us; speedup vs baseline: 1.4424x; 1.0324x over previous
//
#include <hip/hip_runtime.h>

#define LN_EPS 1e-5f
#define NSRC 28672          // total source nodes (B*n)
#define SPB 9               // source groups per edge block
#define EPB 63              // edges per block = SPB*7
#define NB_E 3186           // ceil(NSRC / SPB)

typedef unsigned short u16;
typedef u16 u16x8 __attribute__((ext_vector_type(8)));
typedef __bf16 bf16x8 __attribute__((ext_vector_type(8)));
typedef float f32x4 __attribute__((ext_vector_type(4)));
typedef float f32x2 __attribute__((ext_vector_type(2)));

__device__ __forceinline__ u16 f2bf(float f){
  return __builtin_bit_cast(u16, (__bf16)f);
}
__device__ __forceinline__ float bf2f(u16 b){
  return (float)__builtin_bit_cast(__bf16, b);
}
__device__ __forceinline__ f32x4 mfma16(u16x8 a, u16x8 b, f32x4 c){
  return __builtin_amdgcn_mfma_f32_16x16x32_bf16(
      __builtin_bit_cast(bf16x8, a), __builtin_bit_cast(bf16x8, b), c, 0, 0, 0);
}
// LDS h-tile: [64 rows][512 k] bf16, XOR swizzle on k (8-elem granules)
__device__ __forceinline__ int uidx(int row, int k){
  return row * 512 + (k ^ ((row & 7) << 3));
}

__device__ __forceinline__ void zero_acc(f32x4 (&acc)[4][4]){
  #pragma unroll
  for (int mt = 0; mt < 4; ++mt)
    #pragma unroll
    for (int ct = 0; ct < 4; ++ct){
      f32x4 z = {0.f, 0.f, 0.f, 0.f};
      acc[mt][ct] = z;
    }
}

// Issue first kt's 4 B-fragment loads BEFORE the preceding barrier (in flight
// across s_barrier; hides cold-start L2 latency).
__device__ __forceinline__ void preload_b4(const u16* __restrict__ Bp, int wave, int lane,
                                           u16x8 (&b)[4]){
  const u16* bb = Bp + ((size_t)(wave * 4) * 64 + lane) * 8;
  #pragma unroll
  for (int ct = 0; ct < 4; ++ct) b[ct] = *(const u16x8*)&bb[ct * 512];
}

// GEMM, A from LDS (64 rows), B from global (N=512 packing, kt-stride 16384),
// 1-deep register prefetch (~64 VGPR clean). b_cur arrives preloaded.
__device__ __forceinline__ void gemm_pipe(const u16* hA, const u16* __restrict__ Bp,
                                          f32x4 (&acc)[4][4], int wave, int lane,
                                          u16x8 (&b_cur)[4]){
  int lrow = lane & 15, lhi = lane >> 4;
  const u16* bb = Bp + ((size_t)(wave * 4) * 64 + lane) * 8;
  u16x8 b_nxt[4], a[4];
  #pragma unroll
  for (int kt = 0; kt < 16; ++kt){
    #pragma unroll
    for (int mt = 0; mt < 4; ++mt)
      a[mt] = *(const u16x8*)&hA[uidx(mt * 16 + lrow, kt * 32 + lhi * 8)];
    if (kt < 15){
      #pragma unroll
      for (int ct = 0; ct < 4; ++ct)
        b_nxt[ct] = *(const u16x8*)&bb[(size_t)(kt + 1) * 16384 + ct * 512];
    }
    __builtin_amdgcn_s_setprio(1);
    #pragma unroll
    for (int ct = 0; ct < 4; ++ct)
      #pragma unroll
      for (int mt = 0; mt < 4; ++mt)
        acc[mt][ct] = mfma16(a[mt], b_cur[ct], acc[mt][ct]);
    __builtin_amdgcn_s_setprio(0);
    #pragma unroll
    for (int ct = 0; ct < 4; ++ct) b_cur[ct] = b_nxt[ct];
  }
}

// K=1024 GEMM, A rows from TWO global sources (nodeb | hsumb), B packed K=1024
// (kt-stride 16384, KT=32).
__device__ __forceinline__ void gemm_k1024_gA(const u16* __restrict__ A0,
                                              const u16* __restrict__ A1, size_t row0,
                                              const u16* __restrict__ Bp,
                                              f32x4 (&acc)[4][4], int wave, int lane){
  int lrow = lane & 15, lhi = lane >> 4;
  const u16* bb = Bp + ((size_t)(wave * 4) * 64 + lane) * 8;
  const u16* a0 = A0 + (row0 + lrow) * 512 + lhi * 8;
  const u16* a1 = A1 + (row0 + lrow) * 512 + lhi * 8;
  u16x8 b_cur[4], b_nxt[4], a[4];
  #pragma unroll
  for (int ct = 0; ct < 4; ++ct) b_cur[ct] = *(const u16x8*)&bb[ct * 512];
  #pragma unroll
  for (int kt = 0; kt < 32; ++kt){
    const u16* ab = (kt < 16) ? a0 : a1;
    int kk = (kt & 15) * 32;
    #pragma unroll
    for (int mt = 0; mt < 4; ++mt)
      a[mt] = *(const u16x8*)&ab[mt * 8192 + kk];
    if (kt < 31){
      #pragma unroll
      for (int ct = 0; ct < 4; ++ct)
        b_nxt[ct] = *(const u16x8*)&bb[(size_t)(kt + 1) * 16384 + ct * 512];
    }
    __builtin_amdgcn_s_setprio(1);
    #pragma unroll
    for (int ct = 0; ct < 4; ++ct)
      #pragma unroll
      for (int mt = 0; mt < 4; ++mt)
        acc[mt][ct] = mfma16(a[mt], b_cur[ct], acc[mt][ct]);
    __builtin_amdgcn_s_setprio(0);
    #pragma unroll
    for (int ct = 0; ct < 4; ++ct) b_cur[ct] = b_nxt[ct];
  }
}

// GEMM over hA with custom B base/kt-stride (for N=1024 w1p packing).
__device__ __forceinline__ void gemm_pipe_s(const u16* hA, const u16* __restrict__ bbBase,
                                            int ktStride, f32x4 (&acc)[4][4],
                                            int lane){
  int lrow = lane & 15, lhi = lane >> 4;
  u16x8 b_cur[4], b_nxt[4], a[4];
  #pragma unroll
  for (int ct = 0; ct < 4; ++ct) b_cur[ct] = *(const u16x8*)&bbBase[ct * 512];
  #pragma unroll
  for (int kt = 0; kt < 16; ++kt){
    #pragma unroll
    for (int mt = 0; mt < 4; ++mt)
      a[mt] = *(const u16x8*)&hA[uidx(mt * 16 + lrow, kt * 32 + lhi * 8)];
    if (kt < 15){
      #pragma unroll
      for (int ct = 0; ct < 4; ++ct)
        b_nxt[ct] = *(const u16x8*)&bbBase[(size_t)(kt + 1) * ktStride + ct * 512];
    }
    __builtin_amdgcn_s_setprio(1);
    #pragma unroll
    for (int ct = 0; ct < 4; ++ct)
      #pragma unroll
      for (int mt = 0; mt < 4; ++mt)
        acc[mt][ct] = mfma16(a[mt], b_cur[ct], acc[mt][ct]);
    __builtin_amdgcn_s_setprio(0);
    #pragma unroll
    for (int ct = 0; ct < 4; ++ct) b_cur[ct] = b_nxt[ct];
  }
}

__device__ __forceinline__ void add_bias8(f32x4 (&acc)[4][4], const float* __restrict__ b,
                                          int wave, int lane){
  int lrow = lane & 15;
  #pragma unroll
  for (int ct = 0; ct < 4; ++ct){
    float bb = b[wave * 64 + ct * 16 + lrow];
    #pragma unroll
    for (int mt = 0; mt < 4; ++mt)
      #pragma unroll
      for (int r = 0; r < 4; ++r) acc[mt][ct][r] += bb;
  }
}

// acc += bias; relu; write bf16 into hA (swizzled). (r1 stage of node MLP.)
__device__ __forceinline__ void relu_to_lds(f32x4 (&acc)[4][4], u16* hA,
                                            const float* __restrict__ b,
                                            int wave, int lane){
  int lrow = lane & 15, lhi = lane >> 4;
  #pragma unroll
  for (int ct = 0; ct < 4; ++ct){
    int c = wave * 64 + ct * 16 + lrow;
    float bb = b[c];
    #pragma unroll
    for (int mt = 0; mt < 4; ++mt)
      #pragma unroll
      for (int r = 0; r < 4; ++r){
        int row = mt * 16 + lhi * 4 + r;
        hA[uidx(row, c)] = f2bf(fmaxf(acc[mt][ct][r] + bb, 0.f));
      }
  }
}

// acc += b2; LayerNorm over 512 cols per row; relu.  (r15-measured: 64 VGPR)
// TO_ACC=0: write bf16 into hA (swizzled); TO_ACC=1: result into acc.
template<int TO_ACC>
__device__ __forceinline__ void ln_relu8_t(f32x4 (&acc)[4][4], u16* hA,
    f32x2 (*stats)[8], f32x2* mufb,
    const float* __restrict__ b2, const float* __restrict__ g, const float* __restrict__ bt,
    int wave, int lane, int tid)
{
  int lrow = lane & 15, lhi = lane >> 4;
  float s1[4][4], s2[4][4];
  #pragma unroll
  for (int mt = 0; mt < 4; ++mt)
    #pragma unroll
    for (int r = 0; r < 4; ++r){ s1[mt][r] = 0.f; s2[mt][r] = 0.f; }
  #pragma unroll
  for (int ct = 0; ct < 4; ++ct){
    int c = wave * 64 + ct * 16 + lrow;
    float bb = b2[c];
    #pragma unroll
    for (int mt = 0; mt < 4; ++mt)
      #pragma unroll
      for (int r = 0; r < 4; ++r){
        float x = acc[mt][ct][r] + bb;
        acc[mt][ct][r] = x;
        s1[mt][r] += x; s2[mt][r] += x * x;
      }
  }
  #pragma unroll
  for (int off = 1; off < 16; off <<= 1){
    #pragma unroll
    for (int mt = 0; mt < 4; ++mt)
      #pragma unroll
      for (int r = 0; r < 4; ++r){
        s1[mt][r] += __shfl_xor(s1[mt][r], off);
        s2[mt][r] += __shfl_xor(s2[mt][r], off);
      }
  }
  float sa1 = 0.f, sa2 = 0.f;
  #pragma unroll
  for (int mt = 0; mt < 4; ++mt)
    #pragma unroll
    for (int r = 0; r < 4; ++r)
      if (lrow == mt * 4 + r){ sa1 = s1[mt][r]; sa2 = s2[mt][r]; }
  int rowa = (lrow >> 2) * 16 + lhi * 4 + (lrow & 3);
  f32x2 pa = {sa1, sa2};
  stats[rowa][wave] = pa;
  __syncthreads();              // also: all waves done reading hA (prev GEMM)
  if (tid < 64){
    float a = 0.f, b = 0.f;
    #pragma unroll
    for (int w = 0; w < 8; ++w){ a += stats[tid][w][0]; b += stats[tid][w][1]; }
    float mu  = a * (1.f / 512.f);
    float var = b * (1.f / 512.f) - mu * mu;
    f32x2 mr = {mu, rsqrtf(fmaxf(var, 0.f) + LN_EPS)};
    mufb[tid] = mr;
  }
  __syncthreads();
  float gv[4], btv[4];
  #pragma unroll
  for (int ct = 0; ct < 4; ++ct){
    int c = wave * 64 + ct * 16 + lrow;
    gv[ct] = g[c]; btv[ct] = bt[c];
  }
  #pragma unroll
  for (int mt = 0; mt < 4; ++mt)
    #pragma unroll
    for (int r = 0; r < 4; ++r){
      int row = mt * 16 + lhi * 4 + r;
      f32x2 mr = mufb[row];
      #pragma unroll
      for (int ct = 0; ct < 4; ++ct){
        int c = wave * 64 + ct * 16 + lrow;
        float x = (acc[mt][ct][r] - mr[0]) * mr[1] * gv[ct] + btv[ct];
        if (TO_ACC) acc[mt][ct][r] = fmaxf(x, 0.f);
        else        hA[uidx(row, c)] = f2bf(fmaxf(x, 0.f));
      }
    }
  // TO_ACC=0 caller: barrier before any cross-thread hA read.
}

// dot each row with weight vector w; per-wave partial -> stats[row][wave].x
__device__ __forceinline__ void head_partial8(f32x4 (&acc)[4][4], const float* __restrict__ w,
                                              f32x2 (*stats)[8], int wave, int lane)
{
  int lrow = lane & 15, lhi = lane >> 4;
  float hs[4][4];
  #pragma unroll
  for (int mt = 0; mt < 4; ++mt)
    #pragma unroll
    for (int r = 0; r < 4; ++r) hs[mt][r] = 0.f;
  #pragma unroll
  for (int ct = 0; ct < 4; ++ct){
    int c = wave * 64 + ct * 16 + lrow;
    float f = w[c];
    #pragma unroll
    for (int mt = 0; mt < 4; ++mt)
      #pragma unroll
      for (int r = 0; r < 4; ++r) hs[mt][r] += acc[mt][ct][r] * f;
  }
  #pragma unroll
  for (int off = 1; off < 16; off <<= 1)
    #pragma unroll
    for (int mt = 0; mt < 4; ++mt)
      #pragma unroll
      for (int r = 0; r < 4; ++r) hs[mt][r] += __shfl_xor(hs[mt][r], off);
  float sa = 0.f;
  #pragma unroll
  for (int mt = 0; mt < 4; ++mt)
    #pragma unroll
    for (int r = 0; r < 4; ++r)
      if (lrow == mt * 4 + r) sa = hs[mt][r];
  int rowa = (lrow >> 2) * 16 + lhi * 4 + (lrow & 3);
  f32x2 pa = {sa, 0.f};
  stats[rowa][wave] = pa;
}

// Staging for source-group blocks: block covers sources bs..bs+8 (9 groups,
// 63 edge rows; row r = sl*7+j, edge = (bs+sl, j)). h1 = relu(P'[s] + Q[qn]),
// qn = (s/7)*7 + j. Row 63 and rows with s >= NSRC are zero pad.
__device__ __forceinline__ void stage_h1(const u16* __restrict__ PQ, int bs, u16* hA,
                                         int wave, int lane){
  u16x8 pA, qA, pB, qB;
  bool vA = false, vB;
  {
    int e = wave;                     // it = 0: e = 0..7 (< 63 always)
    int sl = e / 7, j = e % 7;
    int s = bs + sl;
    vA = (s < NSRC);
    if (vA){
      int qn = s - s % 7 + j;
      pA = *(const u16x8*)&PQ[(size_t)s * 1024 + lane * 8];
      qA = *(const u16x8*)&PQ[(size_t)qn * 1024 + 512 + lane * 8];
    }
  }
  #pragma unroll
  for (int it = 0; it < 8; ++it){
    int e = it * 8 + wave;
    if (it < 7){
      int e2 = e + 8;
      int sl = e2 / 7, j = e2 % 7;
      int s = bs + sl;
      vB = (e2 < EPB) && (s < NSRC);
      if (vB){
        int qn = s - s % 7 + j;
        pB = *(const u16x8*)&PQ[(size_t)s * 1024 + lane * 8];
        qB = *(const u16x8*)&PQ[(size_t)qn * 1024 + 512 + lane * 8];
      }
    }
    u16x8 o;
    if (vA){
      #pragma unroll
      for (int u = 0; u < 8; ++u)
        o[u] = f2bf(fmaxf(bf2f(pA[u]) + bf2f(qA[u]), 0.f));
    } else {
      #pragma unroll
      for (int u = 0; u < 8; ++u) o[u] = 0;
    }
    *(u16x8*)&hA[uidx(e, lane * 8)] = o;
    pA = pB; qA = qB; vA = vB;
  }
}

// ======== edge pass 0: stage -> GEMM1(w2) -> LN -> colsum -> hsum (global) ======
__global__ __launch_bounds__(512, 2) void edge0_kernel(
    const u16* __restrict__ PQ, const u16* __restrict__ w2p,
    const float* __restrict__ b2,
    const float* __restrict__ g, const float* __restrict__ bt,
    u16* __restrict__ hsum)
{
  __shared__ alignas(16) u16 hA[64 * 512];
  __shared__ f32x2 stats[64][8];
  __shared__ f32x2 mufb[64];
  int bs = blockIdx.x * SPB;
  int tid = threadIdx.x;
  int wave = tid >> 6, lane = tid & 63;

  stage_h1(PQ, bs, hA, wave, lane);
  u16x8 bpre[4];
  preload_b4(w2p, wave, lane, bpre);
  __syncthreads();

  f32x4 acc[4][4];
  zero_acc(acc);
  gemm_pipe(hA, w2p, acc, wave, lane, bpre);
  ln_relu8_t<0>(acc, hA, stats, mufb, b2, g, bt, wave, lane, tid);
  __syncthreads();                    // h2n rows visible
  // vectorized column sums: wave = source group (wave 0 also takes sl=8);
  // lane covers 8 cols. hsum[s][c0..c0+8) = sum_j h2n[sl*7+j][c]
  {
    int c0 = lane * 8;
    for (int sl = wave; sl < SPB; sl += 8){
      int s = bs + sl;
      if (s < NSRC){
        float a8[8];
        #pragma unroll
        for (int u = 0; u < 8; ++u) a8[u] = 0.f;
        #pragma unroll
        for (int j = 0; j < 7; ++j){
          u16x8 v = *(const u16x8*)&hA[uidx(sl * 7 + j, c0)];
          #pragma unroll
          for (int u = 0; u < 8; ++u) a8[u] += bf2f(v[u]);
        }
        u16x8 o;
        #pragma unroll
        for (int u = 0; u < 8; ++u) o[u] = f2bf(a8[u]);
        *(u16x8*)&hsum[(size_t)s * 512 + c0] = o;
      }
    }
  }
}

// ============ edge pass 1: w3 folded to a vector (w3f = ew3@few) ============
__global__ __launch_bounds__(512, 2) void edge1_kernel(
    const u16* __restrict__ PQ, const u16* __restrict__ w2p,
    const float* __restrict__ b2,
    const float* __restrict__ g, const float* __restrict__ bt,
    const float* __restrict__ w3f, float* __restrict__ out)
{
  __shared__ alignas(16) u16 hA[64 * 512];
  __shared__ f32x2 stats[64][8];
  __shared__ f32x2 mufb[64];
  int bs = blockIdx.x * SPB;
  int tid = threadIdx.x;
  int wave = tid >> 6, lane = tid & 63;

  stage_h1(PQ, bs, hA, wave, lane);
  u16x8 bpre[4];
  preload_b4(w2p, wave, lane, bpre);
  __syncthreads();

  f32x4 acc[4][4];
  zero_acc(acc);
  gemm_pipe(hA, w2p, acc, wave, lane, bpre);
  ln_relu8_t<1>(acc, hA, stats, mufb, b2, g, bt, wave, lane, tid);  // acc := relu(LN)
  head_partial8(acc, w3f, stats, wave, lane);
  __syncthreads();
  if (tid < EPB){
    int sl = tid / 7, j = tid % 7;
    int s = bs + sl;
    if (s < NSRC){
      int gg = s / 7, i = s % 7;
      float sum = w3f[512];   // eb3.few + feb
      #pragma unroll
      for (int w = 0; w < 8; ++w) sum += stats[tid][w][0];
      out[(size_t)gg * 56 + 7 + i * 7 + j] = sum;
    }
  }
}

// ==== node mega-kernel: r1 -> h2 -> LN -> node2 (+head) -> PQ (pass 2) ====
__global__ __launch_bounds__(512, 2) void node_mega(
    const u16* __restrict__ nodeb, const u16* __restrict__ hsumb,
    const u16* __restrict__ nw1cat, const u16* __restrict__ nw2p,
    const u16* __restrict__ nw3p, const u16* __restrict__ w1p,
    const float* __restrict__ bvec, const float* __restrict__ nb2,
    const float* __restrict__ ng, const float* __restrict__ nbt,
    const float* __restrict__ nb3, const float* __restrict__ hw,
    const float* __restrict__ hb, const float* __restrict__ b1,
    u16* __restrict__ PQ, float* __restrict__ out)
{
  __shared__ alignas(16) u16 hA[64 * 512];
  __shared__ f32x2 stats[64][8];
  __shared__ f32x2 mufb[64];
  int tid = threadIdx.x;
  int wave = tid >> 6, lane = tid & 63;
  int lrow = lane & 15, lhi = lane >> 4;
  size_t row0 = (size_t)blockIdx.x * 64;

  // r1 = relu([nodeb|hsumb] @ [nw1a|w3n] + bvec)  (K=1024, A from global)
  f32x4 acc[4][4];
  zero_acc(acc);
  gemm_k1024_gA(nodeb, hsumb, row0, nw1cat, acc, wave, lane);
  relu_to_lds(acc, hA, bvec, wave, lane);
  u16x8 bpre[4];
  preload_b4(nw2p, wave, lane, bpre);
  __syncthreads();
  // h2 = r1 @ nw2 (+nb2 in LN) -> LN -> relu -> hA
  zero_acc(acc);
  gemm_pipe(hA, nw2p, acc, wave, lane, bpre);
  ln_relu8_t<0>(acc, hA, stats, mufb, nb2, ng, nbt, wave, lane, tid);
  preload_b4(nw3p, wave, lane, bpre);
  __syncthreads();
  // node2 = h2n @ nw3 + nb3
  zero_acc(acc);
  gemm_pipe(hA, nw3p, acc, wave, lane, bpre);
  add_bias8(acc, nb3, wave, lane);
  __syncthreads();   // all GEMM reads of hA (h2n) done before overwrite
  // node2 -> hA (for PQ GEMMs); head partial
  #pragma unroll
  for (int ct = 0; ct < 4; ++ct){
    int c = wave * 64 + ct * 16 + lrow;
    #pragma unroll
    for (int mt = 0; mt < 4; ++mt)
      #pragma unroll
      for (int r = 0; r < 4; ++r)
        hA[uidx(mt * 16 + lhi * 4 + r, c)] = f2bf(acc[mt][ct][r]);
  }
  head_partial8(acc, hw, stats, wave, lane);
  __syncthreads();   // node2 + stats visible
  if (tid < 64){
    size_t v = row0 + tid;
    float s = hb[0];
    #pragma unroll
    for (int w = 0; w < 8; ++w) s += stats[tid][w][0];
    out[(v / 7) * 56 + (v % 7)] = s;
  }
  // PQ = node2 @ w1p  (N=1024, two 512-col passes; P half gets +b1)
  #pragma unroll
  for (int pp = 0; pp < 2; ++pp){
    zero_acc(acc);
    const u16* bbBase = w1p + (((size_t)(pp * 32) + wave * 4) * 64 + lane) * 8;
    gemm_pipe_s(hA, bbBase, 32768, acc, lane);
    #pragma unroll
    for (int ct = 0; ct < 4; ++ct){
      int cc = wave * 64 + ct * 16 + lrow;
      int c = pp * 512 + cc;
      float bb = (pp == 0) ? b1[cc] : 0.f;
      #pragma unroll
      for (int mt = 0; mt < 4; ++mt)
        #pragma unroll
        for (int r = 0; r < 4; ++r){
          size_t grow = row0 + mt * 16 + lhi * 4 + r;
          PQ[grow * 1024 + c] = f2bf(acc[mt][ct][r] + bb);
        }
    }
  }
}

// gemm64 MODE0: PQ = nodeb @ w1p (pass 1); P half (coff==0) gets +b1.
__global__ __launch_bounds__(256, 2) void gemm64_0(
    const u16* __restrict__ A0, const u16* __restrict__ Bp,
    const float* __restrict__ b1, u16* __restrict__ Cout)
{
  int tid = threadIdx.x;
  int wave = tid >> 6, lane = tid & 63;
  int lrow = lane & 15, lhi = lane >> 4;
  size_t row0 = (size_t)blockIdx.x * 64;
  int coff = blockIdx.y * 512;
  const u16* bb = Bp + (((size_t)(coff >> 4) + wave * 8) * 64 + lane) * 8;
  f32x4 acc[4][8];
  #pragma unroll
  for (int mt = 0; mt < 4; ++mt)
    #pragma unroll
    for (int ct = 0; ct < 8; ++ct){
      f32x4 z = {0.f, 0.f, 0.f, 0.f};
      acc[mt][ct] = z;
    }
  u16x8 b_cur[8], b_nxt[8];
  #pragma unroll
  for (int ct = 0; ct < 8; ++ct) b_cur[ct] = *(const u16x8*)&bb[ct * 512];
  #pragma unroll
  for (int kt = 0; kt < 16; ++kt){
    u16x8 af[4];
    #pragma unroll
    for (int mt = 0; mt < 4; ++mt)
      af[mt] = *(const u16x8*)&A0[(row0 + mt * 16 + lrow) * 512 + kt * 32 + lhi * 8];
    if (kt < 15){
      #pragma unroll
      for (int ct = 0; ct < 8; ++ct)
        b_nxt[ct] = *(const u16x8*)&bb[((size_t)(kt + 1) * 64 * 64 + ct * 64) * 8];
    }
    __builtin_amdgcn_s_setprio(1);
    #pragma unroll
    for (int ct = 0; ct < 8; ++ct)
      #pragma unroll
      for (int mt = 0; mt < 4; ++mt) acc[mt][ct] = mfma16(af[mt], b_cur[ct], acc[mt][ct]);
    __builtin_amdgcn_s_setprio(0);
    #pragma unroll
    for (int ct = 0; ct < 8; ++ct) b_cur[ct] = b_nxt[ct];
  }
  #pragma unroll
  for (int ct = 0; ct < 8; ++ct){
    int cc = wave * 128 + ct * 16 + lrow;
    int c = coff + cc;
    float bb2 = (coff == 0) ? b1[cc] : 0.f;
    #pragma unroll
    for (int mt = 0; mt < 4; ++mt)
      #pragma unroll
      for (int r = 0; r < 4; ++r){
        size_t grow = row0 + mt * 16 + lhi * 4 + r;
        Cout[grow * 1024 + c] = f2bf(acc[mt][ct][r] + bb2);
      }
  }
}

// w3n = ew3(f32) @ nw1b(packed bf16): 512x512, K=512. Grid (8,4).
// Output written DIRECTLY in packed B-fragment order into nw1cat+512*512.
__global__ __launch_bounds__(256) void gemm_w3n(
    const float* __restrict__ A, const u16* __restrict__ Bp, u16* __restrict__ dst)
{
  int tid = threadIdx.x;
  int wave = tid >> 6, lane = tid & 63;
  int lrow = lane & 15, lhi = lane >> 4;
  size_t row0 = (size_t)blockIdx.x * 64;
  int coff = blockIdx.y * 128;
  const u16* bb = Bp + (((size_t)(coff >> 4) + wave * 2) * 64 + lane) * 8;
  f32x4 acc[4][2];
  #pragma unroll
  for (int mt = 0; mt < 4; ++mt)
    #pragma unroll
    for (int ct = 0; ct < 2; ++ct){
      f32x4 z = {0.f, 0.f, 0.f, 0.f};
      acc[mt][ct] = z;
    }
  for (int kt = 0; kt < 16; ++kt){
    u16x8 af[4], bv[2];
    #pragma unroll
    for (int mt = 0; mt < 4; ++mt){
      const float* ar = A + (row0 + mt * 16 + lrow) * 512 + kt * 32 + lhi * 8;
      float4 v0 = *(const float4*)ar, v1 = *(const float4*)(ar + 4);
      af[mt][0] = f2bf(v0.x); af[mt][1] = f2bf(v0.y);
      af[mt][2] = f2bf(v0.z); af[mt][3] = f2bf(v0.w);
      af[mt][4] = f2bf(v1.x); af[mt][5] = f2bf(v1.y);
      af[mt][6] = f2bf(v1.z); af[mt][7] = f2bf(v1.w);
    }
    #pragma unroll
    for (int ct = 0; ct < 2; ++ct)
      bv[ct] = *(const u16x8*)&bb[(size_t)kt * 16384 + ct * 512];
    #pragma unroll
    for (int ct = 0; ct < 2; ++ct)
      #pragma unroll
      for (int mt = 0; mt < 4; ++mt) acc[mt][ct] = mfma16(af[mt], bv[ct], acc[mt][ct]);
  }
  #pragma unroll
  for (int ct = 0; ct < 2; ++ct){
    int c = coff + wave * 32 + ct * 16 + lrow;
    int ctp = c >> 4, lanelo = c & 15;
    #pragma unroll
    for (int mt = 0; mt < 4; ++mt)
      #pragma unroll
      for (int r = 0; r < 4; ++r){
        int k = (int)row0 + mt * 16 + lhi * 4 + r;
        int kt = k >> 5, lanehi = (k >> 3) & 3, j = k & 7;
        dst[((size_t)(kt * 32 + ctp) * 64 + lanehi * 16 + lanelo) * 8 + j]
            = f2bf(acc[mt][ct][r]);
      }
  }
}

// ==== prep_all: all packing / folding / casting in ONE launch ====
__device__ __forceinline__ void pack_body(const float* __restrict__ W, u16* __restrict__ dst,
                                          int N, int w1mode, int idx){
  int lane = idx & 63;
  int t = idx >> 6;
  int nt = N >> 4;
  int ct = t % nt;
  int kt = t / nt;
  int c  = ct * 16 + (lane & 15);
  int k0 = kt * 32 + (lane >> 4) * 8;
  u16x8 o;
  #pragma unroll
  for (int j = 0; j < 8; ++j){
    int k = k0 + j;
    float v;
    if (w1mode){
      v = (c < 512) ? W[(size_t)k * 512 + c] : W[(size_t)(k + 512) * 512 + (c - 512)];
    } else {
      v = W[(size_t)k * N + c];
    }
    o[j] = f2bf(v);
  }
  *(u16x8*)&dst[(size_t)idx * 8] = o;
}

__global__ __launch_bounds__(256) void prep_all(
    const float* __restrict__ states,
    const float* __restrict__ ew1, const float* __restrict__ nw1,
    const float* __restrict__ ew2, const float* __restrict__ nw2,
    const float* __restrict__ nw3, const float* __restrict__ ew3,
    const float* __restrict__ few, const float* __restrict__ eb3,
    const float* __restrict__ feb, const float* __restrict__ nb1,
    u16* __restrict__ nodeb, u16* __restrict__ w1p, u16* __restrict__ nw1cat,
    u16* __restrict__ nw1bp, u16* __restrict__ w2p, u16* __restrict__ nw2p,
    u16* __restrict__ nw3p, float* __restrict__ w3f, float* __restrict__ bvec)
{
  int blk = blockIdx.x;
  int tid = threadIdx.x;
  if (blk < 256){
    pack_body(ew1, w1p, 1024, 1, blk * 256 + tid);
  } else if (blk < 384){
    pack_body(nw1, nw1cat, 512, 0, (blk - 256) * 256 + tid);
  } else if (blk < 512){
    pack_body(nw1 + 512 * 512, nw1bp, 512, 0, (blk - 384) * 256 + tid);
  } else if (blk < 640){
    pack_body(ew2, w2p, 512, 0, (blk - 512) * 256 + tid);
  } else if (blk < 768){
    pack_body(nw2, nw2p, 512, 0, (blk - 640) * 256 + tid);
  } else if (blk < 896){
    pack_body(nw3, nw3p, 512, 0, (blk - 768) * 256 + tid);
  } else if (blk < 1025){
    int k = (blk - 896) * 4 + (tid >> 6);
    int l = tid & 63;
    if (k <= 512){
      const float* row = (k < 512) ? (ew3 + (size_t)k * 512) : eb3;
      float s = 0.f;
      for (int c = l; c < 512; c += 64) s += row[c] * few[c];
      #pragma unroll
      for (int off = 32; off; off >>= 1) s += __shfl_down(s, off);
      if (l == 0) w3f[k] = (k < 512) ? s : s + feb[0];
    }
  } else if (blk < 1027){
    int c = (blk - 1025) * 256 + tid;
    float s = 0.f;
    for (int m = 0; m < 512; ++m)
      s += eb3[m] * nw1[(size_t)(512 + m) * 512 + c];
    bvec[c] = nb1[c] + 7.f * s;
  } else {
    int idx = (blk - 1027) * 256 + tid;   // cast_node, n8 = NV*512/8
    const float4* s = (const float4*)states;
    float4 a = s[(size_t)idx * 2], b = s[(size_t)idx * 2 + 1];
    u16x8 o;
    o[0] = f2bf(a.x); o[1] = f2bf(a.y); o[2] = f2bf(a.z); o[3] = f2bf(a.w);
    o[4] = f2bf(b.x); o[5] = f2bf(b.y); o[6] = f2bf(b.z); o[7] = f2bf(b.w);
    *(u16x8*)&nodeb[(size_t)idx * 8] = o;
  }
}

extern "C" void kernel_launch(void* const* d_in, const int* in_sizes, int n_in,
                              void* d_out, int out_size, void* d_ws, size_t ws_size,
                              hipStream_t stream)
{
  (void)in_sizes; (void)n_in; (void)out_size; (void)ws_size;
  const float* states = (const float*)d_in[0];
  const float* ew1 = (const float*)d_in[1];
  const float* eb1 = (const float*)d_in[2];
  const float* ew2 = (const float*)d_in[3];
  const float* eb2 = (const float*)d_in[4];
  const float* eg  = (const float*)d_in[5];
  const float* ebt = (const float*)d_in[6];
  const float* ew3 = (const float*)d_in[7];
  const float* eb3 = (const float*)d_in[8];
  const float* nw1 = (const float*)d_in[9];
  const float* nb1 = (const float*)d_in[10];
  const float* nw2 = (const float*)d_in[11];
  const float* nb2 = (const float*)d_in[12];
  const float* ng  = (const float*)d_in[13];
  const float* nbt = (const float*)d_in[14];
  const float* nw3 = (const float*)d_in[15];
  const float* nb3 = (const float*)d_in[16];
  const float* fnw = (const float*)d_in[17];
  const float* fnb = (const float*)d_in[18];
  const float* few = (const float*)d_in[19];
  const float* feb = (const float*)d_in[20];
  float* out = (float*)d_out;

  char* ws = (char*)d_ws;
  size_t off = 0;
  auto alloc = [&](size_t bytes) -> void* {
    void* p = ws + off;
    off += (bytes + 255) & ~(size_t)255;
    return p;
  };
  const size_t NV = 28672;  // B*n
  u16* PQ     = (u16*)alloc(NV * 1024 * 2);   // [NV][P'(512)|Q(512)] bf16 (P' = P+b1)
  u16* nodeb  = (u16*)alloc(NV * 512 * 2);
  u16* hsumb  = (u16*)alloc(NV * 512 * 2);
  u16* w1p    = (u16*)alloc(512 * 1024 * 2);
  u16* nw1cat = (u16*)alloc(1024 * 512 * 2);  // [nw1a packed | w3n packed]
  u16* nw1bp  = (u16*)alloc(512 * 512 * 2);
  u16* w2p    = (u16*)alloc(512 * 512 * 2);
  u16* nw2p   = (u16*)alloc(512 * 512 * 2);
  u16* nw3p   = (u16*)alloc(512 * 512 * 2);
  float* w3f  = (float*)alloc(513 * 4);
  float* bvec = (float*)alloc(512 * 4);

  // all packing/folding/casting in one launch (segments by blockIdx)
  prep_all<<<1027 + 7168, 256, 0, stream>>>(
      states, ew1, nw1, ew2, nw2, nw3, ew3, few, eb3, feb, nb1,
      nodeb, w1p, nw1cat, nw1bp, w2p, nw2p, nw3p, w3f, bvec);
  // w3n = ew3 @ nw1b, written directly packed into nw1cat second half
  gemm_w3n<<<dim3(8, 4), 256, 0, stream>>>(ew3, nw1bp, nw1cat + 512 * 512);

  // Pass 1
  gemm64_0<<<dim3(448, 2), 256, 0, stream>>>(nodeb, w1p, eb1, PQ);
  edge0_kernel<<<NB_E, 512, 0, stream>>>(PQ, w2p, eb2, eg, ebt, hsumb);
  // Node update + head + PQ for pass 2 (fused)
  node_mega<<<448, 512, 0, stream>>>(nodeb, hsumb, nw1cat, nw2p, nw3p, w1p,
                                     bvec, nb2, ng, nbt, nb3, fnw, fnb, eb1, PQ, out);
  // Pass 2 edge head
  edge1_kernel<<<NB_E, 512, 0, stream>>>(PQ, w2p, eb2, eg, ebt, w3f, out);
}

// Round 20
// 518.861 us; speedup vs baseline: 1.4983x; 1.0388x over previous
//
#include <hip/hip_runtime.h>

#define LN_EPS 1e-5f
#define NSRC 28672          // total source nodes (B*n)
#define SPB 9               // source groups per edge block
#define EPB 63              // edges per block = SPB*7
#define NB_E 3186           // ceil(NSRC / SPB)

typedef unsigned short u16;
typedef u16 u16x8 __attribute__((ext_vector_type(8)));
typedef __bf16 bf16x8 __attribute__((ext_vector_type(8)));
typedef float f32x4 __attribute__((ext_vector_type(4)));
typedef float f32x2 __attribute__((ext_vector_type(2)));

__device__ __forceinline__ u16 f2bf(float f){
  return __builtin_bit_cast(u16, (__bf16)f);
}
__device__ __forceinline__ float bf2f(u16 b){
  return (float)__builtin_bit_cast(__bf16, b);
}
__device__ __forceinline__ f32x4 mfma16(u16x8 a, u16x8 b, f32x4 c){
  return __builtin_amdgcn_mfma_f32_16x16x32_bf16(
      __builtin_bit_cast(bf16x8, a), __builtin_bit_cast(bf16x8, b), c, 0, 0, 0);
}
// LDS h-tile: [64 rows][512 k] bf16, XOR swizzle on k (8-elem granules)
__device__ __forceinline__ int uidx(int row, int k){
  return row * 512 + (k ^ ((row & 7) << 3));
}

__device__ __forceinline__ void zero_acc(f32x4 (&acc)[4][4]){
  #pragma unroll
  for (int mt = 0; mt < 4; ++mt)
    #pragma unroll
    for (int ct = 0; ct < 4; ++ct){
      f32x4 z = {0.f, 0.f, 0.f, 0.f};
      acc[mt][ct] = z;
    }
}

// Issue first kt's 4 B-fragment loads BEFORE the preceding barrier (in flight
// across s_barrier; hides cold-start L2 latency).
__device__ __forceinline__ void preload_b4(const u16* __restrict__ Bp, int wave, int lane,
                                           u16x8 (&b)[4]){
  const u16* bb = Bp + ((size_t)(wave * 4) * 64 + lane) * 8;
  #pragma unroll
  for (int ct = 0; ct < 4; ++ct) b[ct] = *(const u16x8*)&bb[ct * 512];
}

// GEMM, A from LDS (64 rows), B from global (N=512 packing, kt-stride 16384),
// 1-deep register prefetch (~64 VGPR clean). b_cur arrives preloaded.
__device__ __forceinline__ void gemm_pipe(const u16* hA, const u16* __restrict__ Bp,
                                          f32x4 (&acc)[4][4], int wave, int lane,
                                          u16x8 (&b_cur)[4]){
  int lrow = lane & 15, lhi = lane >> 4;
  const u16* bb = Bp + ((size_t)(wave * 4) * 64 + lane) * 8;
  u16x8 b_nxt[4], a[4];
  #pragma unroll
  for (int kt = 0; kt < 16; ++kt){
    #pragma unroll
    for (int mt = 0; mt < 4; ++mt)
      a[mt] = *(const u16x8*)&hA[uidx(mt * 16 + lrow, kt * 32 + lhi * 8)];
    if (kt < 15){
      #pragma unroll
      for (int ct = 0; ct < 4; ++ct)
        b_nxt[ct] = *(const u16x8*)&bb[(size_t)(kt + 1) * 16384 + ct * 512];
    }
    __builtin_amdgcn_s_setprio(1);
    #pragma unroll
    for (int ct = 0; ct < 4; ++ct)
      #pragma unroll
      for (int mt = 0; mt < 4; ++mt)
        acc[mt][ct] = mfma16(a[mt], b_cur[ct], acc[mt][ct]);
    __builtin_amdgcn_s_setprio(0);
    #pragma unroll
    for (int ct = 0; ct < 4; ++ct) b_cur[ct] = b_nxt[ct];
  }
}

// K=1024 GEMM, A rows from TWO global sources (nodeb | hsumb), B packed K=1024
// (kt-stride 16384, KT=32).
__device__ __forceinline__ void gemm_k1024_gA(const u16* __restrict__ A0,
                                              const u16* __restrict__ A1, size_t row0,
                                              const u16* __restrict__ Bp,
                                              f32x4 (&acc)[4][4], int wave, int lane){
  int lrow = lane & 15, lhi = lane >> 4;
  const u16* bb = Bp + ((size_t)(wave * 4) * 64 + lane) * 8;
  const u16* a0 = A0 + (row0 + lrow) * 512 + lhi * 8;
  const u16* a1 = A1 + (row0 + lrow) * 512 + lhi * 8;
  u16x8 b_cur[4], b_nxt[4], a[4];
  #pragma unroll
  for (int ct = 0; ct < 4; ++ct) b_cur[ct] = *(const u16x8*)&bb[ct * 512];
  #pragma unroll
  for (int kt = 0; kt < 32; ++kt){
    const u16* ab = (kt < 16) ? a0 : a1;
    int kk = (kt & 15) * 32;
    #pragma unroll
    for (int mt = 0; mt < 4; ++mt)
      a[mt] = *(const u16x8*)&ab[mt * 8192 + kk];
    if (kt < 31){
      #pragma unroll
      for (int ct = 0; ct < 4; ++ct)
        b_nxt[ct] = *(const u16x8*)&bb[(size_t)(kt + 1) * 16384 + ct * 512];
    }
    __builtin_amdgcn_s_setprio(1);
    #pragma unroll
    for (int ct = 0; ct < 4; ++ct)
      #pragma unroll
      for (int mt = 0; mt < 4; ++mt)
        acc[mt][ct] = mfma16(a[mt], b_cur[ct], acc[mt][ct]);
    __builtin_amdgcn_s_setprio(0);
    #pragma unroll
    for (int ct = 0; ct < 4; ++ct) b_cur[ct] = b_nxt[ct];
  }
}

// GEMM over hA with custom B base/kt-stride (for N=1024 w1p packing).
__device__ __forceinline__ void gemm_pipe_s(const u16* hA, const u16* __restrict__ bbBase,
                                            int ktStride, f32x4 (&acc)[4][4],
                                            int lane){
  int lrow = lane & 15, lhi = lane >> 4;
  u16x8 b_cur[4], b_nxt[4], a[4];
  #pragma unroll
  for (int ct = 0; ct < 4; ++ct) b_cur[ct] = *(const u16x8*)&bbBase[ct * 512];
  #pragma unroll
  for (int kt = 0; kt < 16; ++kt){
    #pragma unroll
    for (int mt = 0; mt < 4; ++mt)
      a[mt] = *(const u16x8*)&hA[uidx(mt * 16 + lrow, kt * 32 + lhi * 8)];
    if (kt < 15){
      #pragma unroll
      for (int ct = 0; ct < 4; ++ct)
        b_nxt[ct] = *(const u16x8*)&bbBase[(size_t)(kt + 1) * ktStride + ct * 512];
    }
    __builtin_amdgcn_s_setprio(1);
    #pragma unroll
    for (int ct = 0; ct < 4; ++ct)
      #pragma unroll
      for (int mt = 0; mt < 4; ++mt)
        acc[mt][ct] = mfma16(a[mt], b_cur[ct], acc[mt][ct]);
    __builtin_amdgcn_s_setprio(0);
    #pragma unroll
    for (int ct = 0; ct < 4; ++ct) b_cur[ct] = b_nxt[ct];
  }
}

__device__ __forceinline__ void add_bias8(f32x4 (&acc)[4][4], const float* __restrict__ b,
                                          int wave, int lane){
  int lrow = lane & 15;
  #pragma unroll
  for (int ct = 0; ct < 4; ++ct){
    float bb = b[wave * 64 + ct * 16 + lrow];
    #pragma unroll
    for (int mt = 0; mt < 4; ++mt)
      #pragma unroll
      for (int r = 0; r < 4; ++r) acc[mt][ct][r] += bb;
  }
}

// acc += bias; relu; write bf16 into hA (swizzled). (r1 stage of node MLP.)
__device__ __forceinline__ void relu_to_lds(f32x4 (&acc)[4][4], u16* hA,
                                            const float* __restrict__ b,
                                            int wave, int lane){
  int lrow = lane & 15, lhi = lane >> 4;
  #pragma unroll
  for (int ct = 0; ct < 4; ++ct){
    int c = wave * 64 + ct * 16 + lrow;
    float bb = b[c];
    #pragma unroll
    for (int mt = 0; mt < 4; ++mt)
      #pragma unroll
      for (int r = 0; r < 4; ++r){
        int row = mt * 16 + lhi * 4 + r;
        hA[uidx(row, c)] = f2bf(fmaxf(acc[mt][ct][r] + bb, 0.f));
      }
  }
}

// acc += b2; LayerNorm over 512 cols per row; relu.  (r15-measured: 64 VGPR)
// TO_ACC=0: write bf16 into hA (swizzled); TO_ACC=1: result into acc.
template<int TO_ACC>
__device__ __forceinline__ void ln_relu8_t(f32x4 (&acc)[4][4], u16* hA,
    f32x2 (*stats)[8], f32x2* mufb,
    const float* __restrict__ b2, const float* __restrict__ g, const float* __restrict__ bt,
    int wave, int lane, int tid)
{
  int lrow = lane & 15, lhi = lane >> 4;
  float s1[4][4], s2[4][4];
  #pragma unroll
  for (int mt = 0; mt < 4; ++mt)
    #pragma unroll
    for (int r = 0; r < 4; ++r){ s1[mt][r] = 0.f; s2[mt][r] = 0.f; }
  #pragma unroll
  for (int ct = 0; ct < 4; ++ct){
    int c = wave * 64 + ct * 16 + lrow;
    float bb = b2[c];
    #pragma unroll
    for (int mt = 0; mt < 4; ++mt)
      #pragma unroll
      for (int r = 0; r < 4; ++r){
        float x = acc[mt][ct][r] + bb;
        acc[mt][ct][r] = x;
        s1[mt][r] += x; s2[mt][r] += x * x;
      }
  }
  #pragma unroll
  for (int off = 1; off < 16; off <<= 1){
    #pragma unroll
    for (int mt = 0; mt < 4; ++mt)
      #pragma unroll
      for (int r = 0; r < 4; ++r){
        s1[mt][r] += __shfl_xor(s1[mt][r], off);
        s2[mt][r] += __shfl_xor(s2[mt][r], off);
      }
  }
  float sa1 = 0.f, sa2 = 0.f;
  #pragma unroll
  for (int mt = 0; mt < 4; ++mt)
    #pragma unroll
    for (int r = 0; r < 4; ++r)
      if (lrow == mt * 4 + r){ sa1 = s1[mt][r]; sa2 = s2[mt][r]; }
  int rowa = (lrow >> 2) * 16 + lhi * 4 + (lrow & 3);
  f32x2 pa = {sa1, sa2};
  stats[rowa][wave] = pa;
  __syncthreads();              // also: all waves done reading hA (prev GEMM)
  if (tid < 64){
    float a = 0.f, b = 0.f;
    #pragma unroll
    for (int w = 0; w < 8; ++w){ a += stats[tid][w][0]; b += stats[tid][w][1]; }
    float mu  = a * (1.f / 512.f);
    float var = b * (1.f / 512.f) - mu * mu;
    f32x2 mr = {mu, rsqrtf(fmaxf(var, 0.f) + LN_EPS)};
    mufb[tid] = mr;
  }
  __syncthreads();
  float gv[4], btv[4];
  #pragma unroll
  for (int ct = 0; ct < 4; ++ct){
    int c = wave * 64 + ct * 16 + lrow;
    gv[ct] = g[c]; btv[ct] = bt[c];
  }
  #pragma unroll
  for (int mt = 0; mt < 4; ++mt)
    #pragma unroll
    for (int r = 0; r < 4; ++r){
      int row = mt * 16 + lhi * 4 + r;
      f32x2 mr = mufb[row];
      #pragma unroll
      for (int ct = 0; ct < 4; ++ct){
        int c = wave * 64 + ct * 16 + lrow;
        float x = (acc[mt][ct][r] - mr[0]) * mr[1] * gv[ct] + btv[ct];
        if (TO_ACC) acc[mt][ct][r] = fmaxf(x, 0.f);
        else        hA[uidx(row, c)] = f2bf(fmaxf(x, 0.f));
      }
    }
  // TO_ACC=0 caller: barrier before any cross-thread hA read.
}

// dot each row with weight vector w; per-wave partial -> stats[row][wave].x
__device__ __forceinline__ void head_partial8(f32x4 (&acc)[4][4], const float* __restrict__ w,
                                              f32x2 (*stats)[8], int wave, int lane)
{
  int lrow = lane & 15, lhi = lane >> 4;
  float hs[4][4];
  #pragma unroll
  for (int mt = 0; mt < 4; ++mt)
    #pragma unroll
    for (int r = 0; r < 4; ++r) hs[mt][r] = 0.f;
  #pragma unroll
  for (int ct = 0; ct < 4; ++ct){
    int c = wave * 64 + ct * 16 + lrow;
    float f = w[c];
    #pragma unroll
    for (int mt = 0; mt < 4; ++mt)
      #pragma unroll
      for (int r = 0; r < 4; ++r) hs[mt][r] += acc[mt][ct][r] * f;
  }
  #pragma unroll
  for (int off = 1; off < 16; off <<= 1)
    #pragma unroll
    for (int mt = 0; mt < 4; ++mt)
      #pragma unroll
      for (int r = 0; r < 4; ++r) hs[mt][r] += __shfl_xor(hs[mt][r], off);
  float sa = 0.f;
  #pragma unroll
  for (int mt = 0; mt < 4; ++mt)
    #pragma unroll
    for (int r = 0; r < 4; ++r)
      if (lrow == mt * 4 + r) sa = hs[mt][r];
  int rowa = (lrow >> 2) * 16 + lhi * 4 + (lrow & 3);
  f32x2 pa = {sa, 0.f};
  stats[rowa][wave] = pa;
}

// Staging, wave-per-source-group: block covers sources bs..bs+8 (9 groups, 63
// rows; row = grp*7+j). Wave w stages group w (wave 0 also group 8); P'[s]
// loaded ONCE per group (vs 7x), Q pipelined 1-deep. Row 63 zeroed by wave 1;
// groups with s >= NSRC zeroed.
__device__ __forceinline__ void stage_h1(const u16* __restrict__ PQ, int bs, u16* hA,
                                         int wave, int lane){
  for (int grp = wave; grp < SPB; grp += 8){
    int s = bs + grp;
    int r0 = grp * 7;
    if (s < NSRC){
      u16x8 p8 = *(const u16x8*)&PQ[(size_t)s * 1024 + lane * 8];
      const u16* Qb = PQ + (size_t)(s - s % 7) * 1024 + 512 + lane * 8;
      u16x8 q_cur = *(const u16x8*)&Qb[0];
      #pragma unroll
      for (int j = 0; j < 7; ++j){
        u16x8 q_nxt;
        if (j < 6) q_nxt = *(const u16x8*)&Qb[(size_t)(j + 1) * 1024];
        u16x8 o;
        #pragma unroll
        for (int u = 0; u < 8; ++u)
          o[u] = f2bf(fmaxf(bf2f(p8[u]) + bf2f(q_cur[u]), 0.f));
        *(u16x8*)&hA[uidx(r0 + j, lane * 8)] = o;
        q_cur = q_nxt;
      }
    } else {
      u16x8 z;
      #pragma unroll
      for (int u = 0; u < 8; ++u) z[u] = 0;
      #pragma unroll
      for (int j = 0; j < 7; ++j)
        *(u16x8*)&hA[uidx(r0 + j, lane * 8)] = z;
    }
  }
  if (wave == 1){
    u16x8 z;
    #pragma unroll
    for (int u = 0; u < 8; ++u) z[u] = 0;
    *(u16x8*)&hA[uidx(63, lane * 8)] = z;
  }
}

// ======== edge pass 0: stage -> GEMM1(w2) -> LN -> colsum -> hsum (global) ======
__global__ __launch_bounds__(512, 2) void edge0_kernel(
    const u16* __restrict__ PQ, const u16* __restrict__ w2p,
    const float* __restrict__ b2,
    const float* __restrict__ g, const float* __restrict__ bt,
    u16* __restrict__ hsum)
{
  __shared__ alignas(16) u16 hA[64 * 512];
  __shared__ f32x2 stats[64][8];
  __shared__ f32x2 mufb[64];
  int bs = blockIdx.x * SPB;
  int tid = threadIdx.x;
  int wave = tid >> 6, lane = tid & 63;

  stage_h1(PQ, bs, hA, wave, lane);
  u16x8 bpre[4];
  preload_b4(w2p, wave, lane, bpre);
  __syncthreads();

  f32x4 acc[4][4];
  zero_acc(acc);
  gemm_pipe(hA, w2p, acc, wave, lane, bpre);
  ln_relu8_t<0>(acc, hA, stats, mufb, b2, g, bt, wave, lane, tid);
  __syncthreads();                    // h2n rows visible
  // vectorized column sums: wave = source group (wave 0 also takes sl=8);
  // lane covers 8 cols. hsum[s][c0..c0+8) = sum_j h2n[sl*7+j][c]
  {
    int c0 = lane * 8;
    for (int sl = wave; sl < SPB; sl += 8){
      int s = bs + sl;
      if (s < NSRC){
        float a8[8];
        #pragma unroll
        for (int u = 0; u < 8; ++u) a8[u] = 0.f;
        #pragma unroll
        for (int j = 0; j < 7; ++j){
          u16x8 v = *(const u16x8*)&hA[uidx(sl * 7 + j, c0)];
          #pragma unroll
          for (int u = 0; u < 8; ++u) a8[u] += bf2f(v[u]);
        }
        u16x8 o;
        #pragma unroll
        for (int u = 0; u < 8; ++u) o[u] = f2bf(a8[u]);
        *(u16x8*)&hsum[(size_t)s * 512 + c0] = o;
      }
    }
  }
}

// ============ edge pass 1: w3 folded to a vector (w3f = ew3@few) ============
__global__ __launch_bounds__(512, 2) void edge1_kernel(
    const u16* __restrict__ PQ, const u16* __restrict__ w2p,
    const float* __restrict__ b2,
    const float* __restrict__ g, const float* __restrict__ bt,
    const float* __restrict__ w3f, float* __restrict__ out)
{
  __shared__ alignas(16) u16 hA[64 * 512];
  __shared__ f32x2 stats[64][8];
  __shared__ f32x2 mufb[64];
  int bs = blockIdx.x * SPB;
  int tid = threadIdx.x;
  int wave = tid >> 6, lane = tid & 63;

  stage_h1(PQ, bs, hA, wave, lane);
  u16x8 bpre[4];
  preload_b4(w2p, wave, lane, bpre);
  __syncthreads();

  f32x4 acc[4][4];
  zero_acc(acc);
  gemm_pipe(hA, w2p, acc, wave, lane, bpre);
  ln_relu8_t<1>(acc, hA, stats, mufb, b2, g, bt, wave, lane, tid);  // acc := relu(LN)
  head_partial8(acc, w3f, stats, wave, lane);
  __syncthreads();
  if (tid < EPB){
    int sl = tid / 7, j = tid % 7;
    int s = bs + sl;
    if (s < NSRC){
      int gg = s / 7, i = s % 7;
      float sum = w3f[512];   // eb3.few + feb
      #pragma unroll
      for (int w = 0; w < 8; ++w) sum += stats[tid][w][0];
      out[(size_t)gg * 56 + 7 + i * 7 + j] = sum;
    }
  }
}

// ==== node mega-kernel: r1 -> h2 -> LN -> node2 (+head) -> PQ (pass 2) ====
__global__ __launch_bounds__(512, 2) void node_mega(
    const u16* __restrict__ nodeb, const u16* __restrict__ hsumb,
    const u16* __restrict__ nw1cat, const u16* __restrict__ nw2p,
    const u16* __restrict__ nw3p, const u16* __restrict__ w1p,
    const float* __restrict__ bvec, const float* __restrict__ nb2,
    const float* __restrict__ ng, const float* __restrict__ nbt,
    const float* __restrict__ nb3, const float* __restrict__ hw,
    const float* __restrict__ hb, const float* __restrict__ b1,
    u16* __restrict__ PQ, float* __restrict__ out)
{
  __shared__ alignas(16) u16 hA[64 * 512];
  __shared__ f32x2 stats[64][8];
  __shared__ f32x2 mufb[64];
  int tid = threadIdx.x;
  int wave = tid >> 6, lane = tid & 63;
  int lrow = lane & 15, lhi = lane >> 4;
  size_t row0 = (size_t)blockIdx.x * 64;

  // r1 = relu([nodeb|hsumb] @ [nw1a|w3n] + bvec)  (K=1024, A from global)
  f32x4 acc[4][4];
  zero_acc(acc);
  gemm_k1024_gA(nodeb, hsumb, row0, nw1cat, acc, wave, lane);
  relu_to_lds(acc, hA, bvec, wave, lane);
  u16x8 bpre[4];
  preload_b4(nw2p, wave, lane, bpre);
  __syncthreads();
  // h2 = r1 @ nw2 (+nb2 in LN) -> LN -> relu -> hA
  zero_acc(acc);
  gemm_pipe(hA, nw2p, acc, wave, lane, bpre);
  ln_relu8_t<0>(acc, hA, stats, mufb, nb2, ng, nbt, wave, lane, tid);
  preload_b4(nw3p, wave, lane, bpre);
  __syncthreads();
  // node2 = h2n @ nw3 + nb3
  zero_acc(acc);
  gemm_pipe(hA, nw3p, acc, wave, lane, bpre);
  add_bias8(acc, nb3, wave, lane);
  __syncthreads();   // all GEMM reads of hA (h2n) done before overwrite
  // node2 -> hA (for PQ GEMMs); head partial
  #pragma unroll
  for (int ct = 0; ct < 4; ++ct){
    int c = wave * 64 + ct * 16 + lrow;
    #pragma unroll
    for (int mt = 0; mt < 4; ++mt)
      #pragma unroll
      for (int r = 0; r < 4; ++r)
        hA[uidx(mt * 16 + lhi * 4 + r, c)] = f2bf(acc[mt][ct][r]);
  }
  head_partial8(acc, hw, stats, wave, lane);
  __syncthreads();   // node2 + stats visible
  if (tid < 64){
    size_t v = row0 + tid;
    float s = hb[0];
    #pragma unroll
    for (int w = 0; w < 8; ++w) s += stats[tid][w][0];
    out[(v / 7) * 56 + (v % 7)] = s;
  }
  // PQ = node2 @ w1p  (N=1024, two 512-col passes; P half gets +b1)
  #pragma unroll
  for (int pp = 0; pp < 2; ++pp){
    zero_acc(acc);
    const u16* bbBase = w1p + (((size_t)(pp * 32) + wave * 4) * 64 + lane) * 8;
    gemm_pipe_s(hA, bbBase, 32768, acc, lane);
    #pragma unroll
    for (int ct = 0; ct < 4; ++ct){
      int cc = wave * 64 + ct * 16 + lrow;
      int c = pp * 512 + cc;
      float bb = (pp == 0) ? b1[cc] : 0.f;
      #pragma unroll
      for (int mt = 0; mt < 4; ++mt)
        #pragma unroll
        for (int r = 0; r < 4; ++r){
          size_t grow = row0 + mt * 16 + lhi * 4 + r;
          PQ[grow * 1024 + c] = f2bf(acc[mt][ct][r] + bb);
        }
    }
  }
}

// gemm64 MODE0: PQ = nodeb @ w1p (pass 1); P half (coff==0) gets +b1.
__global__ __launch_bounds__(256, 2) void gemm64_0(
    const u16* __restrict__ A0, const u16* __restrict__ Bp,
    const float* __restrict__ b1, u16* __restrict__ Cout)
{
  int tid = threadIdx.x;
  int wave = tid >> 6, lane = tid & 63;
  int lrow = lane & 15, lhi = lane >> 4;
  size_t row0 = (size_t)blockIdx.x * 64;
  int coff = blockIdx.y * 512;
  const u16* bb = Bp + (((size_t)(coff >> 4) + wave * 8) * 64 + lane) * 8;
  f32x4 acc[4][8];
  #pragma unroll
  for (int mt = 0; mt < 4; ++mt)
    #pragma unroll
    for (int ct = 0; ct < 8; ++ct){
      f32x4 z = {0.f, 0.f, 0.f, 0.f};
      acc[mt][ct] = z;
    }
  u16x8 b_cur[8], b_nxt[8];
  #pragma unroll
  for (int ct = 0; ct < 8; ++ct) b_cur[ct] = *(const u16x8*)&bb[ct * 512];
  #pragma unroll
  for (int kt = 0; kt < 16; ++kt){
    u16x8 af[4];
    #pragma unroll
    for (int mt = 0; mt < 4; ++mt)
      af[mt] = *(const u16x8*)&A0[(row0 + mt * 16 + lrow) * 512 + kt * 32 + lhi * 8];
    if (kt < 15){
      #pragma unroll
      for (int ct = 0; ct < 8; ++ct)
        b_nxt[ct] = *(const u16x8*)&bb[((size_t)(kt + 1) * 64 * 64 + ct * 64) * 8];
    }
    __builtin_amdgcn_s_setprio(1);
    #pragma unroll
    for (int ct = 0; ct < 8; ++ct)
      #pragma unroll
      for (int mt = 0; mt < 4; ++mt) acc[mt][ct] = mfma16(af[mt], b_cur[ct], acc[mt][ct]);
    __builtin_amdgcn_s_setprio(0);
    #pragma unroll
    for (int ct = 0; ct < 8; ++ct) b_cur[ct] = b_nxt[ct];
  }
  #pragma unroll
  for (int ct = 0; ct < 8; ++ct){
    int cc = wave * 128 + ct * 16 + lrow;
    int c = coff + cc;
    float bb2 = (coff == 0) ? b1[cc] : 0.f;
    #pragma unroll
    for (int mt = 0; mt < 4; ++mt)
      #pragma unroll
      for (int r = 0; r < 4; ++r){
        size_t grow = row0 + mt * 16 + lhi * 4 + r;
        Cout[grow * 1024 + c] = f2bf(acc[mt][ct][r] + bb2);
      }
  }
}

// w3n = ew3(f32) @ nw1b(packed bf16): 512x512, K=512. Grid (8,4).
// Output written DIRECTLY in packed B-fragment order into nw1cat+512*512.
__global__ __launch_bounds__(256) void gemm_w3n(
    const float* __restrict__ A, const u16* __restrict__ Bp, u16* __restrict__ dst)
{
  int tid = threadIdx.x;
  int wave = tid >> 6, lane = tid & 63;
  int lrow = lane & 15, lhi = lane >> 4;
  size_t row0 = (size_t)blockIdx.x * 64;
  int coff = blockIdx.y * 128;
  const u16* bb = Bp + (((size_t)(coff >> 4) + wave * 2) * 64 + lane) * 8;
  f32x4 acc[4][2];
  #pragma unroll
  for (int mt = 0; mt < 4; ++mt)
    #pragma unroll
    for (int ct = 0; ct < 2; ++ct){
      f32x4 z = {0.f, 0.f, 0.f, 0.f};
      acc[mt][ct] = z;
    }
  for (int kt = 0; kt < 16; ++kt){
    u16x8 af[4], bv[2];
    #pragma unroll
    for (int mt = 0; mt < 4; ++mt){
      const float* ar = A + (row0 + mt * 16 + lrow) * 512 + kt * 32 + lhi * 8;
      float4 v0 = *(const float4*)ar, v1 = *(const float4*)(ar + 4);
      af[mt][0] = f2bf(v0.x); af[mt][1] = f2bf(v0.y);
      af[mt][2] = f2bf(v0.z); af[mt][3] = f2bf(v0.w);
      af[mt][4] = f2bf(v1.x); af[mt][5] = f2bf(v1.y);
      af[mt][6] = f2bf(v1.z); af[mt][7] = f2bf(v1.w);
    }
    #pragma unroll
    for (int ct = 0; ct < 2; ++ct)
      bv[ct] = *(const u16x8*)&bb[(size_t)kt * 16384 + ct * 512];
    #pragma unroll
    for (int ct = 0; ct < 2; ++ct)
      #pragma unroll
      for (int mt = 0; mt < 4; ++mt) acc[mt][ct] = mfma16(af[mt], bv[ct], acc[mt][ct]);
  }
  #pragma unroll
  for (int ct = 0; ct < 2; ++ct){
    int c = coff + wave * 32 + ct * 16 + lrow;
    int ctp = c >> 4, lanelo = c & 15;
    #pragma unroll
    for (int mt = 0; mt < 4; ++mt)
      #pragma unroll
      for (int r = 0; r < 4; ++r){
        int k = (int)row0 + mt * 16 + lhi * 4 + r;
        int kt = k >> 5, lanehi = (k >> 3) & 3, j = k & 7;
        dst[((size_t)(kt * 32 + ctp) * 64 + lanehi * 16 + lanelo) * 8 + j]
            = f2bf(acc[mt][ct][r]);
      }
  }
}

// ==== prep_all: all packing / folding / casting in ONE launch ====
__device__ __forceinline__ void pack_body(const float* __restrict__ W, u16* __restrict__ dst,
                                          int N, int w1mode, int idx){
  int lane = idx & 63;
  int t = idx >> 6;
  int nt = N >> 4;
  int ct = t % nt;
  int kt = t / nt;
  int c  = ct * 16 + (lane & 15);
  int k0 = kt * 32 + (lane >> 4) * 8;
  u16x8 o;
  #pragma unroll
  for (int j = 0; j < 8; ++j){
    int k = k0 + j;
    float v;
    if (w1mode){
      v = (c < 512) ? W[(size_t)k * 512 + c] : W[(size_t)(k + 512) * 512 + (c - 512)];
    } else {
      v = W[(size_t)k * N + c];
    }
    o[j] = f2bf(v);
  }
  *(u16x8*)&dst[(size_t)idx * 8] = o;
}

__global__ __launch_bounds__(256) void prep_all(
    const float* __restrict__ states,
    const float* __restrict__ ew1, const float* __restrict__ nw1,
    const float* __restrict__ ew2, const float* __restrict__ nw2,
    const float* __restrict__ nw3, const float* __restrict__ ew3,
    const float* __restrict__ few, const float* __restrict__ eb3,
    const float* __restrict__ feb, const float* __restrict__ nb1,
    u16* __restrict__ nodeb, u16* __restrict__ w1p, u16* __restrict__ nw1cat,
    u16* __restrict__ nw1bp, u16* __restrict__ w2p, u16* __restrict__ nw2p,
    u16* __restrict__ nw3p, float* __restrict__ w3f, float* __restrict__ bvec)
{
  int blk = blockIdx.x;
  int tid = threadIdx.x;
  if (blk < 256){
    pack_body(ew1, w1p, 1024, 1, blk * 256 + tid);
  } else if (blk < 384){
    pack_body(nw1, nw1cat, 512, 0, (blk - 256) * 256 + tid);
  } else if (blk < 512){
    pack_body(nw1 + 512 * 512, nw1bp, 512, 0, (blk - 384) * 256 + tid);
  } else if (blk < 640){
    pack_body(ew2, w2p, 512, 0, (blk - 512) * 256 + tid);
  } else if (blk < 768){
    pack_body(nw2, nw2p, 512, 0, (blk - 640) * 256 + tid);
  } else if (blk < 896){
    pack_body(nw3, nw3p, 512, 0, (blk - 768) * 256 + tid);
  } else if (blk < 1025){
    int k = (blk - 896) * 4 + (tid >> 6);
    int l = tid & 63;
    if (k <= 512){
      const float* row = (k < 512) ? (ew3 + (size_t)k * 512) : eb3;
      float s = 0.f;
      for (int c = l; c < 512; c += 64) s += row[c] * few[c];
      #pragma unroll
      for (int off = 32; off; off >>= 1) s += __shfl_down(s, off);
      if (l == 0) w3f[k] = (k < 512) ? s : s + feb[0];
    }
  } else if (blk < 1027){
    int c = (blk - 1025) * 256 + tid;
    float s = 0.f;
    for (int m = 0; m < 512; ++m)
      s += eb3[m] * nw1[(size_t)(512 + m) * 512 + c];
    bvec[c] = nb1[c] + 7.f * s;
  } else {
    int idx = (blk - 1027) * 256 + tid;   // cast_node, n8 = NV*512/8
    const float4* s = (const float4*)states;
    float4 a = s[(size_t)idx * 2], b = s[(size_t)idx * 2 + 1];
    u16x8 o;
    o[0] = f2bf(a.x); o[1] = f2bf(a.y); o[2] = f2bf(a.z); o[3] = f2bf(a.w);
    o[4] = f2bf(b.x); o[5] = f2bf(b.y); o[6] = f2bf(b.z); o[7] = f2bf(b.w);
    *(u16x8*)&nodeb[(size_t)idx * 8] = o;
  }
}

extern "C" void kernel_launch(void* const* d_in, const int* in_sizes, int n_in,
                              void* d_out, int out_size, void* d_ws, size_t ws_size,
                              hipStream_t stream)
{
  (void)in_sizes; (void)n_in; (void)out_size; (void)ws_size;
  const float* states = (const float*)d_in[0];
  const float* ew1 = (const float*)d_in[1];
  const float* eb1 = (const float*)d_in[2];
  const float* ew2 = (const float*)d_in[3];
  const float* eb2 = (const float*)d_in[4];
  const float* eg  = (const float*)d_in[5];
  const float* ebt = (const float*)d_in[6];
  const float* ew3 = (const float*)d_in[7];
  const float* eb3 = (const float*)d_in[8];
  const float* nw1 = (const float*)d_in[9];
  const float* nb1 = (const float*)d_in[10];
  const float* nw2 = (const float*)d_in[11];
  const float* nb2 = (const float*)d_in[12];
  const float* ng  = (const float*)d_in[13];
  const float* nbt = (const float*)d_in[14];
  const float* nw3 = (const float*)d_in[15];
  const float* nb3 = (const float*)d_in[16];
  const float* fnw = (const float*)d_in[17];
  const float* fnb = (const float*)d_in[18];
  const float* few = (const float*)d_in[19];
  const float* feb = (const float*)d_in[20];
  float* out = (float*)d_out;

  char* ws = (char*)d_ws;
  size_t off = 0;
  auto alloc = [&](size_t bytes) -> void* {
    void* p = ws + off;
    off += (bytes + 255) & ~(size_t)255;
    return p;
  };
  const size_t NV = 28672;  // B*n
  u16* PQ     = (u16*)alloc(NV * 1024 * 2);   // [NV][P'(512)|Q(512)] bf16 (P' = P+b1)
  u16* nodeb  = (u16*)alloc(NV * 512 * 2);
  u16* hsumb  = (u16*)alloc(NV * 512 * 2);
  u16* w1p    = (u16*)alloc(512 * 1024 * 2);
  u16* nw1cat = (u16*)alloc(1024 * 512 * 2);  // [nw1a packed | w3n packed]
  u16* nw1bp  = (u16*)alloc(512 * 512 * 2);
  u16* w2p    = (u16*)alloc(512 * 512 * 2);
  u16* nw2p   = (u16*)alloc(512 * 512 * 2);
  u16* nw3p   = (u16*)alloc(512 * 512 * 2);
  float* w3f  = (float*)alloc(513 * 4);
  float* bvec = (float*)alloc(512 * 4);

  // all packing/folding/casting in one launch (segments by blockIdx)
  prep_all<<<1027 + 7168, 256, 0, stream>>>(
      states, ew1, nw1, ew2, nw2, nw3, ew3, few, eb3, feb, nb1,
      nodeb, w1p, nw1cat, nw1bp, w2p, nw2p, nw3p, w3f, bvec);
  // w3n = ew3 @ nw1b, written directly packed into nw1cat second half
  gemm_w3n<<<dim3(8, 4), 256, 0, stream>>>(ew3, nw1bp, nw1cat + 512 * 512);

  // Pass 1
  gemm64_0<<<dim3(448, 2), 256, 0, stream>>>(nodeb, w1p, eb1, PQ);
  edge0_kernel<<<NB_E, 512, 0, stream>>>(PQ, w2p, eb2, eg, ebt, hsumb);
  // Node update + head + PQ for pass 2 (fused)
  node_mega<<<448, 512, 0, stream>>>(nodeb, hsumb, nw1cat, nw2p, nw3p, w1p,
                                     bvec, nb2, ng, nbt, nb3, fnw, fnb, eb1, PQ, out);
  // Pass 2 edge head
  edge1_kernel<<<NB_E, 512, 0, stream>>>(PQ, w2p, eb2, eg, ebt, w3f, out);
}

// Round 21
// 480.281 us; speedup vs baseline: 1.6187x; 1.0803x over previous
//
#include <hip/hip_runtime.h>

#define LN_EPS 1e-5f
#define NSRC 28672          // total source nodes (B*n)
#define SPB 9               // source groups per edge block
#define EPB 63              // edges per block = SPB*7
#define NB_E 3186           // ceil(NSRC / SPB)

typedef unsigned short u16;
typedef u16 u16x8 __attribute__((ext_vector_type(8)));
typedef __bf16 bf16x8 __attribute__((ext_vector_type(8)));
typedef float f32x4 __attribute__((ext_vector_type(4)));
typedef float f32x2 __attribute__((ext_vector_type(2)));

__device__ __forceinline__ u16 f2bf(float f){
  return __builtin_bit_cast(u16, (__bf16)f);
}
__device__ __forceinline__ float bf2f(u16 b){
  return (float)__builtin_bit_cast(__bf16, b);
}
__device__ __forceinline__ f32x4 mfma16(u16x8 a, u16x8 b, f32x4 c){
  return __builtin_amdgcn_mfma_f32_16x16x32_bf16(
      __builtin_bit_cast(bf16x8, a), __builtin_bit_cast(bf16x8, b), c, 0, 0, 0);
}
// LDS h-tile: [64 rows][512 k] bf16, XOR swizzle on k (8-elem granules)
__device__ __forceinline__ int uidx(int row, int k){
  return row * 512 + (k ^ ((row & 7) << 3));
}

__device__ __forceinline__ void zero_acc(f32x4 (&acc)[4][4]){
  #pragma unroll
  for (int mt = 0; mt < 4; ++mt)
    #pragma unroll
    for (int ct = 0; ct < 4; ++ct){
      f32x4 z = {0.f, 0.f, 0.f, 0.f};
      acc[mt][ct] = z;
    }
}

// Issue first kt's 4 B-fragment loads BEFORE the preceding barrier (in flight
// across s_barrier; hides cold-start L2 latency).
__device__ __forceinline__ void preload_b4(const u16* __restrict__ Bp, int wave, int lane,
                                           u16x8 (&b)[4]){
  const u16* bb = Bp + ((size_t)(wave * 4) * 64 + lane) * 8;
  #pragma unroll
  for (int ct = 0; ct < 4; ++ct) b[ct] = *(const u16x8*)&bb[ct * 512];
}

// GEMM, A from LDS (64 rows), B from global (N=512 packing, kt-stride 16384),
// 1-deep register prefetch (~64 VGPR clean). b_cur arrives preloaded.
__device__ __forceinline__ void gemm_pipe(const u16* hA, const u16* __restrict__ Bp,
                                          f32x4 (&acc)[4][4], int wave, int lane,
                                          u16x8 (&b_cur)[4]){
  int lrow = lane & 15, lhi = lane >> 4;
  const u16* bb = Bp + ((size_t)(wave * 4) * 64 + lane) * 8;
  u16x8 b_nxt[4], a[4];
  #pragma unroll
  for (int kt = 0; kt < 16; ++kt){
    #pragma unroll
    for (int mt = 0; mt < 4; ++mt)
      a[mt] = *(const u16x8*)&hA[uidx(mt * 16 + lrow, kt * 32 + lhi * 8)];
    if (kt < 15){
      #pragma unroll
      for (int ct = 0; ct < 4; ++ct)
        b_nxt[ct] = *(const u16x8*)&bb[(size_t)(kt + 1) * 16384 + ct * 512];
    }
    __builtin_amdgcn_s_setprio(1);
    #pragma unroll
    for (int ct = 0; ct < 4; ++ct)
      #pragma unroll
      for (int mt = 0; mt < 4; ++mt)
        acc[mt][ct] = mfma16(a[mt], b_cur[ct], acc[mt][ct]);
    __builtin_amdgcn_s_setprio(0);
    #pragma unroll
    for (int ct = 0; ct < 4; ++ct) b_cur[ct] = b_nxt[ct];
  }
}

// GEMM over hA with custom B base/kt-stride (for N=1024 w1p packing).
__device__ __forceinline__ void gemm_pipe_s(const u16* hA, const u16* __restrict__ bbBase,
                                            int ktStride, f32x4 (&acc)[4][4],
                                            int lane){
  int lrow = lane & 15, lhi = lane >> 4;
  u16x8 b_cur[4], b_nxt[4], a[4];
  #pragma unroll
  for (int ct = 0; ct < 4; ++ct) b_cur[ct] = *(const u16x8*)&bbBase[ct * 512];
  #pragma unroll
  for (int kt = 0; kt < 16; ++kt){
    #pragma unroll
    for (int mt = 0; mt < 4; ++mt)
      a[mt] = *(const u16x8*)&hA[uidx(mt * 16 + lrow, kt * 32 + lhi * 8)];
    if (kt < 15){
      #pragma unroll
      for (int ct = 0; ct < 4; ++ct)
        b_nxt[ct] = *(const u16x8*)&bbBase[(size_t)(kt + 1) * ktStride + ct * 512];
    }
    __builtin_amdgcn_s_setprio(1);
    #pragma unroll
    for (int ct = 0; ct < 4; ++ct)
      #pragma unroll
      for (int mt = 0; mt < 4; ++mt)
        acc[mt][ct] = mfma16(a[mt], b_cur[ct], acc[mt][ct]);
    __builtin_amdgcn_s_setprio(0);
    #pragma unroll
    for (int ct = 0; ct < 4; ++ct) b_cur[ct] = b_nxt[ct];
  }
}

__device__ __forceinline__ void add_bias8(f32x4 (&acc)[4][4], const float* __restrict__ b,
                                          int wave, int lane){
  int lrow = lane & 15;
  #pragma unroll
  for (int ct = 0; ct < 4; ++ct){
    float bb = b[wave * 64 + ct * 16 + lrow];
    #pragma unroll
    for (int mt = 0; mt < 4; ++mt)
      #pragma unroll
      for (int r = 0; r < 4; ++r) acc[mt][ct][r] += bb;
  }
}

// acc += bias; relu; write bf16 into hA (swizzled). (r1 stage of node MLP.)
__device__ __forceinline__ void relu_to_lds(f32x4 (&acc)[4][4], u16* hA,
                                            const float* __restrict__ b,
                                            int wave, int lane){
  int lrow = lane & 15, lhi = lane >> 4;
  #pragma unroll
  for (int ct = 0; ct < 4; ++ct){
    int c = wave * 64 + ct * 16 + lrow;
    float bb = b[c];
    #pragma unroll
    for (int mt = 0; mt < 4; ++mt)
      #pragma unroll
      for (int r = 0; r < 4; ++r){
        int row = mt * 16 + lhi * 4 + r;
        hA[uidx(row, c)] = f2bf(fmaxf(acc[mt][ct][r] + bb, 0.f));
      }
  }
}

// acc += b2; LayerNorm over 512 cols per row; relu.  (r15-measured: 64 VGPR)
// TO_ACC=0: write bf16 into hA (swizzled); TO_ACC=1: result into acc.
template<int TO_ACC>
__device__ __forceinline__ void ln_relu8_t(f32x4 (&acc)[4][4], u16* hA,
    f32x2 (*stats)[8], f32x2* mufb,
    const float* __restrict__ b2, const float* __restrict__ g, const float* __restrict__ bt,
    int wave, int lane, int tid)
{
  int lrow = lane & 15, lhi = lane >> 4;
  float s1[4][4], s2[4][4];
  #pragma unroll
  for (int mt = 0; mt < 4; ++mt)
    #pragma unroll
    for (int r = 0; r < 4; ++r){ s1[mt][r] = 0.f; s2[mt][r] = 0.f; }
  #pragma unroll
  for (int ct = 0; ct < 4; ++ct){
    int c = wave * 64 + ct * 16 + lrow;
    float bb = b2[c];
    #pragma unroll
    for (int mt = 0; mt < 4; ++mt)
      #pragma unroll
      for (int r = 0; r < 4; ++r){
        float x = acc[mt][ct][r] + bb;
        acc[mt][ct][r] = x;
        s1[mt][r] += x; s2[mt][r] += x * x;
      }
  }
  #pragma unroll
  for (int off = 1; off < 16; off <<= 1){
    #pragma unroll
    for (int mt = 0; mt < 4; ++mt)
      #pragma unroll
      for (int r = 0; r < 4; ++r){
        s1[mt][r] += __shfl_xor(s1[mt][r], off);
        s2[mt][r] += __shfl_xor(s2[mt][r], off);
      }
  }
  float sa1 = 0.f, sa2 = 0.f;
  #pragma unroll
  for (int mt = 0; mt < 4; ++mt)
    #pragma unroll
    for (int r = 0; r < 4; ++r)
      if (lrow == mt * 4 + r){ sa1 = s1[mt][r]; sa2 = s2[mt][r]; }
  int rowa = (lrow >> 2) * 16 + lhi * 4 + (lrow & 3);
  f32x2 pa = {sa1, sa2};
  stats[rowa][wave] = pa;
  __syncthreads();              // also: all waves done reading hA (prev GEMM)
  if (tid < 64){
    float a = 0.f, b = 0.f;
    #pragma unroll
    for (int w = 0; w < 8; ++w){ a += stats[tid][w][0]; b += stats[tid][w][1]; }
    float mu  = a * (1.f / 512.f);
    float var = b * (1.f / 512.f) - mu * mu;
    f32x2 mr = {mu, rsqrtf(fmaxf(var, 0.f) + LN_EPS)};
    mufb[tid] = mr;
  }
  __syncthreads();
  float gv[4], btv[4];
  #pragma unroll
  for (int ct = 0; ct < 4; ++ct){
    int c = wave * 64 + ct * 16 + lrow;
    gv[ct] = g[c]; btv[ct] = bt[c];
  }
  #pragma unroll
  for (int mt = 0; mt < 4; ++mt)
    #pragma unroll
    for (int r = 0; r < 4; ++r){
      int row = mt * 16 + lhi * 4 + r;
      f32x2 mr = mufb[row];
      #pragma unroll
      for (int ct = 0; ct < 4; ++ct){
        int c = wave * 64 + ct * 16 + lrow;
        float x = (acc[mt][ct][r] - mr[0]) * mr[1] * gv[ct] + btv[ct];
        if (TO_ACC) acc[mt][ct][r] = fmaxf(x, 0.f);
        else        hA[uidx(row, c)] = f2bf(fmaxf(x, 0.f));
      }
    }
  // TO_ACC=0 caller: barrier before any cross-thread hA read.
}

// dot each row with weight vector w; per-wave partial -> stats[row][wave].x
__device__ __forceinline__ void head_partial8(f32x4 (&acc)[4][4], const float* __restrict__ w,
                                              f32x2 (*stats)[8], int wave, int lane)
{
  int lrow = lane & 15, lhi = lane >> 4;
  float hs[4][4];
  #pragma unroll
  for (int mt = 0; mt < 4; ++mt)
    #pragma unroll
    for (int r = 0; r < 4; ++r) hs[mt][r] = 0.f;
  #pragma unroll
  for (int ct = 0; ct < 4; ++ct){
    int c = wave * 64 + ct * 16 + lrow;
    float f = w[c];
    #pragma unroll
    for (int mt = 0; mt < 4; ++mt)
      #pragma unroll
      for (int r = 0; r < 4; ++r) hs[mt][r] += acc[mt][ct][r] * f;
  }
  #pragma unroll
  for (int off = 1; off < 16; off <<= 1)
    #pragma unroll
    for (int mt = 0; mt < 4; ++mt)
      #pragma unroll
      for (int r = 0; r < 4; ++r) hs[mt][r] += __shfl_xor(hs[mt][r], off);
  float sa = 0.f;
  #pragma unroll
  for (int mt = 0; mt < 4; ++mt)
    #pragma unroll
    for (int r = 0; r < 4; ++r)
      if (lrow == mt * 4 + r) sa = hs[mt][r];
  int rowa = (lrow >> 2) * 16 + lhi * 4 + (lrow & 3);
  f32x2 pa = {sa, 0.f};
  stats[rowa][wave] = pa;
}

// Staging, wave-per-source-group: block covers sources bs..bs+8 (9 groups, 63
// rows; row = grp*7+j). Wave w stages group w (wave 0 also group 8); P'[s]
// loaded ONCE per group (vs 7x), Q pipelined 1-deep. Row 63 zeroed by wave 1;
// groups with s >= NSRC zeroed.
__device__ __forceinline__ void stage_h1(const u16* __restrict__ PQ, int bs, u16* hA,
                                         int wave, int lane){
  for (int grp = wave; grp < SPB; grp += 8){
    int s = bs + grp;
    int r0 = grp * 7;
    if (s < NSRC){
      u16x8 p8 = *(const u16x8*)&PQ[(size_t)s * 1024 + lane * 8];
      const u16* Qb = PQ + (size_t)(s - s % 7) * 1024 + 512 + lane * 8;
      u16x8 q_cur = *(const u16x8*)&Qb[0];
      #pragma unroll
      for (int j = 0; j < 7; ++j){
        u16x8 q_nxt;
        if (j < 6) q_nxt = *(const u16x8*)&Qb[(size_t)(j + 1) * 1024];
        u16x8 o;
        #pragma unroll
        for (int u = 0; u < 8; ++u)
          o[u] = f2bf(fmaxf(bf2f(p8[u]) + bf2f(q_cur[u]), 0.f));
        *(u16x8*)&hA[uidx(r0 + j, lane * 8)] = o;
        q_cur = q_nxt;
      }
    } else {
      u16x8 z;
      #pragma unroll
      for (int u = 0; u < 8; ++u) z[u] = 0;
      #pragma unroll
      for (int j = 0; j < 7; ++j)
        *(u16x8*)&hA[uidx(r0 + j, lane * 8)] = z;
    }
  }
  if (wave == 1){
    u16x8 z;
    #pragma unroll
    for (int u = 0; u < 8; ++u) z[u] = 0;
    *(u16x8*)&hA[uidx(63, lane * 8)] = z;
  }
}

// ======== edge pass 0: stage -> GEMM1(w2) -> LN -> colsum -> hsum (global) ======
__global__ __launch_bounds__(512, 2) void edge0_kernel(
    const u16* __restrict__ PQ, const u16* __restrict__ w2p,
    const float* __restrict__ b2,
    const float* __restrict__ g, const float* __restrict__ bt,
    u16* __restrict__ hsum)
{
  __shared__ alignas(16) u16 hA[64 * 512];
  __shared__ f32x2 stats[64][8];
  __shared__ f32x2 mufb[64];
  int bs = blockIdx.x * SPB;
  int tid = threadIdx.x;
  int wave = tid >> 6, lane = tid & 63;

  stage_h1(PQ, bs, hA, wave, lane);
  u16x8 bpre[4];
  preload_b4(w2p, wave, lane, bpre);
  __syncthreads();

  f32x4 acc[4][4];
  zero_acc(acc);
  gemm_pipe(hA, w2p, acc, wave, lane, bpre);
  ln_relu8_t<0>(acc, hA, stats, mufb, b2, g, bt, wave, lane, tid);
  __syncthreads();                    // h2n rows visible
  // vectorized column sums: wave = source group (wave 0 also takes sl=8);
  // lane covers 8 cols. hsum[s][c0..c0+8) = sum_j h2n[sl*7+j][c]
  {
    int c0 = lane * 8;
    for (int sl = wave; sl < SPB; sl += 8){
      int s = bs + sl;
      if (s < NSRC){
        float a8[8];
        #pragma unroll
        for (int u = 0; u < 8; ++u) a8[u] = 0.f;
        #pragma unroll
        for (int j = 0; j < 7; ++j){
          u16x8 v = *(const u16x8*)&hA[uidx(sl * 7 + j, c0)];
          #pragma unroll
          for (int u = 0; u < 8; ++u) a8[u] += bf2f(v[u]);
        }
        u16x8 o;
        #pragma unroll
        for (int u = 0; u < 8; ++u) o[u] = f2bf(a8[u]);
        *(u16x8*)&hsum[(size_t)s * 512 + c0] = o;
      }
    }
  }
}

// ============ edge pass 1: w3 folded to a vector (w3f = ew3@few) ============
__global__ __launch_bounds__(512, 2) void edge1_kernel(
    const u16* __restrict__ PQ, const u16* __restrict__ w2p,
    const float* __restrict__ b2,
    const float* __restrict__ g, const float* __restrict__ bt,
    const float* __restrict__ w3f, float* __restrict__ out)
{
  __shared__ alignas(16) u16 hA[64 * 512];
  __shared__ f32x2 stats[64][8];
  __shared__ f32x2 mufb[64];
  int bs = blockIdx.x * SPB;
  int tid = threadIdx.x;
  int wave = tid >> 6, lane = tid & 63;

  stage_h1(PQ, bs, hA, wave, lane);
  u16x8 bpre[4];
  preload_b4(w2p, wave, lane, bpre);
  __syncthreads();

  f32x4 acc[4][4];
  zero_acc(acc);
  gemm_pipe(hA, w2p, acc, wave, lane, bpre);
  ln_relu8_t<1>(acc, hA, stats, mufb, b2, g, bt, wave, lane, tid);  // acc := relu(LN)
  head_partial8(acc, w3f, stats, wave, lane);
  __syncthreads();
  if (tid < EPB){
    int sl = tid / 7, j = tid % 7;
    int s = bs + sl;
    if (s < NSRC){
      int gg = s / 7, i = s % 7;
      float sum = w3f[512];   // eb3.few + feb
      #pragma unroll
      for (int w = 0; w < 8; ++w) sum += stats[tid][w][0];
      out[(size_t)gg * 56 + 7 + i * 7 + j] = sum;
    }
  }
}

// ==== node mega-kernel v2: split-K LDS-staged r1 -> h2 -> LN -> node2 -> PQ ====
// r1 = relu(node@nw1a + hsum@w3n + bvec): A halves staged to LDS (edge-like
// register profile; target <= 64 VGPR -> 2 blocks/CU).
__global__ __launch_bounds__(512, 2) void node_mega(
    const u16* __restrict__ nodeb, const u16* __restrict__ hsumb,
    const u16* __restrict__ nw1cat, const u16* __restrict__ nw2p,
    const u16* __restrict__ nw3p, const u16* __restrict__ w1p,
    const float* __restrict__ bvec, const float* __restrict__ nb2,
    const float* __restrict__ ng, const float* __restrict__ nbt,
    const float* __restrict__ nb3, const float* __restrict__ hw,
    const float* __restrict__ hb, const float* __restrict__ b1,
    u16* __restrict__ PQ, float* __restrict__ out)
{
  __shared__ alignas(16) u16 hA[64 * 512];
  __shared__ f32x2 stats[64][8];
  __shared__ f32x2 mufb[64];
  int tid = threadIdx.x;
  int wave = tid >> 6, lane = tid & 63;
  int lrow = lane & 15, lhi = lane >> 4;
  size_t row0 = (size_t)blockIdx.x * 64;

  // stage nodeb rows -> hA
  #pragma unroll
  for (int it = 0; it < 8; ++it){
    int row = it * 8 + wave;
    u16x8 v = *(const u16x8*)&nodeb[(row0 + row) * 512 + lane * 8];
    *(u16x8*)&hA[uidx(row, lane * 8)] = v;
  }
  u16x8 bpre[4];
  preload_b4(nw1cat, wave, lane, bpre);
  __syncthreads();
  f32x4 acc[4][4];
  zero_acc(acc);
  gemm_pipe(hA, nw1cat, acc, wave, lane, bpre);      // node @ nw1a
  __syncthreads();   // all reads of hA done before restage
  // stage hsumb rows -> hA
  #pragma unroll
  for (int it = 0; it < 8; ++it){
    int row = it * 8 + wave;
    u16x8 v = *(const u16x8*)&hsumb[(row0 + row) * 512 + lane * 8];
    *(u16x8*)&hA[uidx(row, lane * 8)] = v;
  }
  preload_b4(nw1cat + (size_t)16 * 16384, wave, lane, bpre);
  __syncthreads();
  gemm_pipe(hA, nw1cat + (size_t)16 * 16384, acc, wave, lane, bpre);  // + hsum @ w3n
  __syncthreads();   // reads done before overwrite
  relu_to_lds(acc, hA, bvec, wave, lane);            // r1 -> hA
  preload_b4(nw2p, wave, lane, bpre);
  __syncthreads();
  // h2 = r1 @ nw2 (+nb2 in LN) -> LN -> relu -> hA
  zero_acc(acc);
  gemm_pipe(hA, nw2p, acc, wave, lane, bpre);
  ln_relu8_t<0>(acc, hA, stats, mufb, nb2, ng, nbt, wave, lane, tid);
  preload_b4(nw3p, wave, lane, bpre);
  __syncthreads();
  // node2 = h2n @ nw3 + nb3
  zero_acc(acc);
  gemm_pipe(hA, nw3p, acc, wave, lane, bpre);
  add_bias8(acc, nb3, wave, lane);
  __syncthreads();   // all GEMM reads of hA (h2n) done before overwrite
  // node2 -> hA (for PQ GEMMs); head partial
  #pragma unroll
  for (int ct = 0; ct < 4; ++ct){
    int c = wave * 64 + ct * 16 + lrow;
    #pragma unroll
    for (int mt = 0; mt < 4; ++mt)
      #pragma unroll
      for (int r = 0; r < 4; ++r)
        hA[uidx(mt * 16 + lhi * 4 + r, c)] = f2bf(acc[mt][ct][r]);
  }
  head_partial8(acc, hw, stats, wave, lane);
  __syncthreads();   // node2 + stats visible
  if (tid < 64){
    size_t v = row0 + tid;
    float s = hb[0];
    #pragma unroll
    for (int w = 0; w < 8; ++w) s += stats[tid][w][0];
    out[(v / 7) * 56 + (v % 7)] = s;
  }
  // PQ = node2 @ w1p  (N=1024, two 512-col passes; P half gets +b1)
  #pragma unroll
  for (int pp = 0; pp < 2; ++pp){
    zero_acc(acc);
    const u16* bbBase = w1p + (((size_t)(pp * 32) + wave * 4) * 64 + lane) * 8;
    gemm_pipe_s(hA, bbBase, 32768, acc, lane);
    #pragma unroll
    for (int ct = 0; ct < 4; ++ct){
      int cc = wave * 64 + ct * 16 + lrow;
      int c = pp * 512 + cc;
      float bb = (pp == 0) ? b1[cc] : 0.f;
      #pragma unroll
      for (int mt = 0; mt < 4; ++mt)
        #pragma unroll
        for (int r = 0; r < 4; ++r){
          size_t grow = row0 + mt * 16 + lhi * 4 + r;
          PQ[grow * 1024 + c] = f2bf(acc[mt][ct][r] + bb);
        }
    }
  }
}

// gemm64 MODE0: PQ = nodeb @ w1p (pass 1); P half (coff==0) gets +b1.
__global__ __launch_bounds__(256, 2) void gemm64_0(
    const u16* __restrict__ A0, const u16* __restrict__ Bp,
    const float* __restrict__ b1, u16* __restrict__ Cout)
{
  int tid = threadIdx.x;
  int wave = tid >> 6, lane = tid & 63;
  int lrow = lane & 15, lhi = lane >> 4;
  size_t row0 = (size_t)blockIdx.x * 64;
  int coff = blockIdx.y * 512;
  const u16* bb = Bp + (((size_t)(coff >> 4) + wave * 8) * 64 + lane) * 8;
  f32x4 acc[4][8];
  #pragma unroll
  for (int mt = 0; mt < 4; ++mt)
    #pragma unroll
    for (int ct = 0; ct < 8; ++ct){
      f32x4 z = {0.f, 0.f, 0.f, 0.f};
      acc[mt][ct] = z;
    }
  u16x8 b_cur[8], b_nxt[8];
  #pragma unroll
  for (int ct = 0; ct < 8; ++ct) b_cur[ct] = *(const u16x8*)&bb[ct * 512];
  #pragma unroll
  for (int kt = 0; kt < 16; ++kt){
    u16x8 af[4];
    #pragma unroll
    for (int mt = 0; mt < 4; ++mt)
      af[mt] = *(const u16x8*)&A0[(row0 + mt * 16 + lrow) * 512 + kt * 32 + lhi * 8];
    if (kt < 15){
      #pragma unroll
      for (int ct = 0; ct < 8; ++ct)
        b_nxt[ct] = *(const u16x8*)&bb[((size_t)(kt + 1) * 64 * 64 + ct * 64) * 8];
    }
    __builtin_amdgcn_s_setprio(1);
    #pragma unroll
    for (int ct = 0; ct < 8; ++ct)
      #pragma unroll
      for (int mt = 0; mt < 4; ++mt) acc[mt][ct] = mfma16(af[mt], b_cur[ct], acc[mt][ct]);
    __builtin_amdgcn_s_setprio(0);
    #pragma unroll
    for (int ct = 0; ct < 8; ++ct) b_cur[ct] = b_nxt[ct];
  }
  #pragma unroll
  for (int ct = 0; ct < 8; ++ct){
    int cc = wave * 128 + ct * 16 + lrow;
    int c = coff + cc;
    float bb2 = (coff == 0) ? b1[cc] : 0.f;
    #pragma unroll
    for (int mt = 0; mt < 4; ++mt)
      #pragma unroll
      for (int r = 0; r < 4; ++r){
        size_t grow = row0 + mt * 16 + lhi * 4 + r;
        Cout[grow * 1024 + c] = f2bf(acc[mt][ct][r] + bb2);
      }
  }
}

// w3n = ew3(f32) @ nw1b(packed bf16): 512x512, K=512. Grid (8,4).
// Output written DIRECTLY in packed B-fragment order into nw1cat+512*512.
__global__ __launch_bounds__(256) void gemm_w3n(
    const float* __restrict__ A, const u16* __restrict__ Bp, u16* __restrict__ dst)
{
  int tid = threadIdx.x;
  int wave = tid >> 6, lane = tid & 63;
  int lrow = lane & 15, lhi = lane >> 4;
  size_t row0 = (size_t)blockIdx.x * 64;
  int coff = blockIdx.y * 128;
  const u16* bb = Bp + (((size_t)(coff >> 4) + wave * 2) * 64 + lane) * 8;
  f32x4 acc[4][2];
  #pragma unroll
  for (int mt = 0; mt < 4; ++mt)
    #pragma unroll
    for (int ct = 0; ct < 2; ++ct){
      f32x4 z = {0.f, 0.f, 0.f, 0.f};
      acc[mt][ct] = z;
    }
  for (int kt = 0; kt < 16; ++kt){
    u16x8 af[4], bv[2];
    #pragma unroll
    for (int mt = 0; mt < 4; ++mt){
      const float* ar = A + (row0 + mt * 16 + lrow) * 512 + kt * 32 + lhi * 8;
      float4 v0 = *(const float4*)ar, v1 = *(const float4*)(ar + 4);
      af[mt][0] = f2bf(v0.x); af[mt][1] = f2bf(v0.y);
      af[mt][2] = f2bf(v0.z); af[mt][3] = f2bf(v0.w);
      af[mt][4] = f2bf(v1.x); af[mt][5] = f2bf(v1.y);
      af[mt][6] = f2bf(v1.z); af[mt][7] = f2bf(v1.w);
    }
    #pragma unroll
    for (int ct = 0; ct < 2; ++ct)
      bv[ct] = *(const u16x8*)&bb[(size_t)kt * 16384 + ct * 512];
    #pragma unroll
    for (int ct = 0; ct < 2; ++ct)
      #pragma unroll
      for (int mt = 0; mt < 4; ++mt) acc[mt][ct] = mfma16(af[mt], bv[ct], acc[mt][ct]);
  }
  #pragma unroll
  for (int ct = 0; ct < 2; ++ct){
    int c = coff + wave * 32 + ct * 16 + lrow;
    int ctp = c >> 4, lanelo = c & 15;
    #pragma unroll
    for (int mt = 0; mt < 4; ++mt)
      #pragma unroll
      for (int r = 0; r < 4; ++r){
        int k = (int)row0 + mt * 16 + lhi * 4 + r;
        int kt = k >> 5, lanehi = (k >> 3) & 3, j = k & 7;
        dst[((size_t)(kt * 32 + ctp) * 64 + lanehi * 16 + lanelo) * 8 + j]
            = f2bf(acc[mt][ct][r]);
      }
  }
}

// ==== prep_all: all packing / folding / casting in ONE launch ====
__device__ __forceinline__ void pack_body(const float* __restrict__ W, u16* __restrict__ dst,
                                          int N, int w1mode, int idx){
  int lane = idx & 63;
  int t = idx >> 6;
  int nt = N >> 4;
  int ct = t % nt;
  int kt = t / nt;
  int c  = ct * 16 + (lane & 15);
  int k0 = kt * 32 + (lane >> 4) * 8;
  u16x8 o;
  #pragma unroll
  for (int j = 0; j < 8; ++j){
    int k = k0 + j;
    float v;
    if (w1mode){
      v = (c < 512) ? W[(size_t)k * 512 + c] : W[(size_t)(k + 512) * 512 + (c - 512)];
    } else {
      v = W[(size_t)k * N + c];
    }
    o[j] = f2bf(v);
  }
  *(u16x8*)&dst[(size_t)idx * 8] = o;
}

__global__ __launch_bounds__(256) void prep_all(
    const float* __restrict__ states,
    const float* __restrict__ ew1, const float* __restrict__ nw1,
    const float* __restrict__ ew2, const float* __restrict__ nw2,
    const float* __restrict__ nw3, const float* __restrict__ ew3,
    const float* __restrict__ few, const float* __restrict__ eb3,
    const float* __restrict__ feb, const float* __restrict__ nb1,
    u16* __restrict__ nodeb, u16* __restrict__ w1p, u16* __restrict__ nw1cat,
    u16* __restrict__ nw1bp, u16* __restrict__ w2p, u16* __restrict__ nw2p,
    u16* __restrict__ nw3p, float* __restrict__ w3f, float* __restrict__ bvec)
{
  int blk = blockIdx.x;
  int tid = threadIdx.x;
  if (blk < 256){
    pack_body(ew1, w1p, 1024, 1, blk * 256 + tid);
  } else if (blk < 384){
    pack_body(nw1, nw1cat, 512, 0, (blk - 256) * 256 + tid);
  } else if (blk < 512){
    pack_body(nw1 + 512 * 512, nw1bp, 512, 0, (blk - 384) * 256 + tid);
  } else if (blk < 640){
    pack_body(ew2, w2p, 512, 0, (blk - 512) * 256 + tid);
  } else if (blk < 768){
    pack_body(nw2, nw2p, 512, 0, (blk - 640) * 256 + tid);
  } else if (blk < 896){
    pack_body(nw3, nw3p, 512, 0, (blk - 768) * 256 + tid);
  } else if (blk < 1025){
    int k = (blk - 896) * 4 + (tid >> 6);
    int l = tid & 63;
    if (k <= 512){
      const float* row = (k < 512) ? (ew3 + (size_t)k * 512) : eb3;
      float s = 0.f;
      for (int c = l; c < 512; c += 64) s += row[c] * few[c];
      #pragma unroll
      for (int off = 32; off; off >>= 1) s += __shfl_down(s, off);
      if (l == 0) w3f[k] = (k < 512) ? s : s + feb[0];
    }
  } else if (blk < 1027){
    int c = (blk - 1025) * 256 + tid;
    float s = 0.f;
    for (int m = 0; m < 512; ++m)
      s += eb3[m] * nw1[(size_t)(512 + m) * 512 + c];
    bvec[c] = nb1[c] + 7.f * s;
  } else {
    int idx = (blk - 1027) * 256 + tid;   // cast_node, n8 = NV*512/8
    const float4* s = (const float4*)states;
    float4 a = s[(size_t)idx * 2], b = s[(size_t)idx * 2 + 1];
    u16x8 o;
    o[0] = f2bf(a.x); o[1] = f2bf(a.y); o[2] = f2bf(a.z); o[3] = f2bf(a.w);
    o[4] = f2bf(b.x); o[5] = f2bf(b.y); o[6] = f2bf(b.z); o[7] = f2bf(b.w);
    *(u16x8*)&nodeb[(size_t)idx * 8] = o;
  }
}

extern "C" void kernel_launch(void* const* d_in, const int* in_sizes, int n_in,
                              void* d_out, int out_size, void* d_ws, size_t ws_size,
                              hipStream_t stream)
{
  (void)in_sizes; (void)n_in; (void)out_size; (void)ws_size;
  const float* states = (const float*)d_in[0];
  const float* ew1 = (const float*)d_in[1];
  const float* eb1 = (const float*)d_in[2];
  const float* ew2 = (const float*)d_in[3];
  const float* eb2 = (const float*)d_in[4];
  const float* eg  = (const float*)d_in[5];
  const float* ebt = (const float*)d_in[6];
  const float* ew3 = (const float*)d_in[7];
  const float* eb3 = (const float*)d_in[8];
  const float* nw1 = (const float*)d_in[9];
  const float* nb1 = (const float*)d_in[10];
  const float* nw2 = (const float*)d_in[11];
  const float* nb2 = (const float*)d_in[12];
  const float* ng  = (const float*)d_in[13];
  const float* nbt = (const float*)d_in[14];
  const float* nw3 = (const float*)d_in[15];
  const float* nb3 = (const float*)d_in[16];
  const float* fnw = (const float*)d_in[17];
  const float* fnb = (const float*)d_in[18];
  const float* few = (const float*)d_in[19];
  const float* feb = (const float*)d_in[20];
  float* out = (float*)d_out;

  char* ws = (char*)d_ws;
  size_t off = 0;
  auto alloc = [&](size_t bytes) -> void* {
    void* p = ws + off;
    off += (bytes + 255) & ~(size_t)255;
    return p;
  };
  const size_t NV = 28672;  // B*n
  u16* PQ     = (u16*)alloc(NV * 1024 * 2);   // [NV][P'(512)|Q(512)] bf16 (P' = P+b1)
  u16* nodeb  = (u16*)alloc(NV * 512 * 2);
  u16* hsumb  = (u16*)alloc(NV * 512 * 2);
  u16* w1p    = (u16*)alloc(512 * 1024 * 2);
  u16* nw1cat = (u16*)alloc(1024 * 512 * 2);  // [nw1a packed | w3n packed]
  u16* nw1bp  = (u16*)alloc(512 * 512 * 2);
  u16* w2p    = (u16*)alloc(512 * 512 * 2);
  u16* nw2p   = (u16*)alloc(512 * 512 * 2);
  u16* nw3p   = (u16*)alloc(512 * 512 * 2);
  float* w3f  = (float*)alloc(513 * 4);
  float* bvec = (float*)alloc(512 * 4);

  // all packing/folding/casting in one launch (segments by blockIdx)
  prep_all<<<1027 + 7168, 256, 0, stream>>>(
      states, ew1, nw1, ew2, nw2, nw3, ew3, few, eb3, feb, nb1,
      nodeb, w1p, nw1cat, nw1bp, w2p, nw2p, nw3p, w3f, bvec);
  // w3n = ew3 @ nw1b, written directly packed into nw1cat second half
  gemm_w3n<<<dim3(8, 4), 256, 0, stream>>>(ew3, nw1bp, nw1cat + 512 * 512);

  // Pass 1
  gemm64_0<<<dim3(448, 2), 256, 0, stream>>>(nodeb, w1p, eb1, PQ);
  edge0_kernel<<<NB_E, 512, 0, stream>>>(PQ, w2p, eb2, eg, ebt, hsumb);
  // Node update + head + PQ for pass 2 (fused)
  node_mega<<<448, 512, 0, stream>>>(nodeb, hsumb, nw1cat, nw2p, nw3p, w1p,
                                     bvec, nb2, ng, nbt, nb3, fnw, fnb, eb1, PQ, out);
  // Pass 2 edge head
  edge1_kernel<<<NB_E, 512, 0, stream>>>(PQ, w2p, eb2, eg, ebt, w3f, out);
}